// Round 8
// baseline (461.790 us; speedup 1.0000x reference)
//
#include <hip/hip_runtime.h>
#include <hip/hip_bf16.h>
#include <math.h>

#define HW 4096
#define EPSV 1e-5f

typedef unsigned short ushort;
typedef __attribute__((ext_vector_type(8))) short bf16x8;
typedef __attribute__((ext_vector_type(4))) float f32x4;

__device__ inline ushort f2bf(float f) {
    __hip_bfloat16 h = __float2bfloat16(f);
    return *reinterpret_cast<ushort*>(&h);
}
__device__ inline float bf2f(ushort u) {
    unsigned int v = ((unsigned int)u) << 16;
    return __uint_as_float(v);
}

// ---------------------------------------------------------------------------
// fp32 [b][C][4096] -> bf16 channel-last [b][4096][C], LDS transpose.
// ---------------------------------------------------------------------------
template<int C>
__global__ __launch_bounds__(256) void to_chlast_bf16(
    const float* __restrict__ src, ushort* __restrict__ dst)
{
    const int b = blockIdx.z, c0 = blockIdx.y * 64, p0 = blockIdx.x * 64;
    const int tid = threadIdx.x;
    __shared__ float sT[64][65];
    for (int i = tid; i < 4096; i += 256) {
        const int ch = i >> 6, px = i & 63;
        sT[ch][px] = src[(size_t)(b * C + c0 + ch) * HW + p0 + px];
    }
    __syncthreads();
    const int px = tid >> 2, seg = tid & 3;
    ushort tmp[16];
    #pragma unroll
    for (int j = 0; j < 16; ++j) tmp[j] = f2bf(sT[seg * 16 + j][px]);
    ushort* d = dst + (size_t)(b * HW + p0 + px) * C + c0 + seg * 16;
    *(uint4*)d = *(uint4*)&tmp[0];
    *(uint4*)(d + 8) = *(uint4*)&tmp[8];
}

// ---------------------------------------------------------------------------
// Pack 3x3 weights [co][ci][3][3] fp32 -> [tap][ci/32][co][ci32] bf16.
// ---------------------------------------------------------------------------
template<int CIN, int COUT>
__global__ __launch_bounds__(256) void pack_w3x3(
    const float* __restrict__ w, ushort* __restrict__ wpk)
{
    const int idx = blockIdx.x * 256 + threadIdx.x;
    constexpr int total = 9 * (CIN / 32) * COUT * 32;
    if (idx >= total) return;
    const int ci_in = idx & 31;
    int rest = idx >> 5;
    const int co = rest % COUT; rest /= COUT;
    const int cc = rest % (CIN / 32);
    const int tap = rest / (CIN / 32);
    wpk[idx] = f2bf(w[((size_t)co * CIN + cc * 32 + ci_in) * 9 + tap]);
}

// ---------------------------------------------------------------------------
// Pack 1x1 weights [co][stride] fp32 -> [co][K] bf16 (first K columns).
// ---------------------------------------------------------------------------
__global__ __launch_bounds__(256) void pack_w1x1(
    const float* __restrict__ w, ushort* __restrict__ o,
    int K, int stride, int total)
{
    const int idx = blockIdx.x * 256 + threadIdx.x;
    if (idx >= total) return;
    const int co = idx / K, k = idx - co * K;
    o[idx] = f2bf(w[(size_t)co * stride + k]);
}

// ---------------------------------------------------------------------------
__global__ __launch_bounds__(256) void zero_pool(float* __restrict__ p)
{
    p[blockIdx.x * 256 + threadIdx.x] = 0.f;
}

// ---------------------------------------------------------------------------
// MFMA implicit-GEMM 3x3 conv, FULL-K, fused BN+PReLU epilogue.
// r8: staging issues ALL global loads first (scoped arrays, dead before the
// MFMA tap loop -> no spill pressure during compute, unlike r5's cross-loop
// buffers), then writes LDS: memory-level parallelism on the ~250cyc L2
// latencies that sit on the phase-locked critical path.
//   - full-K (no fp32 partial chain);
//   - weights in LDS fragment-major (lane-linear ds_read, 0 conflicts);
//   - OMODE 0 (dc): BN+PReLU -> bf16 channel-last + pool atomicAdd;
//   - OMODE 1 (c2): BN+PReLU -> fp32 ch-first.
// dc: COTILE=32, ROWS=2 -> grid (32,8,4)=1024, 4 blocks/CU (~39 KB LDS).
// c2: COTILE=32, ROWS=2, DIL=2 -> grid (32,4,4)=512 (~51 KB LDS).
// ---------------------------------------------------------------------------
template<int CIN, int COUT, int COTILE, int DIL, int ROWS, int OMODE>
__global__ __launch_bounds__(256, OMODE == 0 ? 4 : 2) void conv3x3_fused(
    const ushort* __restrict__ xin,   // [b][64][64][CIN] bf16
    const ushort* __restrict__ wpk,   // [9][CIN/32][COUT][32] bf16
    const float* __restrict__ bias, const float* __restrict__ bng,
    const float* __restrict__ bnb, const float* __restrict__ bnm,
    const float* __restrict__ bnv, const float* __restrict__ al,
    void* __restrict__ outv,
    float* __restrict__ pool)         // [4][256] sums (OMODE 0 only)
{
    constexpr int HR = ROWS + 2 * DIL;
    constexpr int NC = 64 + 2 * DIL;
    constexpr int MT = COTILE / 16;
    constexpr int WPR = 4 / ROWS;
    constexpr int NT = ROWS;
    constexpr int SAS = 40;
    constexpr int CH = CIN / 32;
    constexpr int NA = HR * NC * 4;
    constexpr int NREG = (NA + 255) / 256;
    constexpr int WCH = 9 * MT * 64;
    constexpr int WPT = (WCH + 255) / 256;

    const int tid = threadIdx.x;
    const int wave = tid >> 6, lane = tid & 63;
    const int l15 = lane & 15, quad = lane >> 4;
    const int b = blockIdx.z;
    const int cob = blockIdx.y;
    const int co0 = cob * COTILE;
    const int h0 = blockIdx.x * ROWS;
    const int row = wave / WPR;
    const int ntbase = (wave % WPR) * NT;

    __shared__ __align__(16) ushort sA[HR * NC * SAS];
    __shared__ __align__(16) ushort sW[WCH * 8];

    f32x4 acc[MT][NT];
    #pragma unroll
    for (int mt = 0; mt < MT; ++mt)
        #pragma unroll
        for (int nt = 0; nt < NT; ++nt) acc[mt][nt] = (f32x4){0.f, 0.f, 0.f, 0.f};

    #pragma unroll 1
    for (int cc = 0; cc < CH; ++cc) {
        if (cc != 0) __syncthreads();       // prev-cc LDS reads done
        {
            // ---- issue ALL staged loads first (MLP), then write LDS.
            // Arrays are dead before the tap loop -> no spill during MFMA.
            uint4 xr[NREG];
            #pragma unroll
            for (int k = 0; k < NREG; ++k) {
                const int i = tid + k * 256;
                uint4 val = {0u, 0u, 0u, 0u};
                if (i < NA) {
                    const int p = i >> 2, seg = i & 3;
                    const int r = p / NC, c = p - r * NC;
                    const int grow = h0 - DIL + r, gcol = c - DIL;
                    if (grow >= 0 && grow < 64 && gcol >= 0 && gcol < 64)
                        val = *(const uint4*)&xin[((size_t)(b * 64 + grow) * 64 + gcol) * CIN
                                                  + cc * 32 + seg * 8];
                }
                xr[k] = val;
            }
            uint4 wr_[WPT];
            #pragma unroll
            for (int k = 0; k < WPT; ++k) {
                const int i = tid + k * 256;
                if (i < WCH) {
                    const int tap = i / (MT * 64);
                    const int r = i - tap * (MT * 64);
                    const int mt = r >> 6, n = r & 63;
                    wr_[k] = *(const uint4*)&wpk[
                        ((size_t)(tap * (CIN / 32) + cc) * COUT + co0 + mt * 16 + (n & 15)) * 32
                        + (n >> 4) * 8];
                }
            }
            #pragma unroll
            for (int k = 0; k < NREG; ++k) {
                const int i = tid + k * 256;
                if (i < NA) *(uint4*)&sA[(i >> 2) * SAS + (i & 3) * 8] = xr[k];
            }
            #pragma unroll
            for (int k = 0; k < WPT; ++k) {
                const int i = tid + k * 256;
                if (i < WCH) *(uint4*)&sW[i * 8] = wr_[k];
            }
        }
        __syncthreads();

        // ---- 9-tap MFMA loop, both operands from LDS
        #pragma unroll
        for (int tap = 0; tap < 9; ++tap) {
            const int ty = tap / 3, tx = tap - ty * 3;
            const int rl = row + ty * DIL;
            bf16x8 wf[MT];
            #pragma unroll
            for (int mt = 0; mt < MT; ++mt)
                wf[mt] = *(const bf16x8*)&sW[((tap * MT + mt) * 64 + lane) * 8];
            #pragma unroll
            for (int nt = 0; nt < NT; ++nt) {
                const int cl = (ntbase + nt) * 16 + l15 + tx * DIL;
                const bf16x8 bp = *(const bf16x8*)&sA[(rl * NC + cl) * SAS + quad * 8];
                #pragma unroll
                for (int mt = 0; mt < MT; ++mt)
                    acc[mt][nt] = __builtin_amdgcn_mfma_f32_16x16x32_bf16(
                        wf[mt], bp, acc[mt][nt], 0, 0, 0);
            }
        }
    }

    const float a = al[0];

    if constexpr (OMODE == 0) {
        // BN+PReLU -> bf16 channel-last via LDS transpose, + pool atomics.
        __syncthreads();                 // done reading sA/sW
        ushort* sT = sA;                 // reuse: [row*64+px][40] (co-padded)
        #pragma unroll
        for (int mt = 0; mt < MT; ++mt) {
            float sc[4], sh[4], psum[4];
            #pragma unroll
            for (int rr = 0; rr < 4; ++rr) {
                const int co = co0 + mt * 16 + quad * 4 + rr;
                sc[rr] = bng[co] * rsqrtf(bnv[co] + EPSV);
                sh[rr] = (bias[co] - bnm[co]) * sc[rr] + bnb[co];
                psum[rr] = 0.f;
            }
            #pragma unroll
            for (int nt = 0; nt < NT; ++nt) {
                float tv[4];
                #pragma unroll
                for (int rr = 0; rr < 4; ++rr) {
                    float t = acc[mt][nt][rr] * sc[rr] + sh[rr];
                    t = t >= 0.f ? t : a * t;
                    tv[rr] = t;
                    psum[rr] += t;
                }
                ushort4 u;
                u.x = f2bf(tv[0]); u.y = f2bf(tv[1]);
                u.z = f2bf(tv[2]); u.w = f2bf(tv[3]);
                const int px = (ntbase + nt) * 16 + l15;
                *(ushort4*)&sT[(row * 64 + px) * 40 + mt * 16 + quad * 4] = u;
            }
            #pragma unroll
            for (int rr = 0; rr < 4; ++rr) {
                float v = psum[rr];
                v += __shfl_xor(v, 1);
                v += __shfl_xor(v, 2);
                v += __shfl_xor(v, 4);
                v += __shfl_xor(v, 8);
                if (l15 == 0)
                    atomicAdd(&pool[b * 256 + co0 + mt * 16 + quad * 4 + rr], v);
            }
        }
        __syncthreads();
        ushort* dst = (ushort*)outv;
        const int p = tid >> 1, half = tid & 1;   // p = row*64+px (0..127)
        const uint4 v0 = *(const uint4*)&sT[p * 40 + half * 16];
        const uint4 v1 = *(const uint4*)&sT[p * 40 + half * 16 + 8];
        const size_t off = ((size_t)(b * 4096 + (h0 + (p >> 6)) * 64 + (p & 63))) * 256
                           + co0 + half * 16;
        *(uint4*)&dst[off] = v0;
        *(uint4*)&dst[off + 8] = v1;
    } else {
        // BN+PReLU -> fp32 channel-first (c2b layout).
        float* out = (float*)outv;
        #pragma unroll
        for (int mt = 0; mt < MT; ++mt)
            #pragma unroll
            for (int rr = 0; rr < 4; ++rr) {
                const int co = co0 + mt * 16 + quad * 4 + rr;
                const float sc = bng[co] * rsqrtf(bnv[co] + EPSV);
                const float sh = (bias[co] - bnm[co]) * sc + bnb[co];
                #pragma unroll
                for (int nt = 0; nt < NT; ++nt) {
                    float t = acc[mt][nt][rr] * sc + sh;
                    t = t >= 0.f ? t : a * t;
                    out[((size_t)(b * COUT + co) * 64 + h0 + row) * 64
                        + (ntbase + nt) * 16 + l15] = t;
                }
            }
    }
}

// ---------------------------------------------------------------------------
// MFMA 1x1 conv on channel-last bf16 input, frags straight from global.
// ---------------------------------------------------------------------------
template<int CIN, int COUT, bool BNACT, int OMODE>
__global__ __launch_bounds__(256) void gemm1x1_cl(
    const ushort* __restrict__ xin,   // [16384][CIN] bf16
    const ushort* __restrict__ wbf,   // [COUT][CIN] bf16
    const float* __restrict__ bias, const float* __restrict__ bng,
    const float* __restrict__ bnb, const float* __restrict__ bnm,
    const float* __restrict__ bnv, const float* __restrict__ al,
    const float* __restrict__ ebias, void* __restrict__ outv,
    int ostride, int ocol)
{
    const int tid = threadIdx.x;
    const int wave = tid >> 6, lane = tid & 63;
    const int l15 = lane & 15, quad = lane >> 4;
    const int pix0 = blockIdx.x * 128 + wave * 32;
    const int co0 = blockIdx.y * 64;

    f32x4 acc[4][2];
    #pragma unroll
    for (int mt = 0; mt < 4; ++mt)
        #pragma unroll
        for (int nt = 0; nt < 2; ++nt) acc[mt][nt] = (f32x4){0.f, 0.f, 0.f, 0.f};

    #pragma unroll 2
    for (int cc = 0; cc < CIN / 32; ++cc) {
        bf16x8 aw[4], bp[2];
        #pragma unroll
        for (int mt = 0; mt < 4; ++mt)
            aw[mt] = *(const bf16x8*)&wbf[(size_t)(co0 + mt * 16 + l15) * CIN + cc * 32 + quad * 8];
        #pragma unroll
        for (int nt = 0; nt < 2; ++nt)
            bp[nt] = *(const bf16x8*)&xin[(size_t)(pix0 + nt * 16 + l15) * CIN + cc * 32 + quad * 8];
        #pragma unroll
        for (int mt = 0; mt < 4; ++mt)
            #pragma unroll
            for (int nt = 0; nt < 2; ++nt)
                acc[mt][nt] = __builtin_amdgcn_mfma_f32_16x16x32_bf16(
                    aw[mt], bp[nt], acc[mt][nt], 0, 0, 0);
    }

    const int bI = pix0 >> 12;
    const float a = BNACT ? al[0] : 0.f;

    if (OMODE == 0) {
        float* out = (float*)outv;
        #pragma unroll
        for (int mt = 0; mt < 4; ++mt)
            #pragma unroll
            for (int r = 0; r < 4; ++r) {
                const int co = co0 + mt * 16 + quad * 4 + r;
                float bb = bias[co];
                if (ebias) bb += ebias[bI * COUT + co];
                float scale = 1.f, shift = bb;
                if (BNACT) {
                    scale = bng[co] * rsqrtf(bnv[co] + EPSV);
                    shift = bb * scale + (bnb[co] - bnm[co] * scale);
                }
                #pragma unroll
                for (int nt = 0; nt < 2; ++nt) {
                    float t = acc[mt][nt][r] * scale + shift;
                    if (BNACT) t = t >= 0.f ? t : a * t;
                    out[((size_t)(bI * COUT + co)) * HW + (pix0 & 4095) + nt * 16 + l15] = t;
                }
            }
    } else {
        __shared__ ushort sT[4][32][68];
        #pragma unroll
        for (int mt = 0; mt < 4; ++mt)
            #pragma unroll
            for (int r = 0; r < 4; ++r) {
                const int co = co0 + mt * 16 + quad * 4 + r;
                float bb = bias[co];
                float scale = 1.f, shift = bb;
                if (BNACT) {
                    scale = bng[co] * rsqrtf(bnv[co] + EPSV);
                    shift = bb * scale + (bnb[co] - bnm[co] * scale);
                }
                #pragma unroll
                for (int nt = 0; nt < 2; ++nt) {
                    float t = acc[mt][nt][r] * scale + shift;
                    if (BNACT) t = t >= 0.f ? t : a * t;
                    sT[wave][nt * 16 + l15][mt * 16 + quad * 4 + r] = f2bf(t);
                }
            }
        __syncthreads();
        const int p = lane >> 1, half = lane & 1;
        ushort* out = (ushort*)outv;
        #pragma unroll
        for (int seg = 0; seg < 4; ++seg) {
            uint2 a0 = *(uint2*)&sT[wave][p][half * 32 + seg * 8];
            uint2 a1 = *(uint2*)&sT[wave][p][half * 32 + seg * 8 + 4];
            uint4 vv = {a0.x, a0.y, a1.x, a1.y};
            *(uint4*)&out[(size_t)(pix0 + p) * ostride + ocol + co0 + half * 32 + seg * 8] = vv;
        }
    }
}

// ---------------------------------------------------------------------------
// Generic fp32 1x1 conv (kept for v).  OUTBF16: write bf16.
// ---------------------------------------------------------------------------
template<int CIN, bool BNACT, bool OUTBF16>
__global__ __launch_bounds__(256) void conv1x1_kernel(
    const float* __restrict__ in0,
    const float* __restrict__ wgt, int wstride, int COUT,
    const float* __restrict__ bias, const float* __restrict__ al,
    void* __restrict__ outv)
{
    const int tid = threadIdx.x;
    const int b = blockIdx.z, co0 = blockIdx.y * 64, p0 = blockIdx.x * 64;
    const int cg = tid >> 4, pg = tid & 15;
    const int c0l = cg * 4, w0 = pg * 4;

    __shared__ __align__(16) float sIn[16 * 64];
    __shared__ __align__(16) float sW[16 * 68];

    float acc[4][4] = {};

    for (int cc = 0; cc < CIN; cc += 16) {
        {
            int i = tid;
            #pragma unroll
            for (int it = 0; it < 4; ++it, i += 256) {
                const int px = i & 63, ci = i >> 6;
                sIn[ci * 64 + px] = in0[(size_t)(b * CIN + cc + ci) * HW + p0 + px];
            }
            i = tid;
            #pragma unroll
            for (int it = 0; it < 4; ++it, i += 256) {
                const int ci = i & 15, co = i >> 4;
                sW[ci * 68 + co] = wgt[(co0 + co) * wstride + cc + ci];
            }
        }
        __syncthreads();
        #pragma unroll
        for (int ci = 0; ci < 16; ++ci) {
            const float4 iv = *(const float4*)&sIn[ci * 64 + w0];
            const float4 wv = *(const float4*)&sW[ci * 68 + c0l];
            const float ia[4] = {iv.x, iv.y, iv.z, iv.w};
            const float wa[4] = {wv.x, wv.y, wv.z, wv.w};
            #pragma unroll
            for (int i2 = 0; i2 < 4; ++i2)
                #pragma unroll
                for (int j = 0; j < 4; ++j)
                    acc[i2][j] = fmaf(wa[i2], ia[j], acc[i2][j]);
        }
        __syncthreads();
    }

    const float a = BNACT ? al[0] : 0.f;
    #pragma unroll
    for (int i2 = 0; i2 < 4; ++i2) {
        const int co = co0 + c0l + i2;
        const float shift = bias[co];
        float r[4];
        #pragma unroll
        for (int j = 0; j < 4; ++j) {
            float t = acc[i2][j] + shift;
            r[j] = (BNACT && t < 0.f) ? a * t : t;
        }
        const size_t base = (size_t)(b * COUT + co) * HW + p0 + w0;
        if (OUTBF16) {
            ushort* out = (ushort*)outv;
            #pragma unroll
            for (int j = 0; j < 4; ++j) out[base + j] = f2bf(r[j]);
        } else {
            float* out = (float*)outv;
            *(float4*)&out[base] = make_float4(r[0], r[1], r[2], r[3]);
        }
    }
}

// ---------------------------------------------------------------------------
// q & k 1x1 convs (128 -> 16 each) -> packed bf16 [b][4096][32]
// ---------------------------------------------------------------------------
__global__ __launch_bounds__(256) void qk_kernel(
    const float* __restrict__ c2g, const float* __restrict__ qw,
    const float* __restrict__ qb2, const float* __restrict__ kw,
    const float* __restrict__ kb2, ushort* __restrict__ qpack,
    ushort* __restrict__ kpack)
{
    const int b = blockIdx.y, p0 = blockIdx.x * 64, tid = threadIdx.x;
    __shared__ float sC[128][64];
    __shared__ float sWq[16][128];
    __shared__ float sWk[16][128];
    for (int i = tid; i < 8192; i += 256) {
        const int px = i & 63, ci = i >> 6;
        sC[ci][px] = c2g[(size_t)(b * 128 + ci) * HW + p0 + px];
    }
    for (int i = tid; i < 2048; i += 256) {
        const int ci = i & 127, co = i >> 7;
        sWq[co][ci] = qw[co * 128 + ci];
        sWk[co][ci] = kw[co * 128 + ci];
    }
    __syncthreads();
    const int px = tid & 63, grp = tid >> 6;
    const int co0 = (grp & 1) * 8;
    const bool isK = grp >= 2;
    const float* sWp = isK ? &sWk[0][0] : &sWq[0][0];
    float acc[8] = {};
    for (int ci = 0; ci < 128; ++ci) {
        const float xv = sC[ci][px];
        #pragma unroll
        for (int j = 0; j < 8; ++j)
            acc[j] = fmaf(sWp[(co0 + j) * 128 + ci], xv, acc[j]);
    }
    const float* bsrc = isK ? kb2 : qb2;
    ushort* osrc = isK ? kpack : qpack;
    const size_t base = (size_t)(b * 4096 + p0 + px) * 32;
    #pragma unroll
    for (int j = 0; j < 8; ++j) {
        osrc[base + co0 + j] = f2bf(acc[j] + bsrc[co0 + j]);
        osrc[base + 16 + co0 + j] = 0;
    }
}

// ---------------------------------------------------------------------------
// SINGLE-PASS flash attention (r8): online softmax with defer-max (T13).
// Pass-1 exact-max (64 of 384 MFMAs/wave + kpack re-read) eliminated.
// Per tile: tileM -> if __any(tileM > runM+8) rescale oacc/runS (rare).
// Rescale factor lives per-column (l15=n) but oacc is n=quad*4+r -> 8 shfls
// transpose it.  Mpart/Spart/opart semantics identical -> attn_combine
// unchanged.  Grid: (32 nblk, 8 msplit, 4 batch).
// ---------------------------------------------------------------------------
__global__ __launch_bounds__(256) void attn_flash(
    const ushort* __restrict__ qpack,
    const ushort* __restrict__ kpack,
    const ushort* __restrict__ vpackT,
    ushort* __restrict__ opart,       // [b][8j][4096n][128c] bf16
    float* __restrict__ Mpart,        // [b][8j][4096n]
    float* __restrict__ Spart)
{
    const int tid = threadIdx.x;
    const int wave = tid >> 6, lane = tid & 63;
    const int l15 = lane & 15, quad = lane >> 4;
    const int b = blockIdx.z, j = blockIdx.y;
    const int n0w = blockIdx.x * 128 + wave * 32;
    const int m_begin = j * 512;

    __shared__ __align__(16) ushort sV[2][128][40];
    __shared__ __align__(16) ushort sP[4][2][16][40];

    const bf16x8 bq0 = *(const bf16x8*)(qpack + ((size_t)(b * 4096 + n0w + l15) * 32 + quad * 8));
    const bf16x8 bq1 = *(const bf16x8*)(qpack + ((size_t)(b * 4096 + n0w + 16 + l15) * 32 + quad * 8));
    const f32x4 z = {0.f, 0.f, 0.f, 0.f};

    float runM0 = -3e30f, runM1 = -3e30f;
    float runS0 = 0.f, runS1 = 0.f;
    f32x4 oacc0[8], oacc1[8];
    #pragma unroll
    for (int cs = 0; cs < 8; ++cs) {
        oacc0[cs] = (f32x4){0.f, 0.f, 0.f, 0.f};
        oacc1[cs] = (f32x4){0.f, 0.f, 0.f, 0.f};
    }

    const int stc = tid >> 1, stseg = tid & 1;

    {
        uint4 v0 = *(const uint4*)&vpackT[(size_t)(b * 128 + stc) * HW + m_begin + stseg * 16];
        uint4 v1 = *(const uint4*)&vpackT[(size_t)(b * 128 + stc) * HW + m_begin + stseg * 16 + 8];
        *(uint4*)&sV[0][stc][stseg * 16] = v0;
        *(uint4*)&sV[0][stc][stseg * 16 + 8] = v1;
    }
    __syncthreads();

    #pragma unroll 1
    for (int t = 0; t < 16; ++t) {
        const int m0 = m_begin + t * 32;
        const int buf = t & 1;
        uint4 nv0, nv1;
        const bool more = (t + 1 < 16);
        if (more) {
            const size_t nb = (size_t)(b * 128 + stc) * HW + m0 + 32 + stseg * 16;
            nv0 = *(const uint4*)&vpackT[nb];
            nv1 = *(const uint4*)&vpackT[nb + 8];
        }
        f32x4 s0[2], s1[2];
        #pragma unroll
        for (int ms = 0; ms < 2; ++ms) {
            const bf16x8 ak = *(const bf16x8*)(
                kpack + ((size_t)(b * 4096 + m0 + ms * 16 + l15) * 32 + quad * 8));
            s0[ms] = __builtin_amdgcn_mfma_f32_16x16x32_bf16(ak, bq0, z, 0, 0, 0);
            s1[ms] = __builtin_amdgcn_mfma_f32_16x16x32_bf16(ak, bq1, z, 0, 0, 0);
        }

        // ---- online max update with defer (THR=8 -> P <= e^8, bf16-safe)
        float tM0 = fmaxf(fmaxf(fmaxf(s0[0][0], s0[0][1]), fmaxf(s0[0][2], s0[0][3])),
                          fmaxf(fmaxf(s0[1][0], s0[1][1]), fmaxf(s0[1][2], s0[1][3])));
        float tM1 = fmaxf(fmaxf(fmaxf(s1[0][0], s1[0][1]), fmaxf(s1[0][2], s1[0][3])),
                          fmaxf(fmaxf(s1[1][0], s1[1][1]), fmaxf(s1[1][2], s1[1][3])));
        tM0 = fmaxf(tM0, __shfl_xor(tM0, 16));
        tM0 = fmaxf(tM0, __shfl_xor(tM0, 32));
        tM1 = fmaxf(tM1, __shfl_xor(tM1, 16));
        tM1 = fmaxf(tM1, __shfl_xor(tM1, 32));
        if (__any(tM0 > runM0 + 8.f)) {
            const float nM = fmaxf(runM0, tM0);
            const float sc = __builtin_amdgcn_exp2f((runM0 - nM) * 1.44269504f);
            runS0 *= sc;
            float scr[4];
            #pragma unroll
            for (int r = 0; r < 4; ++r) scr[r] = __shfl(sc, quad * 4 + r);
            #pragma unroll
            for (int cs = 0; cs < 8; ++cs) {
                oacc0[cs][0] *= scr[0]; oacc0[cs][1] *= scr[1];
                oacc0[cs][2] *= scr[2]; oacc0[cs][3] *= scr[3];
            }
            runM0 = nM;
        }
        if (__any(tM1 > runM1 + 8.f)) {
            const float nM = fmaxf(runM1, tM1);
            const float sc = __builtin_amdgcn_exp2f((runM1 - nM) * 1.44269504f);
            runS1 *= sc;
            float scr[4];
            #pragma unroll
            for (int r = 0; r < 4; ++r) scr[r] = __shfl(sc, quad * 4 + r);
            #pragma unroll
            for (int cs = 0; cs < 8; ++cs) {
                oacc1[cs][0] *= scr[0]; oacc1[cs][1] *= scr[1];
                oacc1[cs][2] *= scr[2]; oacc1[cs][3] *= scr[3];
            }
            runM1 = nM;
        }
        const float Ms0 = runM0 * 1.44269504f;
        const float Ms1 = runM1 * 1.44269504f;

        #pragma unroll
        for (int ms = 0; ms < 2; ++ms) {
            float p0[4], p1[4];
            #pragma unroll
            for (int r = 0; r < 4; ++r) {
                p0[r] = __builtin_amdgcn_exp2f(fmaf(s0[ms][r], 1.44269504f, -Ms0));
                p1[r] = __builtin_amdgcn_exp2f(fmaf(s1[ms][r], 1.44269504f, -Ms1));
                runS0 += p0[r];
                runS1 += p1[r];
            }
            ushort4 u0, u1;
            u0.x = f2bf(p0[0]); u0.y = f2bf(p0[1]); u0.z = f2bf(p0[2]); u0.w = f2bf(p0[3]);
            u1.x = f2bf(p1[0]); u1.y = f2bf(p1[1]); u1.z = f2bf(p1[2]); u1.w = f2bf(p1[3]);
            *(uint2*)&sP[wave][0][l15][ms * 16 + quad * 4] = *(uint2*)&u0;
            *(uint2*)&sP[wave][1][l15][ms * 16 + quad * 4] = *(uint2*)&u1;
        }
        asm volatile("s_waitcnt lgkmcnt(0)" ::: "memory");
        const bf16x8 ap0 = *(const bf16x8*)&sP[wave][0][l15][quad * 8];
        const bf16x8 ap1 = *(const bf16x8*)&sP[wave][1][l15][quad * 8];
        #pragma unroll
        for (int cs = 0; cs < 8; ++cs) {
            const bf16x8 bv = *(const bf16x8*)&sV[buf][cs * 16 + l15][quad * 8];
            oacc0[cs] = __builtin_amdgcn_mfma_f32_16x16x32_bf16(ap0, bv, oacc0[cs], 0, 0, 0);
            oacc1[cs] = __builtin_amdgcn_mfma_f32_16x16x32_bf16(ap1, bv, oacc1[cs], 0, 0, 0);
        }
        if (more) {
            *(uint4*)&sV[buf ^ 1][stc][stseg * 16] = nv0;
            *(uint4*)&sV[buf ^ 1][stc][stseg * 16 + 8] = nv1;
            __syncthreads();
        }
    }

    runS0 += __shfl_xor(runS0, 16);
    runS0 += __shfl_xor(runS0, 32);
    runS1 += __shfl_xor(runS1, 16);
    runS1 += __shfl_xor(runS1, 32);
    if (lane < 32) {
        const float Mv = (lane < 16) ? runM0 : runM1;
        const float Sv = (lane < 16) ? runS0 : runS1;
        const int n = n0w + ((lane < 16) ? 0 : 16) + l15;
        Mpart[((size_t)b * 8 + j) * 4096 + n] = Mv;
        Spart[((size_t)b * 8 + j) * 4096 + n] = Sv;
    }
    #pragma unroll
    for (int cs = 0; cs < 8; ++cs)
        #pragma unroll
        for (int r = 0; r < 4; ++r) {
            const int n = n0w + quad * 4 + r;
            opart[(((size_t)b * 8 + j) * 4096 + n) * 128 + cs * 16 + l15] = f2bf(oacc0[cs][r]);
            opart[(((size_t)b * 8 + j) * 4096 + n + 16) * 128 + cs * 16 + l15] = f2bf(oacc1[cs][r]);
        }
}

// ---------------------------------------------------------------------------
// Combine 8 m-split partials, normalize, fuse gamma2*O + c2 -> catb[:,128:256]
// ---------------------------------------------------------------------------
__global__ __launch_bounds__(256) void attn_combine(
    const ushort* __restrict__ opart, const float* __restrict__ Mpart,
    const float* __restrict__ Spart, const float* __restrict__ c2g,
    const float* __restrict__ gamma2, ushort* __restrict__ catb)
{
    const int b = blockIdx.y, n0 = blockIdx.x * 32, tid = threadIdx.x;
    __shared__ float sC2[128][33];
    __shared__ float sWj[8][32];
    if (tid < 32) {
        const int n = n0 + tid;
        float Mj[8], Sj[8];
        #pragma unroll
        for (int j = 0; j < 8; ++j) {
            Mj[j] = Mpart[((size_t)b * 8 + j) * 4096 + n];
            Sj[j] = Spart[((size_t)b * 8 + j) * 4096 + n];
        }
        float M = -3e30f;
        #pragma unroll
        for (int j = 0; j < 8; ++j) M = fmaxf(M, Mj[j]);
        float St = 0.f, e[8];
        #pragma unroll
        for (int j = 0; j < 8; ++j) { e[j] = __expf(Mj[j] - M); St += Sj[j] * e[j]; }
        const float inv = 1.0f / St;
        #pragma unroll
        for (int j = 0; j < 8; ++j) sWj[j][tid] = e[j] * inv;
    }
    #pragma unroll
    for (int e = 0; e < 16; ++e) {
        const int idx = tid + e * 256;
        const int c = idx >> 5, n = idx & 31;
        sC2[c][n] = c2g[(size_t)(b * 128 + c) * HW + n0 + n];
    }
    __syncthreads();
    const float g2 = gamma2[0];
    #pragma unroll
    for (int e = 0; e < 16; ++e) {
        const int idx = tid + e * 256;
        const int n = idx >> 7, c = idx & 127;
        float s = 0.f;
        #pragma unroll
        for (int j = 0; j < 8; ++j)
            s += bf2f(opart[(((size_t)b * 8 + j) * 4096 + n0 + n) * 128 + c]) * sWj[j][n];
        catb[(size_t)(b * 4096 + n0 + n) * 256 + 128 + c] = f2bf(fmaf(g2, s, sC2[c][n]));
    }
}

// ---------------------------------------------------------------------------
// c3_fbias: pool holds raw sums (atomic-accumulated); scale by 1/4096.
// ---------------------------------------------------------------------------
__global__ __launch_bounds__(256) void c3_fbias_kernel(
    const float* __restrict__ pool, const float* __restrict__ c3w,
    const float* __restrict__ c3b, const float* __restrict__ bng,
    const float* __restrict__ bnb, const float* __restrict__ bnm,
    const float* __restrict__ bnv, const float* __restrict__ al,
    const float* __restrict__ fw, float* __restrict__ fbias)
{
    const int b = blockIdx.x, tid = threadIdx.x;
    __shared__ float sp[256];
    __shared__ float sc3[128];
    sp[tid] = pool[b * 256 + tid] * (1.0f / 4096.0f);
    __syncthreads();
    if (tid < 128) {
        float acc = c3b[tid];
        for (int ci = 0; ci < 256; ++ci) acc = fmaf(c3w[tid * 256 + ci], sp[ci], acc);
        const float scale = bng[tid] * rsqrtf(bnv[tid] + EPSV);
        float t = (acc - bnm[tid]) * scale + bnb[tid];
        const float a = al[0];
        sc3[tid] = t >= 0.f ? t : a * t;
    }
    __syncthreads();
    float f = 0.f;
    for (int j = 0; j < 128; ++j) f = fmaf(fw[tid * 384 + 256 + j], sc3[j], f);
    fbias[b * 256 + tid] = f;
}

// ---------------------------------------------------------------------------
extern "C" void kernel_launch(void* const* d_in, const int* in_sizes, int n_in,
                              void* d_out, int out_size, void* d_ws, size_t ws_size,
                              hipStream_t stream)
{
    const float* x     = (const float*)d_in[0];
    const float* dc_w  = (const float*)d_in[1];
    const float* dc_b  = (const float*)d_in[2];
    const float* dc_g  = (const float*)d_in[3];
    const float* dc_bt = (const float*)d_in[4];
    const float* dc_m  = (const float*)d_in[5];
    const float* dc_v  = (const float*)d_in[6];
    const float* dc_a  = (const float*)d_in[7];
    const float* c1_w  = (const float*)d_in[8];
    const float* c1_b  = (const float*)d_in[9];
    const float* c1_g  = (const float*)d_in[10];
    const float* c1_bt = (const float*)d_in[11];
    const float* c1_m  = (const float*)d_in[12];
    const float* c1_v  = (const float*)d_in[13];
    const float* c1_a  = (const float*)d_in[14];
    const float* c2_w  = (const float*)d_in[15];
    const float* c2_b  = (const float*)d_in[16];
    const float* c2_g  = (const float*)d_in[17];
    const float* c2_bt = (const float*)d_in[18];
    const float* c2_m  = (const float*)d_in[19];
    const float* c2_v  = (const float*)d_in[20];
    const float* c2_a  = (const float*)d_in[21];
    const float* q_w   = (const float*)d_in[22];
    const float* q_b   = (const float*)d_in[23];
    const float* k_w   = (const float*)d_in[24];
    const float* k_b   = (const float*)d_in[25];
    const float* v_w   = (const float*)d_in[26];
    const float* v_b   = (const float*)d_in[27];
    const float* gamma2= (const float*)d_in[28];
    const float* c3_w  = (const float*)d_in[29];
    const float* c3_b  = (const float*)d_in[30];
    const float* c3_g  = (const float*)d_in[31];
    const float* c3_bt = (const float*)d_in[32];
    const float* c3_m  = (const float*)d_in[33];
    const float* c3_v  = (const float*)d_in[34];
    const float* c3_a  = (const float*)d_in[35];
    const float* f_w   = (const float*)d_in[36];
    const float* f_b   = (const float*)d_in[37];
    const float* f_g   = (const float*)d_in[38];
    const float* f_bt  = (const float*)d_in[39];
    const float* f_m   = (const float*)d_in[40];
    const float* f_v   = (const float*)d_in[41];
    const float* f_a   = (const float*)d_in[42];

    // ---- workspace layout by live range (r5-verified, no aliasing) ----
    // opart  [0, 33554432)            live attn_flash..attn_combine
    // xbf    [0, 16777216)            live steps 0..1 (dead before attn)
    // qpk    [33554432, 34603008)
    // kpk    [34603008, 35651584)
    // vbh    [35651584, 39845888)
    // c2b    [39845888, 48234496)     live c2 conv..attn_combine
    // xpbf   [50331648, 58720256)     live dc..c2 conv
    // catb   [58720256, 75497472)
    // weights/pool/fb/M/S above 75497472
    char* base = (char*)d_ws;
    ushort* xbf   = (ushort*)base;                       // [4,4096,512] bf16
    ushort* opart = (ushort*)base;                       // [4,8,4096,128] bf16
    ushort* qpk   = (ushort*)(base + 33554432);          // [4,4096,32]
    ushort* kpk   = (ushort*)(base + 34603008);
    ushort* vbh   = (ushort*)(base + 35651584);          // [4,128,4096] bf16
    float*  c2b   = (float*)(base + 39845888);           // [4,128,4096] f32
    ushort* xpbf  = (ushort*)(base + 50331648);          // [4,4096,256] bf16
    ushort* catb  = (ushort*)(base + 58720256);          // [4,4096,256] bf16
    ushort* wdcp  = (ushort*)(base + 75497472);          // [9,16,256,32]
    ushort* wc2p  = (ushort*)(base + 77856768);          // [9,8,128,32]
    ushort* wc1b  = (ushort*)(base + 78446592);          // [128,256]
    ushort* wfb   = (ushort*)(base + 78512128);          // [256,256]
    float*  poolb = (float*)(base + 78643200);           // 1024 (atomic sums)
    float*  fbb   = (float*)(base + 78647296);           // 1024
    float*  Mpart = (float*)(base + 78651392);           // [4,8,4096]
    float*  Spart = (float*)(base + 79175680);           // [4,8,4096]

    // 0. packs + x -> channel-last bf16 + pool zero
    pack_w3x3<512, 256><<<dim3((9*16*256*32 + 255)/256), 256, 0, stream>>>(dc_w, wdcp);
    pack_w3x3<256, 128><<<dim3((9*8*128*32 + 255)/256), 256, 0, stream>>>(c2_w, wc2p);
    pack_w1x1<<<dim3((32768 + 255)/256), 256, 0, stream>>>(c1_w, wc1b, 256, 256, 32768);
    pack_w1x1<<<dim3((65536 + 255)/256), 256, 0, stream>>>(f_w, wfb, 256, 384, 65536);
    to_chlast_bf16<512><<<dim3(64, 8, 4), 256, 0, stream>>>(x, xbf);
    zero_pool<<<dim3(4), 256, 0, stream>>>(poolb);
    // 1. down_conv 3x3 512->256, full-K, fused BN+PReLU -> xpbf (ch-last bf16)
    //    + pool atomics.
    conv3x3_fused<512, 256, 32, 1, 2, 0><<<dim3(32, 8, 4), 256, 0, stream>>>(
        xbf, wdcp, dc_b, dc_g, dc_bt, dc_m, dc_v, dc_a, xpbf, poolb);
    // 2. c3 branch bias (reads pooled sums)
    c3_fbias_kernel<<<dim3(4), 256, 0, stream>>>(
        poolb, c3_w, c3_b, c3_g, c3_bt, c3_m, c3_v, c3_a, f_w, fbb);
    // 3. branch1 1x1 (MFMA) -> catb cols 0..127
    gemm1x1_cl<256, 128, true, 1><<<dim3(128, 2), 256, 0, stream>>>(
        xpbf, wc1b, c1_b, c1_g, c1_bt, c1_m, c1_v, c1_a, nullptr, catb, 256, 0);
    // 4. branch2 dilated 3x3, full-K, fused BN+PReLU -> c2b (ch-first f32).
    conv3x3_fused<256, 128, 32, 2, 2, 1><<<dim3(32, 4, 4), 256, 0, stream>>>(
        xpbf, wc2p, c2_b, c2_g, c2_bt, c2_m, c2_v, c2_a, c2b, nullptr);
    // 5. q,k
    qk_kernel<<<dim3(64, 4), 256, 0, stream>>>(c2b, q_w, q_b, k_w, k_b, qpk, kpk);
    // 6. v -> bf16 [c][m]
    conv1x1_kernel<128, false, true><<<dim3(64, 2, 4), 256, 0, stream>>>(
        c2b, v_w, 128, 128, v_b, nullptr, vbh);
    // 7. single-pass online flash attention + combine
    attn_flash<<<dim3(32, 8, 4), 256, 0, stream>>>(qpk, kpk, vbh, opart, Mpart, Spart);
    attn_combine<<<dim3(128, 4), 256, 0, stream>>>(opart, Mpart, Spart, c2b, gamma2, catb);
    // 8. fuse conv (MFMA, K=256) -> d_out
    gemm1x1_cl<256, 256, true, 0><<<dim3(128, 4), 256, 0, stream>>>(
        catb, wfb, f_b, f_g, f_bt, f_m, f_v, f_a, fbb, (float*)d_out, 0, 0);
}

// Round 9
// 412.894 us; speedup vs baseline: 1.1184x; 1.1184x over previous
//
#include <hip/hip_runtime.h>
#include <hip/hip_bf16.h>
#include <math.h>

#define HW 4096
#define EPSV 1e-5f

typedef unsigned short ushort;
typedef __attribute__((ext_vector_type(8))) short bf16x8;
typedef __attribute__((ext_vector_type(4))) float f32x4;

__device__ inline ushort f2bf(float f) {
    __hip_bfloat16 h = __float2bfloat16(f);
    return *reinterpret_cast<ushort*>(&h);
}
__device__ inline float bf2f(ushort u) {
    unsigned int v = ((unsigned int)u) << 16;
    return __uint_as_float(v);
}

// ---------------------------------------------------------------------------
// fp32 [b][C][4096] -> bf16 channel-last [b][4096][C], LDS transpose.
// ---------------------------------------------------------------------------
template<int C>
__global__ __launch_bounds__(256) void to_chlast_bf16(
    const float* __restrict__ src, ushort* __restrict__ dst)
{
    const int b = blockIdx.z, c0 = blockIdx.y * 64, p0 = blockIdx.x * 64;
    const int tid = threadIdx.x;
    __shared__ float sT[64][65];
    for (int i = tid; i < 4096; i += 256) {
        const int ch = i >> 6, px = i & 63;
        sT[ch][px] = src[(size_t)(b * C + c0 + ch) * HW + p0 + px];
    }
    __syncthreads();
    const int px = tid >> 2, seg = tid & 3;
    ushort tmp[16];
    #pragma unroll
    for (int j = 0; j < 16; ++j) tmp[j] = f2bf(sT[seg * 16 + j][px]);
    ushort* d = dst + (size_t)(b * HW + p0 + px) * C + c0 + seg * 16;
    *(uint4*)d = *(uint4*)&tmp[0];
    *(uint4*)(d + 8) = *(uint4*)&tmp[8];
}

// ---------------------------------------------------------------------------
// Pack 3x3 weights [co][ci][3][3] fp32 -> [tap][ci/32][co][ci32] bf16.
// ---------------------------------------------------------------------------
template<int CIN, int COUT>
__global__ __launch_bounds__(256) void pack_w3x3(
    const float* __restrict__ w, ushort* __restrict__ wpk)
{
    const int idx = blockIdx.x * 256 + threadIdx.x;
    constexpr int total = 9 * (CIN / 32) * COUT * 32;
    if (idx >= total) return;
    const int ci_in = idx & 31;
    int rest = idx >> 5;
    const int co = rest % COUT; rest /= COUT;
    const int cc = rest % (CIN / 32);
    const int tap = rest / (CIN / 32);
    wpk[idx] = f2bf(w[((size_t)co * CIN + cc * 32 + ci_in) * 9 + tap]);
}

// ---------------------------------------------------------------------------
// Pack 1x1 weights [co][stride] fp32 -> [co][K] bf16 (first K columns).
// ---------------------------------------------------------------------------
__global__ __launch_bounds__(256) void pack_w1x1(
    const float* __restrict__ w, ushort* __restrict__ o,
    int K, int stride, int total)
{
    const int idx = blockIdx.x * 256 + threadIdx.x;
    if (idx >= total) return;
    const int co = idx / K, k = idx - co * K;
    o[idx] = f2bf(w[(size_t)co * stride + k]);
}

// ---------------------------------------------------------------------------
__global__ __launch_bounds__(256) void zero_pool(float* __restrict__ p)
{
    p[blockIdx.x * 256 + threadIdx.x] = 0.f;
}

// ---------------------------------------------------------------------------
// MFMA implicit-GEMM 3x3 conv, FULL-K, fused BN+PReLU epilogue.
// r9 = EXACT r7 staging (load -> immediate ds_write, short-lived registers).
// COMPILER FACT (r5, r8, twice-confirmed): any staging array whose elements
// are all live simultaneously gets spilled to scratch (WRITE_SIZE 278-288 MB,
// dur 126us) even when the nominal VGPR budget fits; only load->immediate-
// consume staging stays in registers (WRITE 10 MB, dur 81us, VGPR 52).
// Do NOT reintroduce register-batched staging here.
//   - full-K (no fp32 partial chain);
//   - weights in LDS fragment-major (lane-linear ds_read, 0 conflicts);
//   - OMODE 0 (dc): BN+PReLU -> bf16 channel-last + pool atomicAdd;
//   - OMODE 1 (c2): BN+PReLU -> fp32 ch-first.
// dc: COTILE=32, ROWS=2 -> grid (32,8,4)=1024, 4 blocks/CU (~39 KB LDS).
// c2: COTILE=32, ROWS=2, DIL=2 -> grid (32,4,4)=512 (~51 KB LDS).
// ---------------------------------------------------------------------------
template<int CIN, int COUT, int COTILE, int DIL, int ROWS, int OMODE>
__global__ __launch_bounds__(256, OMODE == 0 ? 4 : 2) void conv3x3_fused(
    const ushort* __restrict__ xin,   // [b][64][64][CIN] bf16
    const ushort* __restrict__ wpk,   // [9][CIN/32][COUT][32] bf16
    const float* __restrict__ bias, const float* __restrict__ bng,
    const float* __restrict__ bnb, const float* __restrict__ bnm,
    const float* __restrict__ bnv, const float* __restrict__ al,
    void* __restrict__ outv,
    float* __restrict__ pool)         // [4][256] sums (OMODE 0 only)
{
    constexpr int HR = ROWS + 2 * DIL;
    constexpr int NC = 64 + 2 * DIL;
    constexpr int MT = COTILE / 16;
    constexpr int WPR = 4 / ROWS;
    constexpr int NT = ROWS;
    constexpr int SAS = 40;
    constexpr int CH = CIN / 32;
    constexpr int NA = HR * NC * 4;
    constexpr int NREG = (NA + 255) / 256;
    constexpr int WCH = 9 * MT * 64;
    constexpr int WPT = (WCH + 255) / 256;

    const int tid = threadIdx.x;
    const int wave = tid >> 6, lane = tid & 63;
    const int l15 = lane & 15, quad = lane >> 4;
    const int b = blockIdx.z;
    const int cob = blockIdx.y;
    const int co0 = cob * COTILE;
    const int h0 = blockIdx.x * ROWS;
    const int row = wave / WPR;
    const int ntbase = (wave % WPR) * NT;

    __shared__ __align__(16) ushort sA[HR * NC * SAS];
    __shared__ __align__(16) ushort sW[WCH * 8];

    f32x4 acc[MT][NT];
    #pragma unroll
    for (int mt = 0; mt < MT; ++mt)
        #pragma unroll
        for (int nt = 0; nt < NT; ++nt) acc[mt][nt] = (f32x4){0.f, 0.f, 0.f, 0.f};

    #pragma unroll 1
    for (int cc = 0; cc < CH; ++cc) {
        if (cc != 0) __syncthreads();       // prev-cc LDS reads done
        // ---- stage input tile: load -> immediate ds_write (no live arrays)
        #pragma unroll
        for (int k = 0; k < NREG; ++k) {
            const int i = tid + k * 256;
            if (i < NA) {
                const int p = i >> 2, seg = i & 3;
                const int r = p / NC, c = p - r * NC;
                const int grow = h0 - DIL + r, gcol = c - DIL;
                uint4 val = {0u, 0u, 0u, 0u};
                if (grow >= 0 && grow < 64 && gcol >= 0 && gcol < 64)
                    val = *(const uint4*)&xin[((size_t)(b * 64 + grow) * 64 + gcol) * CIN
                                              + cc * 32 + seg * 8];
                *(uint4*)&sA[p * SAS + seg * 8] = val;
            }
        }
        // ---- stage weight slice (fragment-major, lane-linear)
        #pragma unroll
        for (int k = 0; k < WPT; ++k) {
            const int i = tid + k * 256;
            if (i < WCH) {
                const int tap = i / (MT * 64);
                const int r = i - tap * (MT * 64);
                const int mt = r >> 6, n = r & 63;
                const uint4 wv = *(const uint4*)&wpk[
                    ((size_t)(tap * (CIN / 32) + cc) * COUT + co0 + mt * 16 + (n & 15)) * 32
                    + (n >> 4) * 8];
                *(uint4*)&sW[i * 8] = wv;
            }
        }
        __syncthreads();

        // ---- 9-tap MFMA loop, both operands from LDS
        #pragma unroll
        for (int tap = 0; tap < 9; ++tap) {
            const int ty = tap / 3, tx = tap - ty * 3;
            const int rl = row + ty * DIL;
            bf16x8 wf[MT];
            #pragma unroll
            for (int mt = 0; mt < MT; ++mt)
                wf[mt] = *(const bf16x8*)&sW[((tap * MT + mt) * 64 + lane) * 8];
            #pragma unroll
            for (int nt = 0; nt < NT; ++nt) {
                const int cl = (ntbase + nt) * 16 + l15 + tx * DIL;
                const bf16x8 bp = *(const bf16x8*)&sA[(rl * NC + cl) * SAS + quad * 8];
                #pragma unroll
                for (int mt = 0; mt < MT; ++mt)
                    acc[mt][nt] = __builtin_amdgcn_mfma_f32_16x16x32_bf16(
                        wf[mt], bp, acc[mt][nt], 0, 0, 0);
            }
        }
    }

    const float a = al[0];

    if constexpr (OMODE == 0) {
        // BN+PReLU -> bf16 channel-last via LDS transpose, + pool atomics.
        __syncthreads();                 // done reading sA/sW
        ushort* sT = sA;                 // reuse: [row*64+px][40] (co-padded)
        #pragma unroll
        for (int mt = 0; mt < MT; ++mt) {
            float sc[4], sh[4], psum[4];
            #pragma unroll
            for (int rr = 0; rr < 4; ++rr) {
                const int co = co0 + mt * 16 + quad * 4 + rr;
                sc[rr] = bng[co] * rsqrtf(bnv[co] + EPSV);
                sh[rr] = (bias[co] - bnm[co]) * sc[rr] + bnb[co];
                psum[rr] = 0.f;
            }
            #pragma unroll
            for (int nt = 0; nt < NT; ++nt) {
                float tv[4];
                #pragma unroll
                for (int rr = 0; rr < 4; ++rr) {
                    float t = acc[mt][nt][rr] * sc[rr] + sh[rr];
                    t = t >= 0.f ? t : a * t;
                    tv[rr] = t;
                    psum[rr] += t;
                }
                ushort4 u;
                u.x = f2bf(tv[0]); u.y = f2bf(tv[1]);
                u.z = f2bf(tv[2]); u.w = f2bf(tv[3]);
                const int px = (ntbase + nt) * 16 + l15;
                *(ushort4*)&sT[(row * 64 + px) * 40 + mt * 16 + quad * 4] = u;
            }
            #pragma unroll
            for (int rr = 0; rr < 4; ++rr) {
                float v = psum[rr];
                v += __shfl_xor(v, 1);
                v += __shfl_xor(v, 2);
                v += __shfl_xor(v, 4);
                v += __shfl_xor(v, 8);
                if (l15 == 0)
                    atomicAdd(&pool[b * 256 + co0 + mt * 16 + quad * 4 + rr], v);
            }
        }
        __syncthreads();
        ushort* dst = (ushort*)outv;
        const int p = tid >> 1, half = tid & 1;   // p = row*64+px (0..127)
        const uint4 v0 = *(const uint4*)&sT[p * 40 + half * 16];
        const uint4 v1 = *(const uint4*)&sT[p * 40 + half * 16 + 8];
        const size_t off = ((size_t)(b * 4096 + (h0 + (p >> 6)) * 64 + (p & 63))) * 256
                           + co0 + half * 16;
        *(uint4*)&dst[off] = v0;
        *(uint4*)&dst[off + 8] = v1;
    } else {
        // BN+PReLU -> fp32 channel-first (c2b layout).
        float* out = (float*)outv;
        #pragma unroll
        for (int mt = 0; mt < MT; ++mt)
            #pragma unroll
            for (int rr = 0; rr < 4; ++rr) {
                const int co = co0 + mt * 16 + quad * 4 + rr;
                const float sc = bng[co] * rsqrtf(bnv[co] + EPSV);
                const float sh = (bias[co] - bnm[co]) * sc + bnb[co];
                #pragma unroll
                for (int nt = 0; nt < NT; ++nt) {
                    float t = acc[mt][nt][rr] * sc + sh;
                    t = t >= 0.f ? t : a * t;
                    out[((size_t)(b * COUT + co) * 64 + h0 + row) * 64
                        + (ntbase + nt) * 16 + l15] = t;
                }
            }
    }
}

// ---------------------------------------------------------------------------
// MFMA 1x1 conv on channel-last bf16 input, frags straight from global.
// ---------------------------------------------------------------------------
template<int CIN, int COUT, bool BNACT, int OMODE>
__global__ __launch_bounds__(256) void gemm1x1_cl(
    const ushort* __restrict__ xin,   // [16384][CIN] bf16
    const ushort* __restrict__ wbf,   // [COUT][CIN] bf16
    const float* __restrict__ bias, const float* __restrict__ bng,
    const float* __restrict__ bnb, const float* __restrict__ bnm,
    const float* __restrict__ bnv, const float* __restrict__ al,
    const float* __restrict__ ebias, void* __restrict__ outv,
    int ostride, int ocol)
{
    const int tid = threadIdx.x;
    const int wave = tid >> 6, lane = tid & 63;
    const int l15 = lane & 15, quad = lane >> 4;
    const int pix0 = blockIdx.x * 128 + wave * 32;
    const int co0 = blockIdx.y * 64;

    f32x4 acc[4][2];
    #pragma unroll
    for (int mt = 0; mt < 4; ++mt)
        #pragma unroll
        for (int nt = 0; nt < 2; ++nt) acc[mt][nt] = (f32x4){0.f, 0.f, 0.f, 0.f};

    #pragma unroll 2
    for (int cc = 0; cc < CIN / 32; ++cc) {
        bf16x8 aw[4], bp[2];
        #pragma unroll
        for (int mt = 0; mt < 4; ++mt)
            aw[mt] = *(const bf16x8*)&wbf[(size_t)(co0 + mt * 16 + l15) * CIN + cc * 32 + quad * 8];
        #pragma unroll
        for (int nt = 0; nt < 2; ++nt)
            bp[nt] = *(const bf16x8*)&xin[(size_t)(pix0 + nt * 16 + l15) * CIN + cc * 32 + quad * 8];
        #pragma unroll
        for (int mt = 0; mt < 4; ++mt)
            #pragma unroll
            for (int nt = 0; nt < 2; ++nt)
                acc[mt][nt] = __builtin_amdgcn_mfma_f32_16x16x32_bf16(
                    aw[mt], bp[nt], acc[mt][nt], 0, 0, 0);
    }

    const int bI = pix0 >> 12;
    const float a = BNACT ? al[0] : 0.f;

    if (OMODE == 0) {
        float* out = (float*)outv;
        #pragma unroll
        for (int mt = 0; mt < 4; ++mt)
            #pragma unroll
            for (int r = 0; r < 4; ++r) {
                const int co = co0 + mt * 16 + quad * 4 + r;
                float bb = bias[co];
                if (ebias) bb += ebias[bI * COUT + co];
                float scale = 1.f, shift = bb;
                if (BNACT) {
                    scale = bng[co] * rsqrtf(bnv[co] + EPSV);
                    shift = bb * scale + (bnb[co] - bnm[co] * scale);
                }
                #pragma unroll
                for (int nt = 0; nt < 2; ++nt) {
                    float t = acc[mt][nt][r] * scale + shift;
                    if (BNACT) t = t >= 0.f ? t : a * t;
                    out[((size_t)(bI * COUT + co)) * HW + (pix0 & 4095) + nt * 16 + l15] = t;
                }
            }
    } else {
        __shared__ ushort sT[4][32][68];
        #pragma unroll
        for (int mt = 0; mt < 4; ++mt)
            #pragma unroll
            for (int r = 0; r < 4; ++r) {
                const int co = co0 + mt * 16 + quad * 4 + r;
                float bb = bias[co];
                float scale = 1.f, shift = bb;
                if (BNACT) {
                    scale = bng[co] * rsqrtf(bnv[co] + EPSV);
                    shift = bb * scale + (bnb[co] - bnm[co] * scale);
                }
                #pragma unroll
                for (int nt = 0; nt < 2; ++nt) {
                    float t = acc[mt][nt][r] * scale + shift;
                    if (BNACT) t = t >= 0.f ? t : a * t;
                    sT[wave][nt * 16 + l15][mt * 16 + quad * 4 + r] = f2bf(t);
                }
            }
        __syncthreads();
        const int p = lane >> 1, half = lane & 1;
        ushort* out = (ushort*)outv;
        #pragma unroll
        for (int seg = 0; seg < 4; ++seg) {
            uint2 a0 = *(uint2*)&sT[wave][p][half * 32 + seg * 8];
            uint2 a1 = *(uint2*)&sT[wave][p][half * 32 + seg * 8 + 4];
            uint4 vv = {a0.x, a0.y, a1.x, a1.y};
            *(uint4*)&out[(size_t)(pix0 + p) * ostride + ocol + co0 + half * 32 + seg * 8] = vv;
        }
    }
}

// ---------------------------------------------------------------------------
// Generic fp32 1x1 conv (kept for v).  OUTBF16: write bf16.
// ---------------------------------------------------------------------------
template<int CIN, bool BNACT, bool OUTBF16>
__global__ __launch_bounds__(256) void conv1x1_kernel(
    const float* __restrict__ in0,
    const float* __restrict__ wgt, int wstride, int COUT,
    const float* __restrict__ bias, const float* __restrict__ al,
    void* __restrict__ outv)
{
    const int tid = threadIdx.x;
    const int b = blockIdx.z, co0 = blockIdx.y * 64, p0 = blockIdx.x * 64;
    const int cg = tid >> 4, pg = tid & 15;
    const int c0l = cg * 4, w0 = pg * 4;

    __shared__ __align__(16) float sIn[16 * 64];
    __shared__ __align__(16) float sW[16 * 68];

    float acc[4][4] = {};

    for (int cc = 0; cc < CIN; cc += 16) {
        {
            int i = tid;
            #pragma unroll
            for (int it = 0; it < 4; ++it, i += 256) {
                const int px = i & 63, ci = i >> 6;
                sIn[ci * 64 + px] = in0[(size_t)(b * CIN + cc + ci) * HW + p0 + px];
            }
            i = tid;
            #pragma unroll
            for (int it = 0; it < 4; ++it, i += 256) {
                const int ci = i & 15, co = i >> 4;
                sW[ci * 68 + co] = wgt[(co0 + co) * wstride + cc + ci];
            }
        }
        __syncthreads();
        #pragma unroll
        for (int ci = 0; ci < 16; ++ci) {
            const float4 iv = *(const float4*)&sIn[ci * 64 + w0];
            const float4 wv = *(const float4*)&sW[ci * 68 + c0l];
            const float ia[4] = {iv.x, iv.y, iv.z, iv.w};
            const float wa[4] = {wv.x, wv.y, wv.z, wv.w};
            #pragma unroll
            for (int i2 = 0; i2 < 4; ++i2)
                #pragma unroll
                for (int j = 0; j < 4; ++j)
                    acc[i2][j] = fmaf(wa[i2], ia[j], acc[i2][j]);
        }
        __syncthreads();
    }

    const float a = BNACT ? al[0] : 0.f;
    #pragma unroll
    for (int i2 = 0; i2 < 4; ++i2) {
        const int co = co0 + c0l + i2;
        const float shift = bias[co];
        float r[4];
        #pragma unroll
        for (int j = 0; j < 4; ++j) {
            float t = acc[i2][j] + shift;
            r[j] = (BNACT && t < 0.f) ? a * t : t;
        }
        const size_t base = (size_t)(b * COUT + co) * HW + p0 + w0;
        if (OUTBF16) {
            ushort* out = (ushort*)outv;
            #pragma unroll
            for (int j = 0; j < 4; ++j) out[base + j] = f2bf(r[j]);
        } else {
            float* out = (float*)outv;
            *(float4*)&out[base] = make_float4(r[0], r[1], r[2], r[3]);
        }
    }
}

// ---------------------------------------------------------------------------
// q & k 1x1 convs (128 -> 16 each) -> packed bf16 [b][4096][32]
// ---------------------------------------------------------------------------
__global__ __launch_bounds__(256) void qk_kernel(
    const float* __restrict__ c2g, const float* __restrict__ qw,
    const float* __restrict__ qb2, const float* __restrict__ kw,
    const float* __restrict__ kb2, ushort* __restrict__ qpack,
    ushort* __restrict__ kpack)
{
    const int b = blockIdx.y, p0 = blockIdx.x * 64, tid = threadIdx.x;
    __shared__ float sC[128][64];
    __shared__ float sWq[16][128];
    __shared__ float sWk[16][128];
    for (int i = tid; i < 8192; i += 256) {
        const int px = i & 63, ci = i >> 6;
        sC[ci][px] = c2g[(size_t)(b * 128 + ci) * HW + p0 + px];
    }
    for (int i = tid; i < 2048; i += 256) {
        const int ci = i & 127, co = i >> 7;
        sWq[co][ci] = qw[co * 128 + ci];
        sWk[co][ci] = kw[co * 128 + ci];
    }
    __syncthreads();
    const int px = tid & 63, grp = tid >> 6;
    const int co0 = (grp & 1) * 8;
    const bool isK = grp >= 2;
    const float* sWp = isK ? &sWk[0][0] : &sWq[0][0];
    float acc[8] = {};
    for (int ci = 0; ci < 128; ++ci) {
        const float xv = sC[ci][px];
        #pragma unroll
        for (int j = 0; j < 8; ++j)
            acc[j] = fmaf(sWp[(co0 + j) * 128 + ci], xv, acc[j]);
    }
    const float* bsrc = isK ? kb2 : qb2;
    ushort* osrc = isK ? kpack : qpack;
    const size_t base = (size_t)(b * 4096 + p0 + px) * 32;
    #pragma unroll
    for (int j = 0; j < 8; ++j) {
        osrc[base + co0 + j] = f2bf(acc[j] + bsrc[co0 + j]);
        osrc[base + 16 + co0 + j] = 0;
    }
}

// ---------------------------------------------------------------------------
// SINGLE-PASS flash attention (r8-verified): online softmax with defer-max.
// Mpart/Spart/opart semantics identical -> attn_combine unchanged.
// Grid: (32 nblk, 8 msplit, 4 batch).
// ---------------------------------------------------------------------------
__global__ __launch_bounds__(256) void attn_flash(
    const ushort* __restrict__ qpack,
    const ushort* __restrict__ kpack,
    const ushort* __restrict__ vpackT,
    ushort* __restrict__ opart,       // [b][8j][4096n][128c] bf16
    float* __restrict__ Mpart,        // [b][8j][4096n]
    float* __restrict__ Spart)
{
    const int tid = threadIdx.x;
    const int wave = tid >> 6, lane = tid & 63;
    const int l15 = lane & 15, quad = lane >> 4;
    const int b = blockIdx.z, j = blockIdx.y;
    const int n0w = blockIdx.x * 128 + wave * 32;
    const int m_begin = j * 512;

    __shared__ __align__(16) ushort sV[2][128][40];
    __shared__ __align__(16) ushort sP[4][2][16][40];

    const bf16x8 bq0 = *(const bf16x8*)(qpack + ((size_t)(b * 4096 + n0w + l15) * 32 + quad * 8));
    const bf16x8 bq1 = *(const bf16x8*)(qpack + ((size_t)(b * 4096 + n0w + 16 + l15) * 32 + quad * 8));
    const f32x4 z = {0.f, 0.f, 0.f, 0.f};

    float runM0 = -3e30f, runM1 = -3e30f;
    float runS0 = 0.f, runS1 = 0.f;
    f32x4 oacc0[8], oacc1[8];
    #pragma unroll
    for (int cs = 0; cs < 8; ++cs) {
        oacc0[cs] = (f32x4){0.f, 0.f, 0.f, 0.f};
        oacc1[cs] = (f32x4){0.f, 0.f, 0.f, 0.f};
    }

    const int stc = tid >> 1, stseg = tid & 1;

    {
        uint4 v0 = *(const uint4*)&vpackT[(size_t)(b * 128 + stc) * HW + m_begin + stseg * 16];
        uint4 v1 = *(const uint4*)&vpackT[(size_t)(b * 128 + stc) * HW + m_begin + stseg * 16 + 8];
        *(uint4*)&sV[0][stc][stseg * 16] = v0;
        *(uint4*)&sV[0][stc][stseg * 16 + 8] = v1;
    }
    __syncthreads();

    #pragma unroll 1
    for (int t = 0; t < 16; ++t) {
        const int m0 = m_begin + t * 32;
        const int buf = t & 1;
        uint4 nv0, nv1;
        const bool more = (t + 1 < 16);
        if (more) {
            const size_t nb = (size_t)(b * 128 + stc) * HW + m0 + 32 + stseg * 16;
            nv0 = *(const uint4*)&vpackT[nb];
            nv1 = *(const uint4*)&vpackT[nb + 8];
        }
        f32x4 s0[2], s1[2];
        #pragma unroll
        for (int ms = 0; ms < 2; ++ms) {
            const bf16x8 ak = *(const bf16x8*)(
                kpack + ((size_t)(b * 4096 + m0 + ms * 16 + l15) * 32 + quad * 8));
            s0[ms] = __builtin_amdgcn_mfma_f32_16x16x32_bf16(ak, bq0, z, 0, 0, 0);
            s1[ms] = __builtin_amdgcn_mfma_f32_16x16x32_bf16(ak, bq1, z, 0, 0, 0);
        }

        // ---- online max update with defer (THR=8 -> P <= e^8, bf16-safe)
        float tM0 = fmaxf(fmaxf(fmaxf(s0[0][0], s0[0][1]), fmaxf(s0[0][2], s0[0][3])),
                          fmaxf(fmaxf(s0[1][0], s0[1][1]), fmaxf(s0[1][2], s0[1][3])));
        float tM1 = fmaxf(fmaxf(fmaxf(s1[0][0], s1[0][1]), fmaxf(s1[0][2], s1[0][3])),
                          fmaxf(fmaxf(s1[1][0], s1[1][1]), fmaxf(s1[1][2], s1[1][3])));
        tM0 = fmaxf(tM0, __shfl_xor(tM0, 16));
        tM0 = fmaxf(tM0, __shfl_xor(tM0, 32));
        tM1 = fmaxf(tM1, __shfl_xor(tM1, 16));
        tM1 = fmaxf(tM1, __shfl_xor(tM1, 32));
        if (__any(tM0 > runM0 + 8.f)) {
            const float nM = fmaxf(runM0, tM0);
            const float sc = __builtin_amdgcn_exp2f((runM0 - nM) * 1.44269504f);
            runS0 *= sc;
            float scr[4];
            #pragma unroll
            for (int r = 0; r < 4; ++r) scr[r] = __shfl(sc, quad * 4 + r);
            #pragma unroll
            for (int cs = 0; cs < 8; ++cs) {
                oacc0[cs][0] *= scr[0]; oacc0[cs][1] *= scr[1];
                oacc0[cs][2] *= scr[2]; oacc0[cs][3] *= scr[3];
            }
            runM0 = nM;
        }
        if (__any(tM1 > runM1 + 8.f)) {
            const float nM = fmaxf(runM1, tM1);
            const float sc = __builtin_amdgcn_exp2f((runM1 - nM) * 1.44269504f);
            runS1 *= sc;
            float scr[4];
            #pragma unroll
            for (int r = 0; r < 4; ++r) scr[r] = __shfl(sc, quad * 4 + r);
            #pragma unroll
            for (int cs = 0; cs < 8; ++cs) {
                oacc1[cs][0] *= scr[0]; oacc1[cs][1] *= scr[1];
                oacc1[cs][2] *= scr[2]; oacc1[cs][3] *= scr[3];
            }
            runM1 = nM;
        }
        const float Ms0 = runM0 * 1.44269504f;
        const float Ms1 = runM1 * 1.44269504f;

        #pragma unroll
        for (int ms = 0; ms < 2; ++ms) {
            float p0[4], p1[4];
            #pragma unroll
            for (int r = 0; r < 4; ++r) {
                p0[r] = __builtin_amdgcn_exp2f(fmaf(s0[ms][r], 1.44269504f, -Ms0));
                p1[r] = __builtin_amdgcn_exp2f(fmaf(s1[ms][r], 1.44269504f, -Ms1));
                runS0 += p0[r];
                runS1 += p1[r];
            }
            ushort4 u0, u1;
            u0.x = f2bf(p0[0]); u0.y = f2bf(p0[1]); u0.z = f2bf(p0[2]); u0.w = f2bf(p0[3]);
            u1.x = f2bf(p1[0]); u1.y = f2bf(p1[1]); u1.z = f2bf(p1[2]); u1.w = f2bf(p1[3]);
            *(uint2*)&sP[wave][0][l15][ms * 16 + quad * 4] = *(uint2*)&u0;
            *(uint2*)&sP[wave][1][l15][ms * 16 + quad * 4] = *(uint2*)&u1;
        }
        asm volatile("s_waitcnt lgkmcnt(0)" ::: "memory");
        const bf16x8 ap0 = *(const bf16x8*)&sP[wave][0][l15][quad * 8];
        const bf16x8 ap1 = *(const bf16x8*)&sP[wave][1][l15][quad * 8];
        #pragma unroll
        for (int cs = 0; cs < 8; ++cs) {
            const bf16x8 bv = *(const bf16x8*)&sV[buf][cs * 16 + l15][quad * 8];
            oacc0[cs] = __builtin_amdgcn_mfma_f32_16x16x32_bf16(ap0, bv, oacc0[cs], 0, 0, 0);
            oacc1[cs] = __builtin_amdgcn_mfma_f32_16x16x32_bf16(ap1, bv, oacc1[cs], 0, 0, 0);
        }
        if (more) {
            *(uint4*)&sV[buf ^ 1][stc][stseg * 16] = nv0;
            *(uint4*)&sV[buf ^ 1][stc][stseg * 16 + 8] = nv1;
            __syncthreads();
        }
    }

    runS0 += __shfl_xor(runS0, 16);
    runS0 += __shfl_xor(runS0, 32);
    runS1 += __shfl_xor(runS1, 16);
    runS1 += __shfl_xor(runS1, 32);
    if (lane < 32) {
        const float Mv = (lane < 16) ? runM0 : runM1;
        const float Sv = (lane < 16) ? runS0 : runS1;
        const int n = n0w + ((lane < 16) ? 0 : 16) + l15;
        Mpart[((size_t)b * 8 + j) * 4096 + n] = Mv;
        Spart[((size_t)b * 8 + j) * 4096 + n] = Sv;
    }
    #pragma unroll
    for (int cs = 0; cs < 8; ++cs)
        #pragma unroll
        for (int r = 0; r < 4; ++r) {
            const int n = n0w + quad * 4 + r;
            opart[(((size_t)b * 8 + j) * 4096 + n) * 128 + cs * 16 + l15] = f2bf(oacc0[cs][r]);
            opart[(((size_t)b * 8 + j) * 4096 + n + 16) * 128 + cs * 16 + l15] = f2bf(oacc1[cs][r]);
        }
}

// ---------------------------------------------------------------------------
// Combine 8 m-split partials, normalize, fuse gamma2*O + c2 -> catb[:,128:256]
// ---------------------------------------------------------------------------
__global__ __launch_bounds__(256) void attn_combine(
    const ushort* __restrict__ opart, const float* __restrict__ Mpart,
    const float* __restrict__ Spart, const float* __restrict__ c2g,
    const float* __restrict__ gamma2, ushort* __restrict__ catb)
{
    const int b = blockIdx.y, n0 = blockIdx.x * 32, tid = threadIdx.x;
    __shared__ float sC2[128][33];
    __shared__ float sWj[8][32];
    if (tid < 32) {
        const int n = n0 + tid;
        float Mj[8], Sj[8];
        #pragma unroll
        for (int j = 0; j < 8; ++j) {
            Mj[j] = Mpart[((size_t)b * 8 + j) * 4096 + n];
            Sj[j] = Spart[((size_t)b * 8 + j) * 4096 + n];
        }
        float M = -3e30f;
        #pragma unroll
        for (int j = 0; j < 8; ++j) M = fmaxf(M, Mj[j]);
        float St = 0.f, e[8];
        #pragma unroll
        for (int j = 0; j < 8; ++j) { e[j] = __expf(Mj[j] - M); St += Sj[j] * e[j]; }
        const float inv = 1.0f / St;
        #pragma unroll
        for (int j = 0; j < 8; ++j) sWj[j][tid] = e[j] * inv;
    }
    #pragma unroll
    for (int e = 0; e < 16; ++e) {
        const int idx = tid + e * 256;
        const int c = idx >> 5, n = idx & 31;
        sC2[c][n] = c2g[(size_t)(b * 128 + c) * HW + n0 + n];
    }
    __syncthreads();
    const float g2 = gamma2[0];
    #pragma unroll
    for (int e = 0; e < 16; ++e) {
        const int idx = tid + e * 256;
        const int n = idx >> 7, c = idx & 127;
        float s = 0.f;
        #pragma unroll
        for (int j = 0; j < 8; ++j)
            s += bf2f(opart[(((size_t)b * 8 + j) * 4096 + n0 + n) * 128 + c]) * sWj[j][n];
        catb[(size_t)(b * 4096 + n0 + n) * 256 + 128 + c] = f2bf(fmaf(g2, s, sC2[c][n]));
    }
}

// ---------------------------------------------------------------------------
// c3_fbias: pool holds raw sums (atomic-accumulated); scale by 1/4096.
// ---------------------------------------------------------------------------
__global__ __launch_bounds__(256) void c3_fbias_kernel(
    const float* __restrict__ pool, const float* __restrict__ c3w,
    const float* __restrict__ c3b, const float* __restrict__ bng,
    const float* __restrict__ bnb, const float* __restrict__ bnm,
    const float* __restrict__ bnv, const float* __restrict__ al,
    const float* __restrict__ fw, float* __restrict__ fbias)
{
    const int b = blockIdx.x, tid = threadIdx.x;
    __shared__ float sp[256];
    __shared__ float sc3[128];
    sp[tid] = pool[b * 256 + tid] * (1.0f / 4096.0f);
    __syncthreads();
    if (tid < 128) {
        float acc = c3b[tid];
        for (int ci = 0; ci < 256; ++ci) acc = fmaf(c3w[tid * 256 + ci], sp[ci], acc);
        const float scale = bng[tid] * rsqrtf(bnv[tid] + EPSV);
        float t = (acc - bnm[tid]) * scale + bnb[tid];
        const float a = al[0];
        sc3[tid] = t >= 0.f ? t : a * t;
    }
    __syncthreads();
    float f = 0.f;
    for (int j = 0; j < 128; ++j) f = fmaf(fw[tid * 384 + 256 + j], sc3[j], f);
    fbias[b * 256 + tid] = f;
}

// ---------------------------------------------------------------------------
extern "C" void kernel_launch(void* const* d_in, const int* in_sizes, int n_in,
                              void* d_out, int out_size, void* d_ws, size_t ws_size,
                              hipStream_t stream)
{
    const float* x     = (const float*)d_in[0];
    const float* dc_w  = (const float*)d_in[1];
    const float* dc_b  = (const float*)d_in[2];
    const float* dc_g  = (const float*)d_in[3];
    const float* dc_bt = (const float*)d_in[4];
    const float* dc_m  = (const float*)d_in[5];
    const float* dc_v  = (const float*)d_in[6];
    const float* dc_a  = (const float*)d_in[7];
    const float* c1_w  = (const float*)d_in[8];
    const float* c1_b  = (const float*)d_in[9];
    const float* c1_g  = (const float*)d_in[10];
    const float* c1_bt = (const float*)d_in[11];
    const float* c1_m  = (const float*)d_in[12];
    const float* c1_v  = (const float*)d_in[13];
    const float* c1_a  = (const float*)d_in[14];
    const float* c2_w  = (const float*)d_in[15];
    const float* c2_b  = (const float*)d_in[16];
    const float* c2_g  = (const float*)d_in[17];
    const float* c2_bt = (const float*)d_in[18];
    const float* c2_m  = (const float*)d_in[19];
    const float* c2_v  = (const float*)d_in[20];
    const float* c2_a  = (const float*)d_in[21];
    const float* q_w   = (const float*)d_in[22];
    const float* q_b   = (const float*)d_in[23];
    const float* k_w   = (const float*)d_in[24];
    const float* k_b   = (const float*)d_in[25];
    const float* v_w   = (const float*)d_in[26];
    const float* v_b   = (const float*)d_in[27];
    const float* gamma2= (const float*)d_in[28];
    const float* c3_w  = (const float*)d_in[29];
    const float* c3_b  = (const float*)d_in[30];
    const float* c3_g  = (const float*)d_in[31];
    const float* c3_bt = (const float*)d_in[32];
    const float* c3_m  = (const float*)d_in[33];
    const float* c3_v  = (const float*)d_in[34];
    const float* c3_a  = (const float*)d_in[35];
    const float* f_w   = (const float*)d_in[36];
    const float* f_b   = (const float*)d_in[37];
    const float* f_g   = (const float*)d_in[38];
    const float* f_bt  = (const float*)d_in[39];
    const float* f_m   = (const float*)d_in[40];
    const float* f_v   = (const float*)d_in[41];
    const float* f_a   = (const float*)d_in[42];

    // ---- workspace layout by live range (r5-verified, no aliasing) ----
    // opart  [0, 33554432)            live attn_flash..attn_combine
    // xbf    [0, 16777216)            live steps 0..1 (dead before attn)
    // qpk    [33554432, 34603008)
    // kpk    [34603008, 35651584)
    // vbh    [35651584, 39845888)
    // c2b    [39845888, 48234496)     live c2 conv..attn_combine
    // xpbf   [50331648, 58720256)     live dc..c2 conv
    // catb   [58720256, 75497472)
    // weights/pool/fb/M/S above 75497472
    char* base = (char*)d_ws;
    ushort* xbf   = (ushort*)base;                       // [4,4096,512] bf16
    ushort* opart = (ushort*)base;                       // [4,8,4096,128] bf16
    ushort* qpk   = (ushort*)(base + 33554432);          // [4,4096,32]
    ushort* kpk   = (ushort*)(base + 34603008);
    ushort* vbh   = (ushort*)(base + 35651584);          // [4,128,4096] bf16
    float*  c2b   = (float*)(base + 39845888);           // [4,128,4096] f32
    ushort* xpbf  = (ushort*)(base + 50331648);          // [4,4096,256] bf16
    ushort* catb  = (ushort*)(base + 58720256);          // [4,4096,256] bf16
    ushort* wdcp  = (ushort*)(base + 75497472);          // [9,16,256,32]
    ushort* wc2p  = (ushort*)(base + 77856768);          // [9,8,128,32]
    ushort* wc1b  = (ushort*)(base + 78446592);          // [128,256]
    ushort* wfb   = (ushort*)(base + 78512128);          // [256,256]
    float*  poolb = (float*)(base + 78643200);           // 1024 (atomic sums)
    float*  fbb   = (float*)(base + 78647296);           // 1024
    float*  Mpart = (float*)(base + 78651392);           // [4,8,4096]
    float*  Spart = (float*)(base + 79175680);           // [4,8,4096]

    // 0. packs + x -> channel-last bf16 + pool zero
    pack_w3x3<512, 256><<<dim3((9*16*256*32 + 255)/256), 256, 0, stream>>>(dc_w, wdcp);
    pack_w3x3<256, 128><<<dim3((9*8*128*32 + 255)/256), 256, 0, stream>>>(c2_w, wc2p);
    pack_w1x1<<<dim3((32768 + 255)/256), 256, 0, stream>>>(c1_w, wc1b, 256, 256, 32768);
    pack_w1x1<<<dim3((65536 + 255)/256), 256, 0, stream>>>(f_w, wfb, 256, 384, 65536);
    to_chlast_bf16<512><<<dim3(64, 8, 4), 256, 0, stream>>>(x, xbf);
    zero_pool<<<dim3(4), 256, 0, stream>>>(poolb);
    // 1. down_conv 3x3 512->256, full-K, fused BN+PReLU -> xpbf (ch-last bf16)
    //    + pool atomics.
    conv3x3_fused<512, 256, 32, 1, 2, 0><<<dim3(32, 8, 4), 256, 0, stream>>>(
        xbf, wdcp, dc_b, dc_g, dc_bt, dc_m, dc_v, dc_a, xpbf, poolb);
    // 2. c3 branch bias (reads pooled sums)
    c3_fbias_kernel<<<dim3(4), 256, 0, stream>>>(
        poolb, c3_w, c3_b, c3_g, c3_bt, c3_m, c3_v, c3_a, f_w, fbb);
    // 3. branch1 1x1 (MFMA) -> catb cols 0..127
    gemm1x1_cl<256, 128, true, 1><<<dim3(128, 2), 256, 0, stream>>>(
        xpbf, wc1b, c1_b, c1_g, c1_bt, c1_m, c1_v, c1_a, nullptr, catb, 256, 0);
    // 4. branch2 dilated 3x3, full-K, fused BN+PReLU -> c2b (ch-first f32).
    conv3x3_fused<256, 128, 32, 2, 2, 1><<<dim3(32, 4, 4), 256, 0, stream>>>(
        xpbf, wc2p, c2_b, c2_g, c2_bt, c2_m, c2_v, c2_a, c2b, nullptr);
    // 5. q,k
    qk_kernel<<<dim3(64, 4), 256, 0, stream>>>(c2b, q_w, q_b, k_w, k_b, qpk, kpk);
    // 6. v -> bf16 [c][m]
    conv1x1_kernel<128, false, true><<<dim3(64, 2, 4), 256, 0, stream>>>(
        c2b, v_w, 128, 128, v_b, nullptr, vbh);
    // 7. single-pass online flash attention + combine
    attn_flash<<<dim3(32, 8, 4), 256, 0, stream>>>(qpk, kpk, vbh, opart, Mpart, Spart);
    attn_combine<<<dim3(128, 4), 256, 0, stream>>>(opart, Mpart, Spart, c2b, gamma2, catb);
    // 8. fuse conv (MFMA, K=256) -> d_out
    gemm1x1_cl<256, 256, true, 0><<<dim3(128, 4), 256, 0, stream>>>(
        catb, wfb, f_b, f_g, f_bt, f_m, f_v, f_a, fbb, (float*)d_out, 0, 0);
}

// Round 11
// 387.890 us; speedup vs baseline: 1.1905x; 1.0645x over previous
//
#include <hip/hip_runtime.h>
#include <hip/hip_bf16.h>
#include <math.h>

#define HW 4096
#define EPSV 1e-5f

typedef unsigned short ushort;
typedef __attribute__((ext_vector_type(8))) short bf16x8;
typedef __attribute__((ext_vector_type(4))) float f32x4;

__device__ inline ushort f2bf(float f) {
    __hip_bfloat16 h = __float2bfloat16(f);
    return *reinterpret_cast<ushort*>(&h);
}
__device__ inline float bf2f(ushort u) {
    unsigned int v = ((unsigned int)u) << 16;
    return __uint_as_float(v);
}

// ---------------------------------------------------------------------------
// fp32 [b][C][4096] -> bf16 channel-last [b][4096][C], LDS transpose.
// ---------------------------------------------------------------------------
template<int C>
__global__ __launch_bounds__(256) void to_chlast_bf16(
    const float* __restrict__ src, ushort* __restrict__ dst)
{
    const int b = blockIdx.z, c0 = blockIdx.y * 64, p0 = blockIdx.x * 64;
    const int tid = threadIdx.x;
    __shared__ float sT[64][65];
    for (int i = tid; i < 4096; i += 256) {
        const int ch = i >> 6, px = i & 63;
        sT[ch][px] = src[(size_t)(b * C + c0 + ch) * HW + p0 + px];
    }
    __syncthreads();
    const int px = tid >> 2, seg = tid & 3;
    ushort tmp[16];
    #pragma unroll
    for (int j = 0; j < 16; ++j) tmp[j] = f2bf(sT[seg * 16 + j][px]);
    ushort* d = dst + (size_t)(b * HW + p0 + px) * C + c0 + seg * 16;
    *(uint4*)d = *(uint4*)&tmp[0];
    *(uint4*)(d + 8) = *(uint4*)&tmp[8];
}

// ---------------------------------------------------------------------------
// ALL weight packs + pool zero in ONE launch (r10: launch-count reduction).
// Ranges: [dc 3x3][c2 3x3][c1 1x1][f 1x1][pool zero]
// ---------------------------------------------------------------------------
__global__ __launch_bounds__(256) void pack_all(
    const float* __restrict__ dc_w, ushort* __restrict__ wdcp,
    const float* __restrict__ c2_w, ushort* __restrict__ wc2p,
    const float* __restrict__ c1_w, ushort* __restrict__ wc1b,
    const float* __restrict__ f_w,  ushort* __restrict__ wfb,
    float* __restrict__ pool)
{
    constexpr int T_DC = 9 * 16 * 256 * 32;   // 1179648
    constexpr int T_C2 = 9 * 8 * 128 * 32;    // 294912
    constexpr int T_C1 = 32768;
    constexpr int T_F  = 65536;
    int idx = blockIdx.x * 256 + threadIdx.x;
    if (idx < T_DC) {
        const int ci_in = idx & 31;
        int rest = idx >> 5;
        const int co = rest % 256; rest /= 256;
        const int cc = rest % 16;
        const int tap = rest / 16;
        wdcp[idx] = f2bf(dc_w[((size_t)co * 512 + cc * 32 + ci_in) * 9 + tap]);
        return;
    }
    idx -= T_DC;
    if (idx < T_C2) {
        const int ci_in = idx & 31;
        int rest = idx >> 5;
        const int co = rest % 128; rest /= 128;
        const int cc = rest % 8;
        const int tap = rest / 8;
        wc2p[idx] = f2bf(c2_w[((size_t)co * 256 + cc * 32 + ci_in) * 9 + tap]);
        return;
    }
    idx -= T_C2;
    if (idx < T_C1) {                  // c1: stride == K == 256 -> identity
        wc1b[idx] = f2bf(c1_w[idx]);
        return;
    }
    idx -= T_C1;
    if (idx < T_F) {
        const int co = idx >> 8, k = idx & 255;
        wfb[idx] = f2bf(f_w[co * 384 + k]);
        return;
    }
    idx -= T_F;
    if (idx < 1024) pool[idx] = 0.f;
}

// ---------------------------------------------------------------------------
// MFMA implicit-GEMM 3x3 conv, FULL-K, fused BN+PReLU epilogue.
// r9-verified (76.8us dc / WRITE 10MB / VGPR 52).
// COMPILER FACT (r5, r8, twice-confirmed): any staging array whose elements
// are all live simultaneously gets spilled to scratch (WRITE 278-288 MB,
// 126us); only load->immediate-consume staging stays in registers.
// ---------------------------------------------------------------------------
template<int CIN, int COUT, int COTILE, int DIL, int ROWS, int OMODE>
__global__ __launch_bounds__(256, OMODE == 0 ? 4 : 2) void conv3x3_fused(
    const ushort* __restrict__ xin,   // [b][64][64][CIN] bf16
    const ushort* __restrict__ wpk,   // [9][CIN/32][COUT][32] bf16
    const float* __restrict__ bias, const float* __restrict__ bng,
    const float* __restrict__ bnb, const float* __restrict__ bnm,
    const float* __restrict__ bnv, const float* __restrict__ al,
    void* __restrict__ outv,
    float* __restrict__ pool)         // [4][256] sums (OMODE 0 only)
{
    constexpr int HR = ROWS + 2 * DIL;
    constexpr int NC = 64 + 2 * DIL;
    constexpr int MT = COTILE / 16;
    constexpr int WPR = 4 / ROWS;
    constexpr int NT = ROWS;
    constexpr int SAS = 40;
    constexpr int CH = CIN / 32;
    constexpr int NA = HR * NC * 4;
    constexpr int NREG = (NA + 255) / 256;
    constexpr int WCH = 9 * MT * 64;
    constexpr int WPT = (WCH + 255) / 256;

    const int tid = threadIdx.x;
    const int wave = tid >> 6, lane = tid & 63;
    const int l15 = lane & 15, quad = lane >> 4;
    const int b = blockIdx.z;
    const int cob = blockIdx.y;
    const int co0 = cob * COTILE;
    const int h0 = blockIdx.x * ROWS;
    const int row = wave / WPR;
    const int ntbase = (wave % WPR) * NT;

    __shared__ __align__(16) ushort sA[HR * NC * SAS];
    __shared__ __align__(16) ushort sW[WCH * 8];

    f32x4 acc[MT][NT];
    #pragma unroll
    for (int mt = 0; mt < MT; ++mt)
        #pragma unroll
        for (int nt = 0; nt < NT; ++nt) acc[mt][nt] = (f32x4){0.f, 0.f, 0.f, 0.f};

    #pragma unroll 1
    for (int cc = 0; cc < CH; ++cc) {
        if (cc != 0) __syncthreads();       // prev-cc LDS reads done
        // ---- stage input tile: load -> immediate ds_write (no live arrays)
        #pragma unroll
        for (int k = 0; k < NREG; ++k) {
            const int i = tid + k * 256;
            if (i < NA) {
                const int p = i >> 2, seg = i & 3;
                const int r = p / NC, c = p - r * NC;
                const int grow = h0 - DIL + r, gcol = c - DIL;
                uint4 val = {0u, 0u, 0u, 0u};
                if (grow >= 0 && grow < 64 && gcol >= 0 && gcol < 64)
                    val = *(const uint4*)&xin[((size_t)(b * 64 + grow) * 64 + gcol) * CIN
                                              + cc * 32 + seg * 8];
                *(uint4*)&sA[p * SAS + seg * 8] = val;
            }
        }
        // ---- stage weight slice (fragment-major, lane-linear)
        #pragma unroll
        for (int k = 0; k < WPT; ++k) {
            const int i = tid + k * 256;
            if (i < WCH) {
                const int tap = i / (MT * 64);
                const int r = i - tap * (MT * 64);
                const int mt = r >> 6, n = r & 63;
                const uint4 wv = *(const uint4*)&wpk[
                    ((size_t)(tap * (CIN / 32) + cc) * COUT + co0 + mt * 16 + (n & 15)) * 32
                    + (n >> 4) * 8];
                *(uint4*)&sW[i * 8] = wv;
            }
        }
        __syncthreads();

        // ---- 9-tap MFMA loop, both operands from LDS
        #pragma unroll
        for (int tap = 0; tap < 9; ++tap) {
            const int ty = tap / 3, tx = tap - ty * 3;
            const int rl = row + ty * DIL;
            bf16x8 wf[MT];
            #pragma unroll
            for (int mt = 0; mt < MT; ++mt)
                wf[mt] = *(const bf16x8*)&sW[((tap * MT + mt) * 64 + lane) * 8];
            #pragma unroll
            for (int nt = 0; nt < NT; ++nt) {
                const int cl = (ntbase + nt) * 16 + l15 + tx * DIL;
                const bf16x8 bp = *(const bf16x8*)&sA[(rl * NC + cl) * SAS + quad * 8];
                #pragma unroll
                for (int mt = 0; mt < MT; ++mt)
                    acc[mt][nt] = __builtin_amdgcn_mfma_f32_16x16x32_bf16(
                        wf[mt], bp, acc[mt][nt], 0, 0, 0);
            }
        }
    }

    const float a = al[0];

    if constexpr (OMODE == 0) {
        // BN+PReLU -> bf16 channel-last via LDS transpose, + pool atomics.
        __syncthreads();                 // done reading sA/sW
        ushort* sT = sA;                 // reuse: [row*64+px][40] (co-padded)
        #pragma unroll
        for (int mt = 0; mt < MT; ++mt) {
            float sc[4], sh[4], psum[4];
            #pragma unroll
            for (int rr = 0; rr < 4; ++rr) {
                const int co = co0 + mt * 16 + quad * 4 + rr;
                sc[rr] = bng[co] * rsqrtf(bnv[co] + EPSV);
                sh[rr] = (bias[co] - bnm[co]) * sc[rr] + bnb[co];
                psum[rr] = 0.f;
            }
            #pragma unroll
            for (int nt = 0; nt < NT; ++nt) {
                float tv[4];
                #pragma unroll
                for (int rr = 0; rr < 4; ++rr) {
                    float t = acc[mt][nt][rr] * sc[rr] + sh[rr];
                    t = t >= 0.f ? t : a * t;
                    tv[rr] = t;
                    psum[rr] += t;
                }
                ushort4 u;
                u.x = f2bf(tv[0]); u.y = f2bf(tv[1]);
                u.z = f2bf(tv[2]); u.w = f2bf(tv[3]);
                const int px = (ntbase + nt) * 16 + l15;
                *(ushort4*)&sT[(row * 64 + px) * 40 + mt * 16 + quad * 4] = u;
            }
            #pragma unroll
            for (int rr = 0; rr < 4; ++rr) {
                float v = psum[rr];
                v += __shfl_xor(v, 1);
                v += __shfl_xor(v, 2);
                v += __shfl_xor(v, 4);
                v += __shfl_xor(v, 8);
                if (l15 == 0)
                    atomicAdd(&pool[b * 256 + co0 + mt * 16 + quad * 4 + rr], v);
            }
        }
        __syncthreads();
        ushort* dst = (ushort*)outv;
        const int p = tid >> 1, half = tid & 1;   // p = row*64+px (0..127)
        const uint4 v0 = *(const uint4*)&sT[p * 40 + half * 16];
        const uint4 v1 = *(const uint4*)&sT[p * 40 + half * 16 + 8];
        const size_t off = ((size_t)(b * 4096 + (h0 + (p >> 6)) * 64 + (p & 63))) * 256
                           + co0 + half * 16;
        *(uint4*)&dst[off] = v0;
        *(uint4*)&dst[off + 8] = v1;
    } else {
        // BN+PReLU -> fp32 channel-first (c2b layout).
        float* out = (float*)outv;
        #pragma unroll
        for (int mt = 0; mt < MT; ++mt)
            #pragma unroll
            for (int rr = 0; rr < 4; ++rr) {
                const int co = co0 + mt * 16 + quad * 4 + rr;
                const float sc = bng[co] * rsqrtf(bnv[co] + EPSV);
                const float sh = (bias[co] - bnm[co]) * sc + bnb[co];
                #pragma unroll
                for (int nt = 0; nt < NT; ++nt) {
                    float t = acc[mt][nt][rr] * sc + sh;
                    t = t >= 0.f ? t : a * t;
                    out[((size_t)(b * COUT + co) * 64 + h0 + row) * 64
                        + (ntbase + nt) * 16 + l15] = t;
                }
            }
    }
}

// ---------------------------------------------------------------------------
// MFMA 1x1 conv on channel-last bf16 input (used for the FUSE conv, OMODE 0).
// ---------------------------------------------------------------------------
template<int CIN, int COUT, bool BNACT, int OMODE>
__global__ __launch_bounds__(256) void gemm1x1_cl(
    const ushort* __restrict__ xin,   // [16384][CIN] bf16
    const ushort* __restrict__ wbf,   // [COUT][CIN] bf16
    const float* __restrict__ bias, const float* __restrict__ bng,
    const float* __restrict__ bnb, const float* __restrict__ bnm,
    const float* __restrict__ bnv, const float* __restrict__ al,
    const float* __restrict__ ebias, void* __restrict__ outv,
    int ostride, int ocol)
{
    const int tid = threadIdx.x;
    const int wave = tid >> 6, lane = tid & 63;
    const int l15 = lane & 15, quad = lane >> 4;
    const int pix0 = blockIdx.x * 128 + wave * 32;
    const int co0 = blockIdx.y * 64;

    f32x4 acc[4][2];
    #pragma unroll
    for (int mt = 0; mt < 4; ++mt)
        #pragma unroll
        for (int nt = 0; nt < 2; ++nt) acc[mt][nt] = (f32x4){0.f, 0.f, 0.f, 0.f};

    #pragma unroll 2
    for (int cc = 0; cc < CIN / 32; ++cc) {
        bf16x8 aw[4], bp[2];
        #pragma unroll
        for (int mt = 0; mt < 4; ++mt)
            aw[mt] = *(const bf16x8*)&wbf[(size_t)(co0 + mt * 16 + l15) * CIN + cc * 32 + quad * 8];
        #pragma unroll
        for (int nt = 0; nt < 2; ++nt)
            bp[nt] = *(const bf16x8*)&xin[(size_t)(pix0 + nt * 16 + l15) * CIN + cc * 32 + quad * 8];
        #pragma unroll
        for (int mt = 0; mt < 4; ++mt)
            #pragma unroll
            for (int nt = 0; nt < 2; ++nt)
                acc[mt][nt] = __builtin_amdgcn_mfma_f32_16x16x32_bf16(
                    aw[mt], bp[nt], acc[mt][nt], 0, 0, 0);
    }

    const int bI = pix0 >> 12;
    const float a = BNACT ? al[0] : 0.f;

    if (OMODE == 0) {
        float* out = (float*)outv;
        #pragma unroll
        for (int mt = 0; mt < 4; ++mt)
            #pragma unroll
            for (int r = 0; r < 4; ++r) {
                const int co = co0 + mt * 16 + quad * 4 + r;
                float bb = bias[co];
                if (ebias) bb += ebias[bI * COUT + co];
                float scale = 1.f, shift = bb;
                if (BNACT) {
                    scale = bng[co] * rsqrtf(bnv[co] + EPSV);
                    shift = bb * scale + (bnb[co] - bnm[co] * scale);
                }
                #pragma unroll
                for (int nt = 0; nt < 2; ++nt) {
                    float t = acc[mt][nt][r] * scale + shift;
                    if (BNACT) t = t >= 0.f ? t : a * t;
                    out[((size_t)(bI * COUT + co)) * HW + (pix0 & 4095) + nt * 16 + l15] = t;
                }
            }
    } else {
        __shared__ ushort sT[4][32][68];
        #pragma unroll
        for (int mt = 0; mt < 4; ++mt)
            #pragma unroll
            for (int r = 0; r < 4; ++r) {
                const int co = co0 + mt * 16 + quad * 4 + r;
                float bb = bias[co];
                float scale = 1.f, shift = bb;
                if (BNACT) {
                    scale = bng[co] * rsqrtf(bnv[co] + EPSV);
                    shift = bb * scale + (bnb[co] - bnm[co] * scale);
                }
                #pragma unroll
                for (int nt = 0; nt < 2; ++nt) {
                    float t = acc[mt][nt][r] * scale + shift;
                    if (BNACT) t = t >= 0.f ? t : a * t;
                    sT[wave][nt * 16 + l15][mt * 16 + quad * 4 + r] = f2bf(t);
                }
            }
        __syncthreads();
        const int p = lane >> 1, half = lane & 1;
        ushort* out = (ushort*)outv;
        #pragma unroll
        for (int seg = 0; seg < 4; ++seg) {
            uint2 a0 = *(uint2*)&sT[wave][p][half * 32 + seg * 8];
            uint2 a1 = *(uint2*)&sT[wave][p][half * 32 + seg * 8 + 4];
            uint4 vv = {a0.x, a0.y, a1.x, a1.y};
            *(uint4*)&out[(size_t)(pix0 + p) * ostride + ocol + co0 + half * 32 + seg * 8] = vv;
        }
    }
}

// ---------------------------------------------------------------------------
// c1 1x1 gemm (OMODE1, BNACT, CIN=256, COUT=128) + c3_fbias folded in as
// 4 extra blocks (r10).  Grid (130, 2): x<128 -> gemm; x>=128 -> c3 for
// b = (x-128)*2 + y.
// ---------------------------------------------------------------------------
__global__ __launch_bounds__(256) void c1_and_c3(
    const ushort* __restrict__ xin, const ushort* __restrict__ wbf,
    const float* __restrict__ bias, const float* __restrict__ bng,
    const float* __restrict__ bnb, const float* __restrict__ bnm,
    const float* __restrict__ bnv, const float* __restrict__ al,
    ushort* __restrict__ catb,
    const float* __restrict__ pool, const float* __restrict__ c3w,
    const float* __restrict__ c3b, const float* __restrict__ c3g,
    const float* __restrict__ c3bt, const float* __restrict__ c3m,
    const float* __restrict__ c3v, const float* __restrict__ c3a,
    const float* __restrict__ fw, float* __restrict__ fbias)
{
    const int tid = threadIdx.x;
    if (blockIdx.x >= 128) {
        // ---- c3 branch bias for b = (x-128)*2 + y
        const int b = (blockIdx.x - 128) * 2 + blockIdx.y;
        __shared__ float sp[256];
        __shared__ float sc3[128];
        sp[tid] = pool[b * 256 + tid] * (1.0f / 4096.0f);
        __syncthreads();
        if (tid < 128) {
            float acc2 = c3b[tid];
            for (int ci = 0; ci < 256; ++ci) acc2 = fmaf(c3w[tid * 256 + ci], sp[ci], acc2);
            const float scale = c3g[tid] * rsqrtf(c3v[tid] + EPSV);
            float t = (acc2 - c3m[tid]) * scale + c3bt[tid];
            const float a2 = c3a[0];
            sc3[tid] = t >= 0.f ? t : a2 * t;
        }
        __syncthreads();
        float f = 0.f;
        for (int j2 = 0; j2 < 128; ++j2) f = fmaf(fw[tid * 384 + 256 + j2], sc3[j2], f);
        fbias[b * 256 + tid] = f;
        return;
    }
    // ---- c1 gemm (CIN=256, COUT=128, BN+PReLU, bf16 ch-last out at ocol 0)
    constexpr int CIN = 256;
    const int wave = tid >> 6, lane = tid & 63;
    const int l15 = lane & 15, quad = lane >> 4;
    const int pix0 = blockIdx.x * 128 + wave * 32;
    const int co0 = blockIdx.y * 64;

    f32x4 acc[4][2];
    #pragma unroll
    for (int mt = 0; mt < 4; ++mt)
        #pragma unroll
        for (int nt = 0; nt < 2; ++nt) acc[mt][nt] = (f32x4){0.f, 0.f, 0.f, 0.f};

    #pragma unroll 2
    for (int cc = 0; cc < CIN / 32; ++cc) {
        bf16x8 aw[4], bp[2];
        #pragma unroll
        for (int mt = 0; mt < 4; ++mt)
            aw[mt] = *(const bf16x8*)&wbf[(size_t)(co0 + mt * 16 + l15) * CIN + cc * 32 + quad * 8];
        #pragma unroll
        for (int nt = 0; nt < 2; ++nt)
            bp[nt] = *(const bf16x8*)&xin[(size_t)(pix0 + nt * 16 + l15) * CIN + cc * 32 + quad * 8];
        #pragma unroll
        for (int mt = 0; mt < 4; ++mt)
            #pragma unroll
            for (int nt = 0; nt < 2; ++nt)
                acc[mt][nt] = __builtin_amdgcn_mfma_f32_16x16x32_bf16(
                    aw[mt], bp[nt], acc[mt][nt], 0, 0, 0);
    }

    const float a = al[0];
    __shared__ ushort sT[4][32][68];
    #pragma unroll
    for (int mt = 0; mt < 4; ++mt)
        #pragma unroll
        for (int r = 0; r < 4; ++r) {
            const int co = co0 + mt * 16 + quad * 4 + r;
            const float scale = bng[co] * rsqrtf(bnv[co] + EPSV);
            const float shift = bias[co] * scale + (bnb[co] - bnm[co] * scale);
            #pragma unroll
            for (int nt = 0; nt < 2; ++nt) {
                float t = acc[mt][nt][r] * scale + shift;
                t = t >= 0.f ? t : a * t;
                sT[wave][nt * 16 + l15][mt * 16 + quad * 4 + r] = f2bf(t);
            }
        }
    __syncthreads();
    const int p = lane >> 1, half = lane & 1;
    #pragma unroll
    for (int seg = 0; seg < 4; ++seg) {
        uint2 a0 = *(uint2*)&sT[wave][p][half * 32 + seg * 8];
        uint2 a1 = *(uint2*)&sT[wave][p][half * 32 + seg * 8 + 4];
        uint4 vv = {a0.x, a0.y, a1.x, a1.y};
        *(uint4*)&catb[(size_t)(pix0 + p) * 256 + co0 + half * 32 + seg * 8] = vv;
    }
}

// ---------------------------------------------------------------------------
// qk (128->16 x2 -> packed bf16 [b][4096][32]) + v (128->128 fp32 FMA ->
// bf16 [b][128][4096]) in ONE launch (r10).  Grid (64, 3, 4):
// y==0 -> qk; y in {1,2} -> v with co0=(y-1)*64.  Block-uniform branch.
// ---------------------------------------------------------------------------
__global__ __launch_bounds__(256) void qkv_kernel(
    const float* __restrict__ c2g, const float* __restrict__ qw,
    const float* __restrict__ qb2, const float* __restrict__ kw,
    const float* __restrict__ kb2, ushort* __restrict__ qpack,
    ushort* __restrict__ kpack,
    const float* __restrict__ vw, const float* __restrict__ vb,
    ushort* __restrict__ vbh)
{
    const int tid = threadIdx.x;
    const int b = blockIdx.z, p0 = blockIdx.x * 64;
    __shared__ __align__(16) char smem[49152];

    if (blockIdx.y == 0) {
        // ---- qk path
        float (*sC)[64]   = (float(*)[64])smem;            // 32768 B
        float (*sWq)[128] = (float(*)[128])(smem + 32768); // 8192 B
        float (*sWk)[128] = (float(*)[128])(smem + 40960); // 8192 B
        for (int i = tid; i < 8192; i += 256) {
            const int px = i & 63, ci = i >> 6;
            sC[ci][px] = c2g[(size_t)(b * 128 + ci) * HW + p0 + px];
        }
        for (int i = tid; i < 2048; i += 256) {
            const int ci = i & 127, co = i >> 7;
            sWq[co][ci] = qw[co * 128 + ci];
            sWk[co][ci] = kw[co * 128 + ci];
        }
        __syncthreads();
        const int px = tid & 63, grp = tid >> 6;
        const int co0 = (grp & 1) * 8;
        const bool isK = grp >= 2;
        const float* sWp = isK ? &sWk[0][0] : &sWq[0][0];
        float acc[8] = {};
        for (int ci = 0; ci < 128; ++ci) {
            const float xv = sC[ci][px];
            #pragma unroll
            for (int j = 0; j < 8; ++j)
                acc[j] = fmaf(sWp[(co0 + j) * 128 + ci], xv, acc[j]);
        }
        const float* bsrc = isK ? kb2 : qb2;
        ushort* osrc = isK ? kpack : qpack;
        const size_t base = (size_t)(b * 4096 + p0 + px) * 32;
        #pragma unroll
        for (int j = 0; j < 8; ++j) {
            osrc[base + co0 + j] = f2bf(acc[j] + bsrc[co0 + j]);
            osrc[base + 16 + co0 + j] = 0;
        }
    } else {
        // ---- v path (fp32 1x1, CIN=COUT=128, bf16 out)
        const int co0 = (blockIdx.y - 1) * 64;
        float* sIn = (float*)smem;                 // 16*64 = 4096 B
        float* sW  = (float*)(smem + 16384);       // 16*68 = 4352 B
        const int cg = tid >> 4, pg = tid & 15;
        const int c0l = cg * 4, w0 = pg * 4;
        float acc[4][4] = {};
        for (int cc = 0; cc < 128; cc += 16) {
            {
                int i = tid;
                #pragma unroll
                for (int it = 0; it < 4; ++it, i += 256) {
                    const int px = i & 63, ci = i >> 6;
                    sIn[ci * 64 + px] = c2g[(size_t)(b * 128 + cc + ci) * HW + p0 + px];
                }
                i = tid;
                #pragma unroll
                for (int it = 0; it < 4; ++it, i += 256) {
                    const int ci = i & 15, co = i >> 4;
                    sW[ci * 68 + co] = vw[(co0 + co) * 128 + cc + ci];
                }
            }
            __syncthreads();
            #pragma unroll
            for (int ci = 0; ci < 16; ++ci) {
                const float4 iv = *(const float4*)&sIn[ci * 64 + w0];
                const float4 wv = *(const float4*)&sW[ci * 68 + c0l];
                const float ia[4] = {iv.x, iv.y, iv.z, iv.w};
                const float wa[4] = {wv.x, wv.y, wv.z, wv.w};
                #pragma unroll
                for (int i2 = 0; i2 < 4; ++i2)
                    #pragma unroll
                    for (int j = 0; j < 4; ++j)
                        acc[i2][j] = fmaf(wa[i2], ia[j], acc[i2][j]);
            }
            __syncthreads();
        }
        #pragma unroll
        for (int i2 = 0; i2 < 4; ++i2) {
            const int co = co0 + c0l + i2;
            const float shift = vb[co];
            const size_t base = (size_t)(b * 128 + co) * HW + p0 + w0;
            #pragma unroll
            for (int j = 0; j < 4; ++j)
                vbh[base + j] = f2bf(acc[i2][j] + shift);
        }
    }
}

// ---------------------------------------------------------------------------
// SINGLE-PASS flash attention (r8/r9-verified): online softmax + defer-max.
// Grid: (32 nblk, 8 msplit, 4 batch).
// ---------------------------------------------------------------------------
__global__ __launch_bounds__(256) void attn_flash(
    const ushort* __restrict__ qpack,
    const ushort* __restrict__ kpack,
    const ushort* __restrict__ vpackT,
    ushort* __restrict__ opart,       // [b][8j][4096n][128c] bf16
    float* __restrict__ Mpart,        // [b][8j][4096n]
    float* __restrict__ Spart)
{
    const int tid = threadIdx.x;
    const int wave = tid >> 6, lane = tid & 63;
    const int l15 = lane & 15, quad = lane >> 4;
    const int b = blockIdx.z, j = blockIdx.y;
    const int n0w = blockIdx.x * 128 + wave * 32;
    const int m_begin = j * 512;

    __shared__ __align__(16) ushort sV[2][128][40];
    __shared__ __align__(16) ushort sP[4][2][16][40];

    const bf16x8 bq0 = *(const bf16x8*)(qpack + ((size_t)(b * 4096 + n0w + l15) * 32 + quad * 8));
    const bf16x8 bq1 = *(const bf16x8*)(qpack + ((size_t)(b * 4096 + n0w + 16 + l15) * 32 + quad * 8));
    const f32x4 z = {0.f, 0.f, 0.f, 0.f};

    float runM0 = -3e30f, runM1 = -3e30f;
    float runS0 = 0.f, runS1 = 0.f;
    f32x4 oacc0[8], oacc1[8];
    #pragma unroll
    for (int cs = 0; cs < 8; ++cs) {
        oacc0[cs] = (f32x4){0.f, 0.f, 0.f, 0.f};
        oacc1[cs] = (f32x4){0.f, 0.f, 0.f, 0.f};
    }

    const int stc = tid >> 1, stseg = tid & 1;

    {
        uint4 v0 = *(const uint4*)&vpackT[(size_t)(b * 128 + stc) * HW + m_begin + stseg * 16];
        uint4 v1 = *(const uint4*)&vpackT[(size_t)(b * 128 + stc) * HW + m_begin + stseg * 16 + 8];
        *(uint4*)&sV[0][stc][stseg * 16] = v0;
        *(uint4*)&sV[0][stc][stseg * 16 + 8] = v1;
    }
    __syncthreads();

    #pragma unroll 1
    for (int t = 0; t < 16; ++t) {
        const int m0 = m_begin + t * 32;
        const int buf = t & 1;
        uint4 nv0, nv1;
        const bool more = (t + 1 < 16);
        if (more) {
            const size_t nb = (size_t)(b * 128 + stc) * HW + m0 + 32 + stseg * 16;
            nv0 = *(const uint4*)&vpackT[nb];
            nv1 = *(const uint4*)&vpackT[nb + 8];
        }
        f32x4 s0[2], s1[2];
        #pragma unroll
        for (int ms = 0; ms < 2; ++ms) {
            const bf16x8 ak = *(const bf16x8*)(
                kpack + ((size_t)(b * 4096 + m0 + ms * 16 + l15) * 32 + quad * 8));
            s0[ms] = __builtin_amdgcn_mfma_f32_16x16x32_bf16(ak, bq0, z, 0, 0, 0);
            s1[ms] = __builtin_amdgcn_mfma_f32_16x16x32_bf16(ak, bq1, z, 0, 0, 0);
        }

        // ---- online max update with defer (THR=8 -> P <= e^8, bf16-safe)
        float tM0 = fmaxf(fmaxf(fmaxf(s0[0][0], s0[0][1]), fmaxf(s0[0][2], s0[0][3])),
                          fmaxf(fmaxf(s0[1][0], s0[1][1]), fmaxf(s0[1][2], s0[1][3])));
        float tM1 = fmaxf(fmaxf(fmaxf(s1[0][0], s1[0][1]), fmaxf(s1[0][2], s1[0][3])),
                          fmaxf(fmaxf(s1[1][0], s1[1][1]), fmaxf(s1[1][2], s1[1][3])));
        tM0 = fmaxf(tM0, __shfl_xor(tM0, 16));
        tM0 = fmaxf(tM0, __shfl_xor(tM0, 32));
        tM1 = fmaxf(tM1, __shfl_xor(tM1, 16));
        tM1 = fmaxf(tM1, __shfl_xor(tM1, 32));
        if (__any(tM0 > runM0 + 8.f)) {
            const float nM = fmaxf(runM0, tM0);
            const float sc = __builtin_amdgcn_exp2f((runM0 - nM) * 1.44269504f);
            runS0 *= sc;
            float scr[4];
            #pragma unroll
            for (int r = 0; r < 4; ++r) scr[r] = __shfl(sc, quad * 4 + r);
            #pragma unroll
            for (int cs = 0; cs < 8; ++cs) {
                oacc0[cs][0] *= scr[0]; oacc0[cs][1] *= scr[1];
                oacc0[cs][2] *= scr[2]; oacc0[cs][3] *= scr[3];
            }
            runM0 = nM;
        }
        if (__any(tM1 > runM1 + 8.f)) {
            const float nM = fmaxf(runM1, tM1);
            const float sc = __builtin_amdgcn_exp2f((runM1 - nM) * 1.44269504f);
            runS1 *= sc;
            float scr[4];
            #pragma unroll
            for (int r = 0; r < 4; ++r) scr[r] = __shfl(sc, quad * 4 + r);
            #pragma unroll
            for (int cs = 0; cs < 8; ++cs) {
                oacc1[cs][0] *= scr[0]; oacc1[cs][1] *= scr[1];
                oacc1[cs][2] *= scr[2]; oacc1[cs][3] *= scr[3];
            }
            runM1 = nM;
        }
        const float Ms0 = runM0 * 1.44269504f;
        const float Ms1 = runM1 * 1.44269504f;

        #pragma unroll
        for (int ms = 0; ms < 2; ++ms) {
            float p0[4], p1[4];
            #pragma unroll
            for (int r = 0; r < 4; ++r) {
                p0[r] = __builtin_amdgcn_exp2f(fmaf(s0[ms][r], 1.44269504f, -Ms0));
                p1[r] = __builtin_amdgcn_exp2f(fmaf(s1[ms][r], 1.44269504f, -Ms1));
                runS0 += p0[r];
                runS1 += p1[r];
            }
            ushort4 u0, u1;
            u0.x = f2bf(p0[0]); u0.y = f2bf(p0[1]); u0.z = f2bf(p0[2]); u0.w = f2bf(p0[3]);
            u1.x = f2bf(p1[0]); u1.y = f2bf(p1[1]); u1.z = f2bf(p1[2]); u1.w = f2bf(p1[3]);
            *(uint2*)&sP[wave][0][l15][ms * 16 + quad * 4] = *(uint2*)&u0;
            *(uint2*)&sP[wave][1][l15][ms * 16 + quad * 4] = *(uint2*)&u1;
        }
        asm volatile("s_waitcnt lgkmcnt(0)" ::: "memory");
        const bf16x8 ap0 = *(const bf16x8*)&sP[wave][0][l15][quad * 8];
        const bf16x8 ap1 = *(const bf16x8*)&sP[wave][1][l15][quad * 8];
        #pragma unroll
        for (int cs = 0; cs < 8; ++cs) {
            const bf16x8 bv = *(const bf16x8*)&sV[buf][cs * 16 + l15][quad * 8];
            oacc0[cs] = __builtin_amdgcn_mfma_f32_16x16x32_bf16(ap0, bv, oacc0[cs], 0, 0, 0);
            oacc1[cs] = __builtin_amdgcn_mfma_f32_16x16x32_bf16(ap1, bv, oacc1[cs], 0, 0, 0);
        }
        if (more) {
            *(uint4*)&sV[buf ^ 1][stc][stseg * 16] = nv0;
            *(uint4*)&sV[buf ^ 1][stc][stseg * 16 + 8] = nv1;
            __syncthreads();
        }
    }

    runS0 += __shfl_xor(runS0, 16);
    runS0 += __shfl_xor(runS0, 32);
    runS1 += __shfl_xor(runS1, 16);
    runS1 += __shfl_xor(runS1, 32);
    if (lane < 32) {
        const float Mv = (lane < 16) ? runM0 : runM1;
        const float Sv = (lane < 16) ? runS0 : runS1;
        const int n = n0w + ((lane < 16) ? 0 : 16) + l15;
        Mpart[((size_t)b * 8 + j) * 4096 + n] = Mv;
        Spart[((size_t)b * 8 + j) * 4096 + n] = Sv;
    }
    #pragma unroll
    for (int cs = 0; cs < 8; ++cs)
        #pragma unroll
        for (int r = 0; r < 4; ++r) {
            const int n = n0w + quad * 4 + r;
            opart[(((size_t)b * 8 + j) * 4096 + n) * 128 + cs * 16 + l15] = f2bf(oacc0[cs][r]);
            opart[(((size_t)b * 8 + j) * 4096 + n + 16) * 128 + cs * 16 + l15] = f2bf(oacc1[cs][r]);
        }
}

// ---------------------------------------------------------------------------
// Combine 8 m-split partials, normalize, fuse gamma2*O + c2 -> catb[:,128:256]
// ---------------------------------------------------------------------------
__global__ __launch_bounds__(256) void attn_combine(
    const ushort* __restrict__ opart, const float* __restrict__ Mpart,
    const float* __restrict__ Spart, const float* __restrict__ c2g,
    const float* __restrict__ gamma2, ushort* __restrict__ catb)
{
    const int b = blockIdx.y, n0 = blockIdx.x * 32, tid = threadIdx.x;
    __shared__ float sC2[128][33];
    __shared__ float sWj[8][32];
    if (tid < 32) {
        const int n = n0 + tid;
        float Mj[8], Sj[8];
        #pragma unroll
        for (int j = 0; j < 8; ++j) {
            Mj[j] = Mpart[((size_t)b * 8 + j) * 4096 + n];
            Sj[j] = Spart[((size_t)b * 8 + j) * 4096 + n];
        }
        float M = -3e30f;
        #pragma unroll
        for (int j = 0; j < 8; ++j) M = fmaxf(M, Mj[j]);
        float St = 0.f, e[8];
        #pragma unroll
        for (int j = 0; j < 8; ++j) { e[j] = __expf(Mj[j] - M); St += Sj[j] * e[j]; }
        const float inv = 1.0f / St;
        #pragma unroll
        for (int j = 0; j < 8; ++j) sWj[j][tid] = e[j] * inv;
    }
    #pragma unroll
    for (int e = 0; e < 16; ++e) {
        const int idx = tid + e * 256;
        const int c = idx >> 5, n = idx & 31;
        sC2[c][n] = c2g[(size_t)(b * 128 + c) * HW + n0 + n];
    }
    __syncthreads();
    const float g2 = gamma2[0];
    #pragma unroll
    for (int e = 0; e < 16; ++e) {
        const int idx = tid + e * 256;
        const int n = idx >> 7, c = idx & 127;
        float s = 0.f;
        #pragma unroll
        for (int j = 0; j < 8; ++j)
            s += bf2f(opart[(((size_t)b * 8 + j) * 4096 + n0 + n) * 128 + c]) * sWj[j][n];
        catb[(size_t)(b * 4096 + n0 + n) * 256 + 128 + c] = f2bf(fmaf(g2, s, sC2[c][n]));
    }
}

// ---------------------------------------------------------------------------
extern "C" void kernel_launch(void* const* d_in, const int* in_sizes, int n_in,
                              void* d_out, int out_size, void* d_ws, size_t ws_size,
                              hipStream_t stream)
{
    const float* x     = (const float*)d_in[0];
    const float* dc_w  = (const float*)d_in[1];
    const float* dc_b  = (const float*)d_in[2];
    const float* dc_g  = (const float*)d_in[3];
    const float* dc_bt = (const float*)d_in[4];
    const float* dc_m  = (const float*)d_in[5];
    const float* dc_v  = (const float*)d_in[6];
    const float* dc_a  = (const float*)d_in[7];
    const float* c1_w  = (const float*)d_in[8];
    const float* c1_b  = (const float*)d_in[9];
    const float* c1_g  = (const float*)d_in[10];
    const float* c1_bt = (const float*)d_in[11];
    const float* c1_m  = (const float*)d_in[12];
    const float* c1_v  = (const float*)d_in[13];
    const float* c1_a  = (const float*)d_in[14];
    const float* c2_w  = (const float*)d_in[15];
    const float* c2_b  = (const float*)d_in[16];
    const float* c2_g  = (const float*)d_in[17];
    const float* c2_bt = (const float*)d_in[18];
    const float* c2_m  = (const float*)d_in[19];
    const float* c2_v  = (const float*)d_in[20];
    const float* c2_a  = (const float*)d_in[21];
    const float* q_w   = (const float*)d_in[22];
    const float* q_b   = (const float*)d_in[23];
    const float* k_w   = (const float*)d_in[24];
    const float* k_b   = (const float*)d_in[25];
    const float* v_w   = (const float*)d_in[26];
    const float* v_b   = (const float*)d_in[27];
    const float* gamma2= (const float*)d_in[28];
    const float* c3_w  = (const float*)d_in[29];
    const float* c3_b  = (const float*)d_in[30];
    const float* c3_g  = (const float*)d_in[31];
    const float* c3_bt = (const float*)d_in[32];
    const float* c3_m  = (const float*)d_in[33];
    const float* c3_v  = (const float*)d_in[34];
    const float* c3_a  = (const float*)d_in[35];
    const float* f_w   = (const float*)d_in[36];
    const float* f_b   = (const float*)d_in[37];
    const float* f_g   = (const float*)d_in[38];
    const float* f_bt  = (const float*)d_in[39];
    const float* f_m   = (const float*)d_in[40];
    const float* f_v   = (const float*)d_in[41];
    const float* f_a   = (const float*)d_in[42];

    // ---- workspace layout by live range (r5-verified, no aliasing) ----
    char* base = (char*)d_ws;
    ushort* xbf   = (ushort*)base;                       // [4,4096,512] bf16
    ushort* opart = (ushort*)base;                       // [4,8,4096,128] bf16
    ushort* qpk   = (ushort*)(base + 33554432);          // [4,4096,32]
    ushort* kpk   = (ushort*)(base + 34603008);
    ushort* vbh   = (ushort*)(base + 35651584);          // [4,128,4096] bf16
    float*  c2b   = (float*)(base + 39845888);           // [4,128,4096] f32
    ushort* xpbf  = (ushort*)(base + 50331648);          // [4,4096,256] bf16
    ushort* catb  = (ushort*)(base + 58720256);          // [4,4096,256] bf16
    ushort* wdcp  = (ushort*)(base + 75497472);          // [9,16,256,32]
    ushort* wc2p  = (ushort*)(base + 77856768);          // [9,8,128,32]
    ushort* wc1b  = (ushort*)(base + 78446592);          // [128,256]
    ushort* wfb   = (ushort*)(base + 78512128);          // [256,256]
    float*  poolb = (float*)(base + 78643200);           // 1024 (atomic sums)
    float*  fbb   = (float*)(base + 78647296);           // 1024
    float*  Mpart = (float*)(base + 78651392);           // [4,8,4096]
    float*  Spart = (float*)(base + 79175680);           // [4,8,4096]

    // 0. all packs + pool zero (1 launch) + x -> channel-last bf16
    pack_all<<<dim3(6148), 256, 0, stream>>>(
        dc_w, wdcp, c2_w, wc2p, c1_w, wc1b, f_w, wfb, poolb);
    to_chlast_bf16<512><<<dim3(64, 8, 4), 256, 0, stream>>>(x, xbf);
    // 1. down_conv 3x3 512->256, full-K, fused BN+PReLU -> xpbf + pool atomics
    conv3x3_fused<512, 256, 32, 1, 2, 0><<<dim3(32, 8, 4), 256, 0, stream>>>(
        xbf, wdcp, dc_b, dc_g, dc_bt, dc_m, dc_v, dc_a, xpbf, poolb);
    // 2. branch1 1x1 -> catb cols 0..127, + c3 fbias (4 extra blocks)
    c1_and_c3<<<dim3(130, 2), 256, 0, stream>>>(
        xpbf, wc1b, c1_b, c1_g, c1_bt, c1_m, c1_v, c1_a, catb,
        poolb, c3_w, c3_b, c3_g, c3_bt, c3_m, c3_v, c3_a, f_w, fbb);
    // 3. branch2 dilated 3x3, full-K, fused BN+PReLU -> c2b (ch-first f32)
    conv3x3_fused<256, 128, 32, 2, 2, 1><<<dim3(32, 4, 4), 256, 0, stream>>>(
        xpbf, wc2p, c2_b, c2_g, c2_bt, c2_m, c2_v, c2_a, c2b, nullptr);
    // 4. q, k, and v in one launch
    qkv_kernel<<<dim3(64, 3, 4), 256, 0, stream>>>(
        c2b, q_w, q_b, k_w, k_b, qpk, kpk, v_w, v_b, vbh);
    // 5. single-pass online flash attention + combine
    attn_flash<<<dim3(32, 8, 4), 256, 0, stream>>>(qpk, kpk, vbh, opart, Mpart, Spart);
    attn_combine<<<dim3(128, 4), 256, 0, stream>>>(opart, Mpart, Spart, c2b, gamma2, catb);
    // 6. fuse conv (MFMA, K=256) -> d_out
    gemm1x1_cl<256, 256, true, 0><<<dim3(128, 4), 256, 0, stream>>>(
        catb, wfb, f_b, f_g, f_bt, f_m, f_v, f_a, fbb, (float*)d_out, 0, 0);
}

// Round 12
// 374.367 us; speedup vs baseline: 1.2335x; 1.0361x over previous
//
#include <hip/hip_runtime.h>
#include <hip/hip_bf16.h>
#include <math.h>

#define HW 4096
#define EPSV 1e-5f

typedef unsigned short ushort;
typedef __attribute__((ext_vector_type(8))) short bf16x8;
typedef __attribute__((ext_vector_type(4))) float f32x4;

__device__ inline ushort f2bf(float f) {
    __hip_bfloat16 h = __float2bfloat16(f);
    return *reinterpret_cast<ushort*>(&h);
}
__device__ inline float bf2f(ushort u) {
    unsigned int v = ((unsigned int)u) << 16;
    return __uint_as_float(v);
}

// ---------------------------------------------------------------------------
// MERGED (r12): all weight packs + pool zero + x->channel-last transpose.
// Blocks [0,6148): pack ranges [dc 3x3][c2 3x3][c1 1x1][f 1x1][pool zero].
// Blocks [6148, 6148+2048): to_chlast for x (C=512), flat -> (px, c0, b).
// Block-uniform branch; barrier only in transpose branch.
// ---------------------------------------------------------------------------
__global__ __launch_bounds__(256) void pack_and_chlast(
    const float* __restrict__ dc_w, ushort* __restrict__ wdcp,
    const float* __restrict__ c2_w, ushort* __restrict__ wc2p,
    const float* __restrict__ c1_w, ushort* __restrict__ wc1b,
    const float* __restrict__ f_w,  ushort* __restrict__ wfb,
    float* __restrict__ pool,
    const float* __restrict__ x, ushort* __restrict__ xbf)
{
    constexpr int PACK_BLKS = 6148;
    constexpr int T_DC = 9 * 16 * 256 * 32;   // 1179648
    constexpr int T_C2 = 9 * 8 * 128 * 32;    // 294912
    constexpr int T_C1 = 32768;
    constexpr int T_F  = 65536;
    const int tid = threadIdx.x;
    __shared__ float sT[64][65];

    if (blockIdx.x < PACK_BLKS) {
        int idx = blockIdx.x * 256 + tid;
        if (idx < T_DC) {
            const int ci_in = idx & 31;
            int rest = idx >> 5;
            const int co = rest % 256; rest /= 256;
            const int cc = rest % 16;
            const int tap = rest / 16;
            wdcp[idx] = f2bf(dc_w[((size_t)co * 512 + cc * 32 + ci_in) * 9 + tap]);
            return;
        }
        idx -= T_DC;
        if (idx < T_C2) {
            const int ci_in = idx & 31;
            int rest = idx >> 5;
            const int co = rest % 128; rest /= 128;
            const int cc = rest % 8;
            const int tap = rest / 8;
            wc2p[idx] = f2bf(c2_w[((size_t)co * 256 + cc * 32 + ci_in) * 9 + tap]);
            return;
        }
        idx -= T_C2;
        if (idx < T_C1) { wc1b[idx] = f2bf(c1_w[idx]); return; }
        idx -= T_C1;
        if (idx < T_F) {
            const int co = idx >> 8, k = idx & 255;
            wfb[idx] = f2bf(f_w[co * 384 + k]);
            return;
        }
        idx -= T_F;
        if (idx < 1024) pool[idx] = 0.f;
        return;
    }

    // ---- to_chlast branch: flat f -> (p-block, c-block, batch), C=512
    const int f = blockIdx.x - PACK_BLKS;     // 0..2047
    const int p0 = (f & 63) * 64;
    const int c0 = ((f >> 6) & 7) * 64;
    const int b  = f >> 9;
    for (int i = tid; i < 4096; i += 256) {
        const int ch = i >> 6, px = i & 63;
        sT[ch][px] = x[(size_t)(b * 512 + c0 + ch) * HW + p0 + px];
    }
    __syncthreads();
    const int px = tid >> 2, seg = tid & 3;
    ushort tmp[16];
    #pragma unroll
    for (int j = 0; j < 16; ++j) tmp[j] = f2bf(sT[seg * 16 + j][px]);
    ushort* d = xbf + (size_t)(b * HW + p0 + px) * 512 + c0 + seg * 16;
    *(uint4*)d = *(uint4*)&tmp[0];
    *(uint4*)(d + 8) = *(uint4*)&tmp[8];
}

// ---------------------------------------------------------------------------
// MFMA implicit-GEMM 3x3 conv, FULL-K, fused BN+PReLU epilogue (dc only).
// r9-verified (76.8us dc / WRITE 10MB / VGPR 52).
// COMPILER FACT (r5, r8, twice-confirmed): any staging array whose elements
// are all live simultaneously gets spilled to scratch (WRITE 278-288 MB,
// 126us); only load->immediate-consume staging stays in registers.
// ---------------------------------------------------------------------------
template<int CIN, int COUT, int COTILE, int DIL, int ROWS, int OMODE>
__global__ __launch_bounds__(256, OMODE == 0 ? 4 : 2) void conv3x3_fused(
    const ushort* __restrict__ xin,   // [b][64][64][CIN] bf16
    const ushort* __restrict__ wpk,   // [9][CIN/32][COUT][32] bf16
    const float* __restrict__ bias, const float* __restrict__ bng,
    const float* __restrict__ bnb, const float* __restrict__ bnm,
    const float* __restrict__ bnv, const float* __restrict__ al,
    void* __restrict__ outv,
    float* __restrict__ pool)         // [4][256] sums (OMODE 0 only)
{
    constexpr int HR = ROWS + 2 * DIL;
    constexpr int NC = 64 + 2 * DIL;
    constexpr int MT = COTILE / 16;
    constexpr int WPR = 4 / ROWS;
    constexpr int NT = ROWS;
    constexpr int SAS = 40;
    constexpr int CH = CIN / 32;
    constexpr int NA = HR * NC * 4;
    constexpr int NREG = (NA + 255) / 256;
    constexpr int WCH = 9 * MT * 64;
    constexpr int WPT = (WCH + 255) / 256;

    const int tid = threadIdx.x;
    const int wave = tid >> 6, lane = tid & 63;
    const int l15 = lane & 15, quad = lane >> 4;
    const int b = blockIdx.z;
    const int cob = blockIdx.y;
    const int co0 = cob * COTILE;
    const int h0 = blockIdx.x * ROWS;
    const int row = wave / WPR;
    const int ntbase = (wave % WPR) * NT;

    __shared__ __align__(16) ushort sA[HR * NC * SAS];
    __shared__ __align__(16) ushort sW[WCH * 8];

    f32x4 acc[MT][NT];
    #pragma unroll
    for (int mt = 0; mt < MT; ++mt)
        #pragma unroll
        for (int nt = 0; nt < NT; ++nt) acc[mt][nt] = (f32x4){0.f, 0.f, 0.f, 0.f};

    #pragma unroll 1
    for (int cc = 0; cc < CH; ++cc) {
        if (cc != 0) __syncthreads();
        #pragma unroll
        for (int k = 0; k < NREG; ++k) {
            const int i = tid + k * 256;
            if (i < NA) {
                const int p = i >> 2, seg = i & 3;
                const int r = p / NC, c = p - r * NC;
                const int grow = h0 - DIL + r, gcol = c - DIL;
                uint4 val = {0u, 0u, 0u, 0u};
                if (grow >= 0 && grow < 64 && gcol >= 0 && gcol < 64)
                    val = *(const uint4*)&xin[((size_t)(b * 64 + grow) * 64 + gcol) * CIN
                                              + cc * 32 + seg * 8];
                *(uint4*)&sA[p * SAS + seg * 8] = val;
            }
        }
        #pragma unroll
        for (int k = 0; k < WPT; ++k) {
            const int i = tid + k * 256;
            if (i < WCH) {
                const int tap = i / (MT * 64);
                const int r = i - tap * (MT * 64);
                const int mt = r >> 6, n = r & 63;
                const uint4 wv = *(const uint4*)&wpk[
                    ((size_t)(tap * (CIN / 32) + cc) * COUT + co0 + mt * 16 + (n & 15)) * 32
                    + (n >> 4) * 8];
                *(uint4*)&sW[i * 8] = wv;
            }
        }
        __syncthreads();

        #pragma unroll
        for (int tap = 0; tap < 9; ++tap) {
            const int ty = tap / 3, tx = tap - ty * 3;
            const int rl = row + ty * DIL;
            bf16x8 wf[MT];
            #pragma unroll
            for (int mt = 0; mt < MT; ++mt)
                wf[mt] = *(const bf16x8*)&sW[((tap * MT + mt) * 64 + lane) * 8];
            #pragma unroll
            for (int nt = 0; nt < NT; ++nt) {
                const int cl = (ntbase + nt) * 16 + l15 + tx * DIL;
                const bf16x8 bp = *(const bf16x8*)&sA[(rl * NC + cl) * SAS + quad * 8];
                #pragma unroll
                for (int mt = 0; mt < MT; ++mt)
                    acc[mt][nt] = __builtin_amdgcn_mfma_f32_16x16x32_bf16(
                        wf[mt], bp, acc[mt][nt], 0, 0, 0);
            }
        }
    }

    const float a = al[0];

    if constexpr (OMODE == 0) {
        __syncthreads();
        ushort* sT = sA;
        #pragma unroll
        for (int mt = 0; mt < MT; ++mt) {
            float sc[4], sh[4], psum[4];
            #pragma unroll
            for (int rr = 0; rr < 4; ++rr) {
                const int co = co0 + mt * 16 + quad * 4 + rr;
                sc[rr] = bng[co] * rsqrtf(bnv[co] + EPSV);
                sh[rr] = (bias[co] - bnm[co]) * sc[rr] + bnb[co];
                psum[rr] = 0.f;
            }
            #pragma unroll
            for (int nt = 0; nt < NT; ++nt) {
                float tv[4];
                #pragma unroll
                for (int rr = 0; rr < 4; ++rr) {
                    float t = acc[mt][nt][rr] * sc[rr] + sh[rr];
                    t = t >= 0.f ? t : a * t;
                    tv[rr] = t;
                    psum[rr] += t;
                }
                ushort4 u;
                u.x = f2bf(tv[0]); u.y = f2bf(tv[1]);
                u.z = f2bf(tv[2]); u.w = f2bf(tv[3]);
                const int px = (ntbase + nt) * 16 + l15;
                *(ushort4*)&sT[(row * 64 + px) * 40 + mt * 16 + quad * 4] = u;
            }
            #pragma unroll
            for (int rr = 0; rr < 4; ++rr) {
                float v = psum[rr];
                v += __shfl_xor(v, 1);
                v += __shfl_xor(v, 2);
                v += __shfl_xor(v, 4);
                v += __shfl_xor(v, 8);
                if (l15 == 0)
                    atomicAdd(&pool[b * 256 + co0 + mt * 16 + quad * 4 + rr], v);
            }
        }
        __syncthreads();
        ushort* dst = (ushort*)outv;
        const int p = tid >> 1, half = tid & 1;
        const uint4 v0 = *(const uint4*)&sT[p * 40 + half * 16];
        const uint4 v1 = *(const uint4*)&sT[p * 40 + half * 16 + 8];
        const size_t off = ((size_t)(b * 4096 + (h0 + (p >> 6)) * 64 + (p & 63))) * 256
                           + co0 + half * 16;
        *(uint4*)&dst[off] = v0;
        *(uint4*)&dst[off + 8] = v1;
    } else {
        float* out = (float*)outv;
        #pragma unroll
        for (int mt = 0; mt < MT; ++mt)
            #pragma unroll
            for (int rr = 0; rr < 4; ++rr) {
                const int co = co0 + mt * 16 + quad * 4 + rr;
                const float sc = bng[co] * rsqrtf(bnv[co] + EPSV);
                const float sh = (bias[co] - bnm[co]) * sc + bnb[co];
                #pragma unroll
                for (int nt = 0; nt < NT; ++nt) {
                    float t = acc[mt][nt][rr] * sc + sh;
                    t = t >= 0.f ? t : a * t;
                    out[((size_t)(b * COUT + co) * 64 + h0 + row) * 64
                        + (ntbase + nt) * 16 + l15] = t;
                }
            }
    }
}

// ---------------------------------------------------------------------------
// MERGED (r12): c2 dilated conv + c1 gemm + c3 fbias in ONE launch.
// Grid (49, 4, 4):
//   x < 32            -> c2 conv body (CIN=256,COUT=128,COTILE=32,DIL=2,ROWS=2)
//   x >= 32           -> flat = (z*4+y)*17 + (x-32) in [0,272); skip >=260;
//                        bx=flat%130, by=flat/130 -> c1 gemm / c3 blocks.
// All inputs from the dc-conv launch; outputs disjoint (c2b | catb[:,0:128],
// fbb) -> race-free.  LDS unioned in one 51072-B buffer.
// ---------------------------------------------------------------------------
__global__ __launch_bounds__(256, 2) void c2_c1_c3(
    const ushort* __restrict__ xin,    // xpbf [b][64][64][256]
    const ushort* __restrict__ wpk,    // wc2p
    const float* __restrict__ c2bias, const float* __restrict__ c2gn,
    const float* __restrict__ c2bt, const float* __restrict__ c2mn,
    const float* __restrict__ c2vr, const float* __restrict__ c2al,
    float* __restrict__ c2out,
    const ushort* __restrict__ wbf,    // wc1b
    const float* __restrict__ bias, const float* __restrict__ bng,
    const float* __restrict__ bnb, const float* __restrict__ bnm,
    const float* __restrict__ bnv, const float* __restrict__ al,
    ushort* __restrict__ catb,
    const float* __restrict__ pool, const float* __restrict__ c3w,
    const float* __restrict__ c3b, const float* __restrict__ c3g,
    const float* __restrict__ c3bt, const float* __restrict__ c3m,
    const float* __restrict__ c3v, const float* __restrict__ c3a,
    const float* __restrict__ fw, float* __restrict__ fbias)
{
    const int tid = threadIdx.x;
    const int wave = tid >> 6, lane = tid & 63;
    const int l15 = lane & 15, quad = lane >> 4;
    __shared__ __align__(16) char smem[51072];

    if (blockIdx.x < 32) {
        // ================= c2 conv body =================
        constexpr int CIN = 256, COUT = 128, COTILE = 32, DIL = 2, ROWS = 2;
        constexpr int HR = ROWS + 2 * DIL;      // 6
        constexpr int NC = 64 + 2 * DIL;        // 68
        constexpr int MT = COTILE / 16;         // 2
        constexpr int WPR = 4 / ROWS;           // 2
        constexpr int NT = ROWS;                // 2
        constexpr int SAS = 40;
        constexpr int CH = CIN / 32;            // 8
        constexpr int NA = HR * NC * 4;         // 1632
        constexpr int NREG = (NA + 255) / 256;  // 7
        constexpr int WCH = 9 * MT * 64;        // 1152
        constexpr int WPT = (WCH + 255) / 256;  // 5

        ushort* sA = (ushort*)smem;                    // 32640 B
        ushort* sW = (ushort*)(smem + 32640);          // 18432 B

        const int b = blockIdx.z;
        const int co0 = blockIdx.y * COTILE;
        const int h0 = blockIdx.x * ROWS;
        const int row = wave / WPR;
        const int ntbase = (wave % WPR) * NT;

        f32x4 acc[MT][NT];
        #pragma unroll
        for (int mt = 0; mt < MT; ++mt)
            #pragma unroll
            for (int nt = 0; nt < NT; ++nt) acc[mt][nt] = (f32x4){0.f, 0.f, 0.f, 0.f};

        #pragma unroll 1
        for (int cc = 0; cc < CH; ++cc) {
            if (cc != 0) __syncthreads();
            #pragma unroll
            for (int k = 0; k < NREG; ++k) {
                const int i = tid + k * 256;
                if (i < NA) {
                    const int p = i >> 2, seg = i & 3;
                    const int r = p / NC, c = p - r * NC;
                    const int grow = h0 - DIL + r, gcol = c - DIL;
                    uint4 val = {0u, 0u, 0u, 0u};
                    if (grow >= 0 && grow < 64 && gcol >= 0 && gcol < 64)
                        val = *(const uint4*)&xin[((size_t)(b * 64 + grow) * 64 + gcol) * CIN
                                                  + cc * 32 + seg * 8];
                    *(uint4*)&sA[p * SAS + seg * 8] = val;
                }
            }
            #pragma unroll
            for (int k = 0; k < WPT; ++k) {
                const int i = tid + k * 256;
                if (i < WCH) {
                    const int tap = i / (MT * 64);
                    const int r = i - tap * (MT * 64);
                    const int mt = r >> 6, n = r & 63;
                    const uint4 wv = *(const uint4*)&wpk[
                        ((size_t)(tap * (CIN / 32) + cc) * COUT + co0 + mt * 16 + (n & 15)) * 32
                        + (n >> 4) * 8];
                    *(uint4*)&sW[i * 8] = wv;
                }
            }
            __syncthreads();

            #pragma unroll
            for (int tap = 0; tap < 9; ++tap) {
                const int ty = tap / 3, tx = tap - ty * 3;
                const int rl = row + ty * DIL;
                bf16x8 wf[MT];
                #pragma unroll
                for (int mt = 0; mt < MT; ++mt)
                    wf[mt] = *(const bf16x8*)&sW[((tap * MT + mt) * 64 + lane) * 8];
                #pragma unroll
                for (int nt = 0; nt < NT; ++nt) {
                    const int cl = (ntbase + nt) * 16 + l15 + tx * DIL;
                    const bf16x8 bp = *(const bf16x8*)&sA[(rl * NC + cl) * SAS + quad * 8];
                    #pragma unroll
                    for (int mt = 0; mt < MT; ++mt)
                        acc[mt][nt] = __builtin_amdgcn_mfma_f32_16x16x32_bf16(
                            wf[mt], bp, acc[mt][nt], 0, 0, 0);
                }
            }
        }

        const float a = c2al[0];
        #pragma unroll
        for (int mt = 0; mt < MT; ++mt)
            #pragma unroll
            for (int rr = 0; rr < 4; ++rr) {
                const int co = co0 + mt * 16 + quad * 4 + rr;
                const float sc = c2gn[co] * rsqrtf(c2vr[co] + EPSV);
                const float sh = (c2bias[co] - c2mn[co]) * sc + c2bt[co];
                #pragma unroll
                for (int nt = 0; nt < NT; ++nt) {
                    float t = acc[mt][nt][rr] * sc + sh;
                    t = t >= 0.f ? t : a * t;
                    c2out[((size_t)(b * COUT + co) * 64 + h0 + row) * 64
                          + (ntbase + nt) * 16 + l15] = t;
                }
            }
        return;
    }

    // ================= c1 / c3 blocks =================
    const int flat = (blockIdx.z * 4 + blockIdx.y) * 17 + (blockIdx.x - 32);
    if (flat >= 260) return;
    const int bx = flat % 130, by = flat / 130;

    if (bx >= 128) {
        // ---- c3 branch bias for b = (bx-128)*2 + by
        const int b = (bx - 128) * 2 + by;
        float* sp  = (float*)smem;            // 1024 B
        float* sc3 = (float*)(smem + 2048);   // 512 B
        sp[tid] = pool[b * 256 + tid] * (1.0f / 4096.0f);
        __syncthreads();
        if (tid < 128) {
            float acc2 = c3b[tid];
            for (int ci = 0; ci < 256; ++ci) acc2 = fmaf(c3w[tid * 256 + ci], sp[ci], acc2);
            const float scale = c3g[tid] * rsqrtf(c3v[tid] + EPSV);
            float t = (acc2 - c3m[tid]) * scale + c3bt[tid];
            const float a2 = c3a[0];
            sc3[tid] = t >= 0.f ? t : a2 * t;
        }
        __syncthreads();
        float f = 0.f;
        for (int j2 = 0; j2 < 128; ++j2) f = fmaf(fw[tid * 384 + 256 + j2], sc3[j2], f);
        fbias[b * 256 + tid] = f;
        return;
    }

    // ---- c1 gemm (CIN=256, COUT=128, BN+PReLU, bf16 ch-last out at col 0)
    {
        constexpr int CIN = 256;
        const int pix0 = bx * 128 + wave * 32;
        const int co0 = by * 64;

        f32x4 acc[4][2];
        #pragma unroll
        for (int mt = 0; mt < 4; ++mt)
            #pragma unroll
            for (int nt = 0; nt < 2; ++nt) acc[mt][nt] = (f32x4){0.f, 0.f, 0.f, 0.f};

        #pragma unroll 2
        for (int cc = 0; cc < CIN / 32; ++cc) {
            bf16x8 aw[4], bp[2];
            #pragma unroll
            for (int mt = 0; mt < 4; ++mt)
                aw[mt] = *(const bf16x8*)&wbf[(size_t)(co0 + mt * 16 + l15) * CIN + cc * 32 + quad * 8];
            #pragma unroll
            for (int nt = 0; nt < 2; ++nt)
                bp[nt] = *(const bf16x8*)&xin[(size_t)(pix0 + nt * 16 + l15) * CIN + cc * 32 + quad * 8];
            #pragma unroll
            for (int mt = 0; mt < 4; ++mt)
                #pragma unroll
                for (int nt = 0; nt < 2; ++nt)
                    acc[mt][nt] = __builtin_amdgcn_mfma_f32_16x16x32_bf16(
                        aw[mt], bp[nt], acc[mt][nt], 0, 0, 0);
        }

        const float a = al[0];
        ushort* sT = (ushort*)smem;          // [4][32][68] = 17408 B
        #pragma unroll
        for (int mt = 0; mt < 4; ++mt)
            #pragma unroll
            for (int r = 0; r < 4; ++r) {
                const int co = co0 + mt * 16 + quad * 4 + r;
                const float scale = bng[co] * rsqrtf(bnv[co] + EPSV);
                const float shift = bias[co] * scale + (bnb[co] - bnm[co] * scale);
                #pragma unroll
                for (int nt = 0; nt < 2; ++nt) {
                    float t = acc[mt][nt][r] * scale + shift;
                    t = t >= 0.f ? t : a * t;
                    sT[((wave * 32 + nt * 16 + l15) * 68) + mt * 16 + quad * 4 + r] = f2bf(t);
                }
            }
        __syncthreads();
        const int p = lane >> 1, half = lane & 1;
        #pragma unroll
        for (int seg = 0; seg < 4; ++seg) {
            uint2 a0 = *(uint2*)&sT[((wave * 32 + p) * 68) + half * 32 + seg * 8];
            uint2 a1 = *(uint2*)&sT[((wave * 32 + p) * 68) + half * 32 + seg * 8 + 4];
            uint4 vv = {a0.x, a0.y, a1.x, a1.y};
            *(uint4*)&catb[(size_t)(pix0 + p) * 256 + co0 + half * 32 + seg * 8] = vv;
        }
    }
}

// ---------------------------------------------------------------------------
// MFMA 1x1 conv on channel-last bf16 input (used for the FUSE conv, OMODE 0).
// ---------------------------------------------------------------------------
template<int CIN, int COUT, bool BNACT, int OMODE>
__global__ __launch_bounds__(256) void gemm1x1_cl(
    const ushort* __restrict__ xin,   // [16384][CIN] bf16
    const ushort* __restrict__ wbf,   // [COUT][CIN] bf16
    const float* __restrict__ bias, const float* __restrict__ bng,
    const float* __restrict__ bnb, const float* __restrict__ bnm,
    const float* __restrict__ bnv, const float* __restrict__ al,
    const float* __restrict__ ebias, void* __restrict__ outv,
    int ostride, int ocol)
{
    const int tid = threadIdx.x;
    const int wave = tid >> 6, lane = tid & 63;
    const int l15 = lane & 15, quad = lane >> 4;
    const int pix0 = blockIdx.x * 128 + wave * 32;
    const int co0 = blockIdx.y * 64;

    f32x4 acc[4][2];
    #pragma unroll
    for (int mt = 0; mt < 4; ++mt)
        #pragma unroll
        for (int nt = 0; nt < 2; ++nt) acc[mt][nt] = (f32x4){0.f, 0.f, 0.f, 0.f};

    #pragma unroll 2
    for (int cc = 0; cc < CIN / 32; ++cc) {
        bf16x8 aw[4], bp[2];
        #pragma unroll
        for (int mt = 0; mt < 4; ++mt)
            aw[mt] = *(const bf16x8*)&wbf[(size_t)(co0 + mt * 16 + l15) * CIN + cc * 32 + quad * 8];
        #pragma unroll
        for (int nt = 0; nt < 2; ++nt)
            bp[nt] = *(const bf16x8*)&xin[(size_t)(pix0 + nt * 16 + l15) * CIN + cc * 32 + quad * 8];
        #pragma unroll
        for (int mt = 0; mt < 4; ++mt)
            #pragma unroll
            for (int nt = 0; nt < 2; ++nt)
                acc[mt][nt] = __builtin_amdgcn_mfma_f32_16x16x32_bf16(
                    aw[mt], bp[nt], acc[mt][nt], 0, 0, 0);
    }

    const int bI = pix0 >> 12;
    const float a = BNACT ? al[0] : 0.f;

    if (OMODE == 0) {
        float* out = (float*)outv;
        #pragma unroll
        for (int mt = 0; mt < 4; ++mt)
            #pragma unroll
            for (int r = 0; r < 4; ++r) {
                const int co = co0 + mt * 16 + quad * 4 + r;
                float bb = bias[co];
                if (ebias) bb += ebias[bI * COUT + co];
                float scale = 1.f, shift = bb;
                if (BNACT) {
                    scale = bng[co] * rsqrtf(bnv[co] + EPSV);
                    shift = bb * scale + (bnb[co] - bnm[co] * scale);
                }
                #pragma unroll
                for (int nt = 0; nt < 2; ++nt) {
                    float t = acc[mt][nt][r] * scale + shift;
                    if (BNACT) t = t >= 0.f ? t : a * t;
                    out[((size_t)(bI * COUT + co)) * HW + (pix0 & 4095) + nt * 16 + l15] = t;
                }
            }
    } else {
        __shared__ ushort sT[4][32][68];
        #pragma unroll
        for (int mt = 0; mt < 4; ++mt)
            #pragma unroll
            for (int r = 0; r < 4; ++r) {
                const int co = co0 + mt * 16 + quad * 4 + r;
                float bb = bias[co];
                float scale = 1.f, shift = bb;
                if (BNACT) {
                    scale = bng[co] * rsqrtf(bnv[co] + EPSV);
                    shift = bb * scale + (bnb[co] - bnm[co] * scale);
                }
                #pragma unroll
                for (int nt = 0; nt < 2; ++nt) {
                    float t = acc[mt][nt][r] * scale + shift;
                    if (BNACT) t = t >= 0.f ? t : a * t;
                    sT[wave][nt * 16 + l15][mt * 16 + quad * 4 + r] = f2bf(t);
                }
            }
        __syncthreads();
        const int p = lane >> 1, half = lane & 1;
        ushort* out = (ushort*)outv;
        #pragma unroll
        for (int seg = 0; seg < 4; ++seg) {
            uint2 a0 = *(uint2*)&sT[wave][p][half * 32 + seg * 8];
            uint2 a1 = *(uint2*)&sT[wave][p][half * 32 + seg * 8 + 4];
            uint4 vv = {a0.x, a0.y, a1.x, a1.y};
            *(uint4*)&out[(size_t)(pix0 + p) * ostride + ocol + co0 + half * 32 + seg * 8] = vv;
        }
    }
}

// ---------------------------------------------------------------------------
// qk + v in ONE launch (r10-verified structure).  Grid (64, 3, 4).
// ---------------------------------------------------------------------------
__global__ __launch_bounds__(256) void qkv_kernel(
    const float* __restrict__ c2g, const float* __restrict__ qw,
    const float* __restrict__ qb2, const float* __restrict__ kw,
    const float* __restrict__ kb2, ushort* __restrict__ qpack,
    ushort* __restrict__ kpack,
    const float* __restrict__ vw, const float* __restrict__ vb,
    ushort* __restrict__ vbh)
{
    const int tid = threadIdx.x;
    const int b = blockIdx.z, p0 = blockIdx.x * 64;
    __shared__ __align__(16) char smem[49152];

    if (blockIdx.y == 0) {
        float (*sC)[64]   = (float(*)[64])smem;
        float (*sWq)[128] = (float(*)[128])(smem + 32768);
        float (*sWk)[128] = (float(*)[128])(smem + 40960);
        for (int i = tid; i < 8192; i += 256) {
            const int px = i & 63, ci = i >> 6;
            sC[ci][px] = c2g[(size_t)(b * 128 + ci) * HW + p0 + px];
        }
        for (int i = tid; i < 2048; i += 256) {
            const int ci = i & 127, co = i >> 7;
            sWq[co][ci] = qw[co * 128 + ci];
            sWk[co][ci] = kw[co * 128 + ci];
        }
        __syncthreads();
        const int px = tid & 63, grp = tid >> 6;
        const int co0 = (grp & 1) * 8;
        const bool isK = grp >= 2;
        const float* sWp = isK ? &sWk[0][0] : &sWq[0][0];
        float acc[8] = {};
        for (int ci = 0; ci < 128; ++ci) {
            const float xv = sC[ci][px];
            #pragma unroll
            for (int j = 0; j < 8; ++j)
                acc[j] = fmaf(sWp[(co0 + j) * 128 + ci], xv, acc[j]);
        }
        const float* bsrc = isK ? kb2 : qb2;
        ushort* osrc = isK ? kpack : qpack;
        const size_t base = (size_t)(b * 4096 + p0 + px) * 32;
        #pragma unroll
        for (int j = 0; j < 8; ++j) {
            osrc[base + co0 + j] = f2bf(acc[j] + bsrc[co0 + j]);
            osrc[base + 16 + co0 + j] = 0;
        }
    } else {
        const int co0 = (blockIdx.y - 1) * 64;
        float* sIn = (float*)smem;
        float* sW  = (float*)(smem + 16384);
        const int cg = tid >> 4, pg = tid & 15;
        const int c0l = cg * 4, w0 = pg * 4;
        float acc[4][4] = {};
        for (int cc = 0; cc < 128; cc += 16) {
            {
                int i = tid;
                #pragma unroll
                for (int it = 0; it < 4; ++it, i += 256) {
                    const int px = i & 63, ci = i >> 6;
                    sIn[ci * 64 + px] = c2g[(size_t)(b * 128 + cc + ci) * HW + p0 + px];
                }
                i = tid;
                #pragma unroll
                for (int it = 0; it < 4; ++it, i += 256) {
                    const int ci = i & 15, co = i >> 4;
                    sW[ci * 68 + co] = vw[(co0 + co) * 128 + cc + ci];
                }
            }
            __syncthreads();
            #pragma unroll
            for (int ci = 0; ci < 16; ++ci) {
                const float4 iv = *(const float4*)&sIn[ci * 64 + w0];
                const float4 wv = *(const float4*)&sW[ci * 68 + c0l];
                const float ia[4] = {iv.x, iv.y, iv.z, iv.w};
                const float wa[4] = {wv.x, wv.y, wv.z, wv.w};
                #pragma unroll
                for (int i2 = 0; i2 < 4; ++i2)
                    #pragma unroll
                    for (int j = 0; j < 4; ++j)
                        acc[i2][j] = fmaf(wa[i2], ia[j], acc[i2][j]);
            }
            __syncthreads();
        }
        #pragma unroll
        for (int i2 = 0; i2 < 4; ++i2) {
            const int co = co0 + c0l + i2;
            const float shift = vb[co];
            const size_t base = (size_t)(b * 128 + co) * HW + p0 + w0;
            #pragma unroll
            for (int j = 0; j < 4; ++j)
                vbh[base + j] = f2bf(acc[i2][j] + shift);
        }
    }
}

// ---------------------------------------------------------------------------
// SINGLE-PASS flash attention (r8/r9-verified): online softmax + defer-max.
// Grid: (32 nblk, 8 msplit, 4 batch).
// ---------------------------------------------------------------------------
__global__ __launch_bounds__(256) void attn_flash(
    const ushort* __restrict__ qpack,
    const ushort* __restrict__ kpack,
    const ushort* __restrict__ vpackT,
    ushort* __restrict__ opart,       // [b][8j][4096n][128c] bf16
    float* __restrict__ Mpart,        // [b][8j][4096n]
    float* __restrict__ Spart)
{
    const int tid = threadIdx.x;
    const int wave = tid >> 6, lane = tid & 63;
    const int l15 = lane & 15, quad = lane >> 4;
    const int b = blockIdx.z, j = blockIdx.y;
    const int n0w = blockIdx.x * 128 + wave * 32;
    const int m_begin = j * 512;

    __shared__ __align__(16) ushort sV[2][128][40];
    __shared__ __align__(16) ushort sP[4][2][16][40];

    const bf16x8 bq0 = *(const bf16x8*)(qpack + ((size_t)(b * 4096 + n0w + l15) * 32 + quad * 8));
    const bf16x8 bq1 = *(const bf16x8*)(qpack + ((size_t)(b * 4096 + n0w + 16 + l15) * 32 + quad * 8));
    const f32x4 z = {0.f, 0.f, 0.f, 0.f};

    float runM0 = -3e30f, runM1 = -3e30f;
    float runS0 = 0.f, runS1 = 0.f;
    f32x4 oacc0[8], oacc1[8];
    #pragma unroll
    for (int cs = 0; cs < 8; ++cs) {
        oacc0[cs] = (f32x4){0.f, 0.f, 0.f, 0.f};
        oacc1[cs] = (f32x4){0.f, 0.f, 0.f, 0.f};
    }

    const int stc = tid >> 1, stseg = tid & 1;

    {
        uint4 v0 = *(const uint4*)&vpackT[(size_t)(b * 128 + stc) * HW + m_begin + stseg * 16];
        uint4 v1 = *(const uint4*)&vpackT[(size_t)(b * 128 + stc) * HW + m_begin + stseg * 16 + 8];
        *(uint4*)&sV[0][stc][stseg * 16] = v0;
        *(uint4*)&sV[0][stc][stseg * 16 + 8] = v1;
    }
    __syncthreads();

    #pragma unroll 1
    for (int t = 0; t < 16; ++t) {
        const int m0 = m_begin + t * 32;
        const int buf = t & 1;
        uint4 nv0, nv1;
        const bool more = (t + 1 < 16);
        if (more) {
            const size_t nb = (size_t)(b * 128 + stc) * HW + m0 + 32 + stseg * 16;
            nv0 = *(const uint4*)&vpackT[nb];
            nv1 = *(const uint4*)&vpackT[nb + 8];
        }
        f32x4 s0[2], s1[2];
        #pragma unroll
        for (int ms = 0; ms < 2; ++ms) {
            const bf16x8 ak = *(const bf16x8*)(
                kpack + ((size_t)(b * 4096 + m0 + ms * 16 + l15) * 32 + quad * 8));
            s0[ms] = __builtin_amdgcn_mfma_f32_16x16x32_bf16(ak, bq0, z, 0, 0, 0);
            s1[ms] = __builtin_amdgcn_mfma_f32_16x16x32_bf16(ak, bq1, z, 0, 0, 0);
        }

        // ---- online max update with defer (THR=8 -> P <= e^8, bf16-safe)
        float tM0 = fmaxf(fmaxf(fmaxf(s0[0][0], s0[0][1]), fmaxf(s0[0][2], s0[0][3])),
                          fmaxf(fmaxf(s0[1][0], s0[1][1]), fmaxf(s0[1][2], s0[1][3])));
        float tM1 = fmaxf(fmaxf(fmaxf(s1[0][0], s1[0][1]), fmaxf(s1[0][2], s1[0][3])),
                          fmaxf(fmaxf(s1[1][0], s1[1][1]), fmaxf(s1[1][2], s1[1][3])));
        tM0 = fmaxf(tM0, __shfl_xor(tM0, 16));
        tM0 = fmaxf(tM0, __shfl_xor(tM0, 32));
        tM1 = fmaxf(tM1, __shfl_xor(tM1, 16));
        tM1 = fmaxf(tM1, __shfl_xor(tM1, 32));
        if (__any(tM0 > runM0 + 8.f)) {
            const float nM = fmaxf(runM0, tM0);
            const float sc = __builtin_amdgcn_exp2f((runM0 - nM) * 1.44269504f);
            runS0 *= sc;
            float scr[4];
            #pragma unroll
            for (int r = 0; r < 4; ++r) scr[r] = __shfl(sc, quad * 4 + r);
            #pragma unroll
            for (int cs = 0; cs < 8; ++cs) {
                oacc0[cs][0] *= scr[0]; oacc0[cs][1] *= scr[1];
                oacc0[cs][2] *= scr[2]; oacc0[cs][3] *= scr[3];
            }
            runM0 = nM;
        }
        if (__any(tM1 > runM1 + 8.f)) {
            const float nM = fmaxf(runM1, tM1);
            const float sc = __builtin_amdgcn_exp2f((runM1 - nM) * 1.44269504f);
            runS1 *= sc;
            float scr[4];
            #pragma unroll
            for (int r = 0; r < 4; ++r) scr[r] = __shfl(sc, quad * 4 + r);
            #pragma unroll
            for (int cs = 0; cs < 8; ++cs) {
                oacc1[cs][0] *= scr[0]; oacc1[cs][1] *= scr[1];
                oacc1[cs][2] *= scr[2]; oacc1[cs][3] *= scr[3];
            }
            runM1 = nM;
        }
        const float Ms0 = runM0 * 1.44269504f;
        const float Ms1 = runM1 * 1.44269504f;

        #pragma unroll
        for (int ms = 0; ms < 2; ++ms) {
            float p0[4], p1[4];
            #pragma unroll
            for (int r = 0; r < 4; ++r) {
                p0[r] = __builtin_amdgcn_exp2f(fmaf(s0[ms][r], 1.44269504f, -Ms0));
                p1[r] = __builtin_amdgcn_exp2f(fmaf(s1[ms][r], 1.44269504f, -Ms1));
                runS0 += p0[r];
                runS1 += p1[r];
            }
            ushort4 u0, u1;
            u0.x = f2bf(p0[0]); u0.y = f2bf(p0[1]); u0.z = f2bf(p0[2]); u0.w = f2bf(p0[3]);
            u1.x = f2bf(p1[0]); u1.y = f2bf(p1[1]); u1.z = f2bf(p1[2]); u1.w = f2bf(p1[3]);
            *(uint2*)&sP[wave][0][l15][ms * 16 + quad * 4] = *(uint2*)&u0;
            *(uint2*)&sP[wave][1][l15][ms * 16 + quad * 4] = *(uint2*)&u1;
        }
        asm volatile("s_waitcnt lgkmcnt(0)" ::: "memory");
        const bf16x8 ap0 = *(const bf16x8*)&sP[wave][0][l15][quad * 8];
        const bf16x8 ap1 = *(const bf16x8*)&sP[wave][1][l15][quad * 8];
        #pragma unroll
        for (int cs = 0; cs < 8; ++cs) {
            const bf16x8 bv = *(const bf16x8*)&sV[buf][cs * 16 + l15][quad * 8];
            oacc0[cs] = __builtin_amdgcn_mfma_f32_16x16x32_bf16(ap0, bv, oacc0[cs], 0, 0, 0);
            oacc1[cs] = __builtin_amdgcn_mfma_f32_16x16x32_bf16(ap1, bv, oacc1[cs], 0, 0, 0);
        }
        if (more) {
            *(uint4*)&sV[buf ^ 1][stc][stseg * 16] = nv0;
            *(uint4*)&sV[buf ^ 1][stc][stseg * 16 + 8] = nv1;
            __syncthreads();
        }
    }

    runS0 += __shfl_xor(runS0, 16);
    runS0 += __shfl_xor(runS0, 32);
    runS1 += __shfl_xor(runS1, 16);
    runS1 += __shfl_xor(runS1, 32);
    if (lane < 32) {
        const float Mv = (lane < 16) ? runM0 : runM1;
        const float Sv = (lane < 16) ? runS0 : runS1;
        const int n = n0w + ((lane < 16) ? 0 : 16) + l15;
        Mpart[((size_t)b * 8 + j) * 4096 + n] = Mv;
        Spart[((size_t)b * 8 + j) * 4096 + n] = Sv;
    }
    #pragma unroll
    for (int cs = 0; cs < 8; ++cs)
        #pragma unroll
        for (int r = 0; r < 4; ++r) {
            const int n = n0w + quad * 4 + r;
            opart[(((size_t)b * 8 + j) * 4096 + n) * 128 + cs * 16 + l15] = f2bf(oacc0[cs][r]);
            opart[(((size_t)b * 8 + j) * 4096 + n + 16) * 128 + cs * 16 + l15] = f2bf(oacc1[cs][r]);
        }
}

// ---------------------------------------------------------------------------
// Combine 8 m-split partials, normalize, fuse gamma2*O + c2 -> catb[:,128:256]
// ---------------------------------------------------------------------------
__global__ __launch_bounds__(256) void attn_combine(
    const ushort* __restrict__ opart, const float* __restrict__ Mpart,
    const float* __restrict__ Spart, const float* __restrict__ c2g,
    const float* __restrict__ gamma2, ushort* __restrict__ catb)
{
    const int b = blockIdx.y, n0 = blockIdx.x * 32, tid = threadIdx.x;
    __shared__ float sC2[128][33];
    __shared__ float sWj[8][32];
    if (tid < 32) {
        const int n = n0 + tid;
        float Mj[8], Sj[8];
        #pragma unroll
        for (int j = 0; j < 8; ++j) {
            Mj[j] = Mpart[((size_t)b * 8 + j) * 4096 + n];
            Sj[j] = Spart[((size_t)b * 8 + j) * 4096 + n];
        }
        float M = -3e30f;
        #pragma unroll
        for (int j = 0; j < 8; ++j) M = fmaxf(M, Mj[j]);
        float St = 0.f, e[8];
        #pragma unroll
        for (int j = 0; j < 8; ++j) { e[j] = __expf(Mj[j] - M); St += Sj[j] * e[j]; }
        const float inv = 1.0f / St;
        #pragma unroll
        for (int j = 0; j < 8; ++j) sWj[j][tid] = e[j] * inv;
    }
    #pragma unroll
    for (int e = 0; e < 16; ++e) {
        const int idx = tid + e * 256;
        const int c = idx >> 5, n = idx & 31;
        sC2[c][n] = c2g[(size_t)(b * 128 + c) * HW + n0 + n];
    }
    __syncthreads();
    const float g2 = gamma2[0];
    #pragma unroll
    for (int e = 0; e < 16; ++e) {
        const int idx = tid + e * 256;
        const int n = idx >> 7, c = idx & 127;
        float s = 0.f;
        #pragma unroll
        for (int j = 0; j < 8; ++j)
            s += bf2f(opart[(((size_t)b * 8 + j) * 4096 + n0 + n) * 128 + c]) * sWj[j][n];
        catb[(size_t)(b * 4096 + n0 + n) * 256 + 128 + c] = f2bf(fmaf(g2, s, sC2[c][n]));
    }
}

// ---------------------------------------------------------------------------
extern "C" void kernel_launch(void* const* d_in, const int* in_sizes, int n_in,
                              void* d_out, int out_size, void* d_ws, size_t ws_size,
                              hipStream_t stream)
{
    const float* x     = (const float*)d_in[0];
    const float* dc_w  = (const float*)d_in[1];
    const float* dc_b  = (const float*)d_in[2];
    const float* dc_g  = (const float*)d_in[3];
    const float* dc_bt = (const float*)d_in[4];
    const float* dc_m  = (const float*)d_in[5];
    const float* dc_v  = (const float*)d_in[6];
    const float* dc_a  = (const float*)d_in[7];
    const float* c1_w  = (const float*)d_in[8];
    const float* c1_b  = (const float*)d_in[9];
    const float* c1_g  = (const float*)d_in[10];
    const float* c1_bt = (const float*)d_in[11];
    const float* c1_m  = (const float*)d_in[12];
    const float* c1_v  = (const float*)d_in[13];
    const float* c1_a  = (const float*)d_in[14];
    const float* c2_w  = (const float*)d_in[15];
    const float* c2_b  = (const float*)d_in[16];
    const float* c2_g  = (const float*)d_in[17];
    const float* c2_bt = (const float*)d_in[18];
    const float* c2_m  = (const float*)d_in[19];
    const float* c2_v  = (const float*)d_in[20];
    const float* c2_a  = (const float*)d_in[21];
    const float* q_w   = (const float*)d_in[22];
    const float* q_b   = (const float*)d_in[23];
    const float* k_w   = (const float*)d_in[24];
    const float* k_b   = (const float*)d_in[25];
    const float* v_w   = (const float*)d_in[26];
    const float* v_b   = (const float*)d_in[27];
    const float* gamma2= (const float*)d_in[28];
    const float* c3_w  = (const float*)d_in[29];
    const float* c3_b  = (const float*)d_in[30];
    const float* c3_g  = (const float*)d_in[31];
    const float* c3_bt = (const float*)d_in[32];
    const float* c3_m  = (const float*)d_in[33];
    const float* c3_v  = (const float*)d_in[34];
    const float* c3_a  = (const float*)d_in[35];
    const float* f_w   = (const float*)d_in[36];
    const float* f_b   = (const float*)d_in[37];
    const float* f_g   = (const float*)d_in[38];
    const float* f_bt  = (const float*)d_in[39];
    const float* f_m   = (const float*)d_in[40];
    const float* f_v   = (const float*)d_in[41];
    const float* f_a   = (const float*)d_in[42];

    // ---- workspace layout by live range (r5-verified, no aliasing) ----
    char* base = (char*)d_ws;
    ushort* xbf   = (ushort*)base;                       // [4,4096,512] bf16
    ushort* opart = (ushort*)base;                       // [4,8,4096,128] bf16
    ushort* qpk   = (ushort*)(base + 33554432);          // [4,4096,32]
    ushort* kpk   = (ushort*)(base + 34603008);
    ushort* vbh   = (ushort*)(base + 35651584);          // [4,128,4096] bf16
    float*  c2b   = (float*)(base + 39845888);           // [4,128,4096] f32
    ushort* xpbf  = (ushort*)(base + 50331648);          // [4,4096,256] bf16
    ushort* catb  = (ushort*)(base + 58720256);          // [4,4096,256] bf16
    ushort* wdcp  = (ushort*)(base + 75497472);          // [9,16,256,32]
    ushort* wc2p  = (ushort*)(base + 77856768);          // [9,8,128,32]
    ushort* wc1b  = (ushort*)(base + 78446592);          // [128,256]
    ushort* wfb   = (ushort*)(base + 78512128);          // [256,256]
    float*  poolb = (float*)(base + 78643200);           // 1024 (atomic sums)
    float*  fbb   = (float*)(base + 78647296);           // 1024
    float*  Mpart = (float*)(base + 78651392);           // [4,8,4096]
    float*  Spart = (float*)(base + 79175680);           // [4,8,4096]

    // 0. packs + pool zero + x->chlast (ONE launch)
    pack_and_chlast<<<dim3(6148 + 2048), 256, 0, stream>>>(
        dc_w, wdcp, c2_w, wc2p, c1_w, wc1b, f_w, wfb, poolb, x, xbf);
    // 1. down_conv 3x3 512->256, full-K, fused BN+PReLU -> xpbf + pool atomics
    conv3x3_fused<512, 256, 32, 1, 2, 0><<<dim3(32, 8, 4), 256, 0, stream>>>(
        xbf, wdcp, dc_b, dc_g, dc_bt, dc_m, dc_v, dc_a, xpbf, poolb);
    // 2. c2 dilated conv + c1 gemm + c3 fbias (ONE launch, overlapped)
    c2_c1_c3<<<dim3(49, 4, 4), 256, 0, stream>>>(
        xpbf, wc2p, c2_b, c2_g, c2_bt, c2_m, c2_v, c2_a, c2b,
        wc1b, c1_b, c1_g, c1_bt, c1_m, c1_v, c1_a, catb,
        poolb, c3_w, c3_b, c3_g, c3_bt, c3_m, c3_v, c3_a, f_w, fbb);
    // 3. q, k, v
    qkv_kernel<<<dim3(64, 3, 4), 256, 0, stream>>>(
        c2b, q_w, q_b, k_w, k_b, qpk, kpk, v_w, v_b, vbh);
    // 4. single-pass online flash attention + combine
    attn_flash<<<dim3(32, 8, 4), 256, 0, stream>>>(qpk, kpk, vbh, opart, Mpart, Spart);
    attn_combine<<<dim3(128, 4), 256, 0, stream>>>(opart, Mpart, Spart, c2b, gamma2, catb);
    // 5. fuse conv (MFMA, K=256) -> d_out
    gemm1x1_cl<256, 256, true, 0><<<dim3(128, 4), 256, 0, stream>>>(
        catb, wfb, f_b, f_g, f_bt, f_m, f_v, f_a, fbb, (float*)d_out, 0, 0);
}

// Round 13
// 368.988 us; speedup vs baseline: 1.2515x; 1.0146x over previous
//
#include <hip/hip_runtime.h>
#include <hip/hip_bf16.h>
#include <math.h>

#define HW 4096
#define EPSV 1e-5f

typedef unsigned short ushort;
typedef __attribute__((ext_vector_type(8))) short bf16x8;
typedef __attribute__((ext_vector_type(4))) float f32x4;

__device__ inline ushort f2bf(float f) {
    __hip_bfloat16 h = __float2bfloat16(f);
    return *reinterpret_cast<ushort*>(&h);
}
__device__ inline float bf2f(ushort u) {
    unsigned int v = ((unsigned int)u) << 16;
    return __uint_as_float(v);
}

// ---------------------------------------------------------------------------
// MERGED: all weight packs (+ qk/v bf16 packs, r13) + pool zero + x->chlast.
// Blocks [0,6228): pack ranges [dc 3x3][c2 3x3][c1][f][qk][v][pool zero].
// Blocks [6228, 6228+2048): to_chlast for x (C=512).
// ---------------------------------------------------------------------------
__global__ __launch_bounds__(256) void pack_and_chlast(
    const float* __restrict__ dc_w, ushort* __restrict__ wdcp,
    const float* __restrict__ c2_w, ushort* __restrict__ wc2p,
    const float* __restrict__ c1_w, ushort* __restrict__ wc1b,
    const float* __restrict__ f_w,  ushort* __restrict__ wfb,
    const float* __restrict__ q_w,  const float* __restrict__ k_w,
    ushort* __restrict__ wqkb,
    const float* __restrict__ v_w,  ushort* __restrict__ wvb,
    float* __restrict__ pool,
    const float* __restrict__ x, ushort* __restrict__ xbf)
{
    constexpr int PACK_BLKS = 6228;
    constexpr int T_DC = 9 * 16 * 256 * 32;   // 1179648
    constexpr int T_C2 = 9 * 8 * 128 * 32;    // 294912
    constexpr int T_C1 = 32768;
    constexpr int T_F  = 65536;
    constexpr int T_QK = 4096;                // [32][128]: 16 q rows + 16 k
    constexpr int T_V  = 16384;               // [128][128]
    const int tid = threadIdx.x;
    __shared__ float sT[64][65];

    if (blockIdx.x < PACK_BLKS) {
        int idx = blockIdx.x * 256 + tid;
        if (idx < T_DC) {
            const int ci_in = idx & 31;
            int rest = idx >> 5;
            const int co = rest % 256; rest /= 256;
            const int cc = rest % 16;
            const int tap = rest / 16;
            wdcp[idx] = f2bf(dc_w[((size_t)co * 512 + cc * 32 + ci_in) * 9 + tap]);
            return;
        }
        idx -= T_DC;
        if (idx < T_C2) {
            const int ci_in = idx & 31;
            int rest = idx >> 5;
            const int co = rest % 128; rest /= 128;
            const int cc = rest % 8;
            const int tap = rest / 8;
            wc2p[idx] = f2bf(c2_w[((size_t)co * 256 + cc * 32 + ci_in) * 9 + tap]);
            return;
        }
        idx -= T_C2;
        if (idx < T_C1) { wc1b[idx] = f2bf(c1_w[idx]); return; }
        idx -= T_C1;
        if (idx < T_F) {
            const int co = idx >> 8, k = idx & 255;
            wfb[idx] = f2bf(f_w[co * 384 + k]);
            return;
        }
        idx -= T_F;
        if (idx < T_QK) {
            wqkb[idx] = f2bf(idx < 2048 ? q_w[idx] : k_w[idx - 2048]);
            return;
        }
        idx -= T_QK;
        if (idx < T_V) { wvb[idx] = f2bf(v_w[idx]); return; }
        idx -= T_V;
        if (idx < 1024) pool[idx] = 0.f;
        return;
    }

    const int f = blockIdx.x - PACK_BLKS;     // 0..2047
    const int p0 = (f & 63) * 64;
    const int c0 = ((f >> 6) & 7) * 64;
    const int b  = f >> 9;
    for (int i = tid; i < 4096; i += 256) {
        const int ch = i >> 6, px = i & 63;
        sT[ch][px] = x[(size_t)(b * 512 + c0 + ch) * HW + p0 + px];
    }
    __syncthreads();
    const int px = tid >> 2, seg = tid & 3;
    ushort tmp[16];
    #pragma unroll
    for (int j = 0; j < 16; ++j) tmp[j] = f2bf(sT[seg * 16 + j][px]);
    ushort* d = xbf + (size_t)(b * HW + p0 + px) * 512 + c0 + seg * 16;
    *(uint4*)d = *(uint4*)&tmp[0];
    *(uint4*)(d + 8) = *(uint4*)&tmp[8];
}

// ---------------------------------------------------------------------------
// MFMA implicit-GEMM 3x3 conv, FULL-K, fused BN+PReLU epilogue (dc only).
// r9-verified (76.8us dc / WRITE 10MB / VGPR 52).
// COMPILER FACT (r5, r8): staging arrays with all elements live at once get
// spilled to scratch; only load->immediate-consume staging stays in regs.
// ---------------------------------------------------------------------------
template<int CIN, int COUT, int COTILE, int DIL, int ROWS, int OMODE>
__global__ __launch_bounds__(256, OMODE == 0 ? 4 : 2) void conv3x3_fused(
    const ushort* __restrict__ xin,   // [b][64][64][CIN] bf16
    const ushort* __restrict__ wpk,   // [9][CIN/32][COUT][32] bf16
    const float* __restrict__ bias, const float* __restrict__ bng,
    const float* __restrict__ bnb, const float* __restrict__ bnm,
    const float* __restrict__ bnv, const float* __restrict__ al,
    void* __restrict__ outv,
    float* __restrict__ pool)         // [4][256] sums (OMODE 0 only)
{
    constexpr int HR = ROWS + 2 * DIL;
    constexpr int NC = 64 + 2 * DIL;
    constexpr int MT = COTILE / 16;
    constexpr int WPR = 4 / ROWS;
    constexpr int NT = ROWS;
    constexpr int SAS = 40;
    constexpr int CH = CIN / 32;
    constexpr int NA = HR * NC * 4;
    constexpr int NREG = (NA + 255) / 256;
    constexpr int WCH = 9 * MT * 64;
    constexpr int WPT = (WCH + 255) / 256;

    const int tid = threadIdx.x;
    const int wave = tid >> 6, lane = tid & 63;
    const int l15 = lane & 15, quad = lane >> 4;
    const int b = blockIdx.z;
    const int cob = blockIdx.y;
    const int co0 = cob * COTILE;
    const int h0 = blockIdx.x * ROWS;
    const int row = wave / WPR;
    const int ntbase = (wave % WPR) * NT;

    __shared__ __align__(16) ushort sA[HR * NC * SAS];
    __shared__ __align__(16) ushort sW[WCH * 8];

    f32x4 acc[MT][NT];
    #pragma unroll
    for (int mt = 0; mt < MT; ++mt)
        #pragma unroll
        for (int nt = 0; nt < NT; ++nt) acc[mt][nt] = (f32x4){0.f, 0.f, 0.f, 0.f};

    #pragma unroll 1
    for (int cc = 0; cc < CH; ++cc) {
        if (cc != 0) __syncthreads();
        #pragma unroll
        for (int k = 0; k < NREG; ++k) {
            const int i = tid + k * 256;
            if (i < NA) {
                const int p = i >> 2, seg = i & 3;
                const int r = p / NC, c = p - r * NC;
                const int grow = h0 - DIL + r, gcol = c - DIL;
                uint4 val = {0u, 0u, 0u, 0u};
                if (grow >= 0 && grow < 64 && gcol >= 0 && gcol < 64)
                    val = *(const uint4*)&xin[((size_t)(b * 64 + grow) * 64 + gcol) * CIN
                                              + cc * 32 + seg * 8];
                *(uint4*)&sA[p * SAS + seg * 8] = val;
            }
        }
        #pragma unroll
        for (int k = 0; k < WPT; ++k) {
            const int i = tid + k * 256;
            if (i < WCH) {
                const int tap = i / (MT * 64);
                const int r = i - tap * (MT * 64);
                const int mt = r >> 6, n = r & 63;
                const uint4 wv = *(const uint4*)&wpk[
                    ((size_t)(tap * (CIN / 32) + cc) * COUT + co0 + mt * 16 + (n & 15)) * 32
                    + (n >> 4) * 8];
                *(uint4*)&sW[i * 8] = wv;
            }
        }
        __syncthreads();

        #pragma unroll
        for (int tap = 0; tap < 9; ++tap) {
            const int ty = tap / 3, tx = tap - ty * 3;
            const int rl = row + ty * DIL;
            bf16x8 wf[MT];
            #pragma unroll
            for (int mt = 0; mt < MT; ++mt)
                wf[mt] = *(const bf16x8*)&sW[((tap * MT + mt) * 64 + lane) * 8];
            #pragma unroll
            for (int nt = 0; nt < NT; ++nt) {
                const int cl = (ntbase + nt) * 16 + l15 + tx * DIL;
                const bf16x8 bp = *(const bf16x8*)&sA[(rl * NC + cl) * SAS + quad * 8];
                #pragma unroll
                for (int mt = 0; mt < MT; ++mt)
                    acc[mt][nt] = __builtin_amdgcn_mfma_f32_16x16x32_bf16(
                        wf[mt], bp, acc[mt][nt], 0, 0, 0);
            }
        }
    }

    const float a = al[0];

    if constexpr (OMODE == 0) {
        __syncthreads();
        ushort* sT = sA;
        #pragma unroll
        for (int mt = 0; mt < MT; ++mt) {
            float sc[4], sh[4], psum[4];
            #pragma unroll
            for (int rr = 0; rr < 4; ++rr) {
                const int co = co0 + mt * 16 + quad * 4 + rr;
                sc[rr] = bng[co] * rsqrtf(bnv[co] + EPSV);
                sh[rr] = (bias[co] - bnm[co]) * sc[rr] + bnb[co];
                psum[rr] = 0.f;
            }
            #pragma unroll
            for (int nt = 0; nt < NT; ++nt) {
                float tv[4];
                #pragma unroll
                for (int rr = 0; rr < 4; ++rr) {
                    float t = acc[mt][nt][rr] * sc[rr] + sh[rr];
                    t = t >= 0.f ? t : a * t;
                    tv[rr] = t;
                    psum[rr] += t;
                }
                ushort4 u;
                u.x = f2bf(tv[0]); u.y = f2bf(tv[1]);
                u.z = f2bf(tv[2]); u.w = f2bf(tv[3]);
                const int px = (ntbase + nt) * 16 + l15;
                *(ushort4*)&sT[(row * 64 + px) * 40 + mt * 16 + quad * 4] = u;
            }
            #pragma unroll
            for (int rr = 0; rr < 4; ++rr) {
                float v = psum[rr];
                v += __shfl_xor(v, 1);
                v += __shfl_xor(v, 2);
                v += __shfl_xor(v, 4);
                v += __shfl_xor(v, 8);
                if (l15 == 0)
                    atomicAdd(&pool[b * 256 + co0 + mt * 16 + quad * 4 + rr], v);
            }
        }
        __syncthreads();
        ushort* dst = (ushort*)outv;
        const int p = tid >> 1, half = tid & 1;
        const uint4 v0 = *(const uint4*)&sT[p * 40 + half * 16];
        const uint4 v1 = *(const uint4*)&sT[p * 40 + half * 16 + 8];
        const size_t off = ((size_t)(b * 4096 + (h0 + (p >> 6)) * 64 + (p & 63))) * 256
                           + co0 + half * 16;
        *(uint4*)&dst[off] = v0;
        *(uint4*)&dst[off + 8] = v1;
    } else {
        float* out = (float*)outv;
        #pragma unroll
        for (int mt = 0; mt < MT; ++mt)
            #pragma unroll
            for (int rr = 0; rr < 4; ++rr) {
                const int co = co0 + mt * 16 + quad * 4 + rr;
                const float sc = bng[co] * rsqrtf(bnv[co] + EPSV);
                const float sh = (bias[co] - bnm[co]) * sc + bnb[co];
                #pragma unroll
                for (int nt = 0; nt < NT; ++nt) {
                    float t = acc[mt][nt][rr] * sc + sh;
                    t = t >= 0.f ? t : a * t;
                    out[((size_t)(b * COUT + co) * 64 + h0 + row) * 64
                        + (ntbase + nt) * 16 + l15] = t;
                }
            }
    }
}

// ---------------------------------------------------------------------------
// MERGED: c2 dilated conv (bf16 ch-last out, r13) + c1 gemm + c3 fbias.
// Grid (49, 4, 4): x<32 -> c2 conv; x>=32 -> flat c1/c3 blocks.
// ---------------------------------------------------------------------------
__global__ __launch_bounds__(256, 2) void c2_c1_c3(
    const ushort* __restrict__ xin,    // xpbf [b][64][64][256]
    const ushort* __restrict__ wpk,    // wc2p
    const float* __restrict__ c2bias, const float* __restrict__ c2gn,
    const float* __restrict__ c2bt, const float* __restrict__ c2mn,
    const float* __restrict__ c2vr, const float* __restrict__ c2al,
    ushort* __restrict__ c2out,        // c2bh [b][4096][128] bf16 ch-last
    const ushort* __restrict__ wbf,    // wc1b
    const float* __restrict__ bias, const float* __restrict__ bng,
    const float* __restrict__ bnb, const float* __restrict__ bnm,
    const float* __restrict__ bnv, const float* __restrict__ al,
    ushort* __restrict__ catb,
    const float* __restrict__ pool, const float* __restrict__ c3w,
    const float* __restrict__ c3b, const float* __restrict__ c3g,
    const float* __restrict__ c3bt, const float* __restrict__ c3m,
    const float* __restrict__ c3v, const float* __restrict__ c3a,
    const float* __restrict__ fw, float* __restrict__ fbias)
{
    const int tid = threadIdx.x;
    const int wave = tid >> 6, lane = tid & 63;
    const int l15 = lane & 15, quad = lane >> 4;
    __shared__ __align__(16) char smem[51072];

    if (blockIdx.x < 32) {
        // ================= c2 conv body =================
        constexpr int CIN = 256, COUT = 128, COTILE = 32, DIL = 2, ROWS = 2;
        constexpr int HR = ROWS + 2 * DIL;      // 6
        constexpr int NC = 64 + 2 * DIL;        // 68
        constexpr int MT = COTILE / 16;         // 2
        constexpr int WPR = 4 / ROWS;           // 2
        constexpr int NT = ROWS;                // 2
        constexpr int SAS = 40;
        constexpr int CH = CIN / 32;            // 8
        constexpr int NA = HR * NC * 4;         // 1632
        constexpr int NREG = (NA + 255) / 256;  // 7
        constexpr int WCH = 9 * MT * 64;        // 1152
        constexpr int WPT = (WCH + 255) / 256;  // 5

        ushort* sA = (ushort*)smem;                    // 32640 B
        ushort* sW = (ushort*)(smem + 32640);          // 18432 B

        const int b = blockIdx.z;
        const int co0 = blockIdx.y * COTILE;
        const int h0 = blockIdx.x * ROWS;
        const int row = wave / WPR;
        const int ntbase = (wave % WPR) * NT;

        f32x4 acc[MT][NT];
        #pragma unroll
        for (int mt = 0; mt < MT; ++mt)
            #pragma unroll
            for (int nt = 0; nt < NT; ++nt) acc[mt][nt] = (f32x4){0.f, 0.f, 0.f, 0.f};

        #pragma unroll 1
        for (int cc = 0; cc < CH; ++cc) {
            if (cc != 0) __syncthreads();
            #pragma unroll
            for (int k = 0; k < NREG; ++k) {
                const int i = tid + k * 256;
                if (i < NA) {
                    const int p = i >> 2, seg = i & 3;
                    const int r = p / NC, c = p - r * NC;
                    const int grow = h0 - DIL + r, gcol = c - DIL;
                    uint4 val = {0u, 0u, 0u, 0u};
                    if (grow >= 0 && grow < 64 && gcol >= 0 && gcol < 64)
                        val = *(const uint4*)&xin[((size_t)(b * 64 + grow) * 64 + gcol) * CIN
                                                  + cc * 32 + seg * 8];
                    *(uint4*)&sA[p * SAS + seg * 8] = val;
                }
            }
            #pragma unroll
            for (int k = 0; k < WPT; ++k) {
                const int i = tid + k * 256;
                if (i < WCH) {
                    const int tap = i / (MT * 64);
                    const int r = i - tap * (MT * 64);
                    const int mt = r >> 6, n = r & 63;
                    const uint4 wv = *(const uint4*)&wpk[
                        ((size_t)(tap * (CIN / 32) + cc) * COUT + co0 + mt * 16 + (n & 15)) * 32
                        + (n >> 4) * 8];
                    *(uint4*)&sW[i * 8] = wv;
                }
            }
            __syncthreads();

            #pragma unroll
            for (int tap = 0; tap < 9; ++tap) {
                const int ty = tap / 3, tx = tap - ty * 3;
                const int rl = row + ty * DIL;
                bf16x8 wf[MT];
                #pragma unroll
                for (int mt = 0; mt < MT; ++mt)
                    wf[mt] = *(const bf16x8*)&sW[((tap * MT + mt) * 64 + lane) * 8];
                #pragma unroll
                for (int nt = 0; nt < NT; ++nt) {
                    const int cl = (ntbase + nt) * 16 + l15 + tx * DIL;
                    const bf16x8 bp = *(const bf16x8*)&sA[(rl * NC + cl) * SAS + quad * 8];
                    #pragma unroll
                    for (int mt = 0; mt < MT; ++mt)
                        acc[mt][nt] = __builtin_amdgcn_mfma_f32_16x16x32_bf16(
                            wf[mt], bp, acc[mt][nt], 0, 0, 0);
                }
            }
        }

        // ---- BN+PReLU -> bf16 channel-last via LDS transpose (r13)
        const float a = c2al[0];
        __syncthreads();
        ushort* sTc = (ushort*)smem;
        #pragma unroll
        for (int mt = 0; mt < MT; ++mt) {
            float sc[4], sh[4];
            #pragma unroll
            for (int rr = 0; rr < 4; ++rr) {
                const int co = co0 + mt * 16 + quad * 4 + rr;
                sc[rr] = c2gn[co] * rsqrtf(c2vr[co] + EPSV);
                sh[rr] = (c2bias[co] - c2mn[co]) * sc[rr] + c2bt[co];
            }
            #pragma unroll
            for (int nt = 0; nt < NT; ++nt) {
                float tv[4];
                #pragma unroll
                for (int rr = 0; rr < 4; ++rr) {
                    float t = acc[mt][nt][rr] * sc[rr] + sh[rr];
                    tv[rr] = t >= 0.f ? t : a * t;
                }
                ushort4 u;
                u.x = f2bf(tv[0]); u.y = f2bf(tv[1]);
                u.z = f2bf(tv[2]); u.w = f2bf(tv[3]);
                const int px = (ntbase + nt) * 16 + l15;
                *(ushort4*)&sTc[(row * 64 + px) * 40 + mt * 16 + quad * 4] = u;
            }
        }
        __syncthreads();
        const int p = tid >> 1, half = tid & 1;   // p = row*64+px (0..127)
        const uint4 v0 = *(const uint4*)&sTc[p * 40 + half * 16];
        const uint4 v1 = *(const uint4*)&sTc[p * 40 + half * 16 + 8];
        const size_t off = ((size_t)(b * 4096 + (h0 + (p >> 6)) * 64 + (p & 63))) * 128
                           + co0 + half * 16;
        *(uint4*)&c2out[off] = v0;
        *(uint4*)&c2out[off + 8] = v1;
        return;
    }

    // ================= c1 / c3 blocks =================
    const int flat = (blockIdx.z * 4 + blockIdx.y) * 17 + (blockIdx.x - 32);
    if (flat >= 260) return;
    const int bx = flat % 130, by = flat / 130;

    if (bx >= 128) {
        const int b = (bx - 128) * 2 + by;
        float* sp  = (float*)smem;
        float* sc3 = (float*)(smem + 2048);
        sp[tid] = pool[b * 256 + tid] * (1.0f / 4096.0f);
        __syncthreads();
        if (tid < 128) {
            float acc2 = c3b[tid];
            for (int ci = 0; ci < 256; ++ci) acc2 = fmaf(c3w[tid * 256 + ci], sp[ci], acc2);
            const float scale = c3g[tid] * rsqrtf(c3v[tid] + EPSV);
            float t = (acc2 - c3m[tid]) * scale + c3bt[tid];
            const float a2 = c3a[0];
            sc3[tid] = t >= 0.f ? t : a2 * t;
        }
        __syncthreads();
        float f = 0.f;
        for (int j2 = 0; j2 < 128; ++j2) f = fmaf(fw[tid * 384 + 256 + j2], sc3[j2], f);
        fbias[b * 256 + tid] = f;
        return;
    }

    // ---- c1 gemm (CIN=256, COUT=128, BN+PReLU, bf16 ch-last out at col 0)
    {
        constexpr int CIN = 256;
        const int pix0 = bx * 128 + wave * 32;
        const int co0 = by * 64;

        f32x4 acc[4][2];
        #pragma unroll
        for (int mt = 0; mt < 4; ++mt)
            #pragma unroll
            for (int nt = 0; nt < 2; ++nt) acc[mt][nt] = (f32x4){0.f, 0.f, 0.f, 0.f};

        #pragma unroll 2
        for (int cc = 0; cc < CIN / 32; ++cc) {
            bf16x8 aw[4], bp[2];
            #pragma unroll
            for (int mt = 0; mt < 4; ++mt)
                aw[mt] = *(const bf16x8*)&wbf[(size_t)(co0 + mt * 16 + l15) * CIN + cc * 32 + quad * 8];
            #pragma unroll
            for (int nt = 0; nt < 2; ++nt)
                bp[nt] = *(const bf16x8*)&xin[(size_t)(pix0 + nt * 16 + l15) * CIN + cc * 32 + quad * 8];
            #pragma unroll
            for (int mt = 0; mt < 4; ++mt)
                #pragma unroll
                for (int nt = 0; nt < 2; ++nt)
                    acc[mt][nt] = __builtin_amdgcn_mfma_f32_16x16x32_bf16(
                        aw[mt], bp[nt], acc[mt][nt], 0, 0, 0);
        }

        const float a = al[0];
        ushort* sT = (ushort*)smem;
        #pragma unroll
        for (int mt = 0; mt < 4; ++mt)
            #pragma unroll
            for (int r = 0; r < 4; ++r) {
                const int co = co0 + mt * 16 + quad * 4 + r;
                const float scale = bng[co] * rsqrtf(bnv[co] + EPSV);
                const float shift = bias[co] * scale + (bnb[co] - bnm[co] * scale);
                #pragma unroll
                for (int nt = 0; nt < 2; ++nt) {
                    float t = acc[mt][nt][r] * scale + shift;
                    t = t >= 0.f ? t : a * t;
                    sT[((wave * 32 + nt * 16 + l15) * 68) + mt * 16 + quad * 4 + r] = f2bf(t);
                }
            }
        __syncthreads();
        const int p = lane >> 1, half = lane & 1;
        #pragma unroll
        for (int seg = 0; seg < 4; ++seg) {
            uint2 a0 = *(uint2*)&sT[((wave * 32 + p) * 68) + half * 32 + seg * 8];
            uint2 a1 = *(uint2*)&sT[((wave * 32 + p) * 68) + half * 32 + seg * 8 + 4];
            uint4 vv = {a0.x, a0.y, a1.x, a1.y};
            *(uint4*)&catb[(size_t)(pix0 + p) * 256 + co0 + half * 32 + seg * 8] = vv;
        }
    }
}

// ---------------------------------------------------------------------------
// MFMA 1x1 conv on channel-last bf16 input (used for the FUSE conv, OMODE 0).
// ---------------------------------------------------------------------------
template<int CIN, int COUT, bool BNACT, int OMODE>
__global__ __launch_bounds__(256) void gemm1x1_cl(
    const ushort* __restrict__ xin,   // [16384][CIN] bf16
    const ushort* __restrict__ wbf,   // [COUT][CIN] bf16
    const float* __restrict__ bias, const float* __restrict__ bng,
    const float* __restrict__ bnb, const float* __restrict__ bnm,
    const float* __restrict__ bnv, const float* __restrict__ al,
    const float* __restrict__ ebias, void* __restrict__ outv,
    int ostride, int ocol)
{
    const int tid = threadIdx.x;
    const int wave = tid >> 6, lane = tid & 63;
    const int l15 = lane & 15, quad = lane >> 4;
    const int pix0 = blockIdx.x * 128 + wave * 32;
    const int co0 = blockIdx.y * 64;

    f32x4 acc[4][2];
    #pragma unroll
    for (int mt = 0; mt < 4; ++mt)
        #pragma unroll
        for (int nt = 0; nt < 2; ++nt) acc[mt][nt] = (f32x4){0.f, 0.f, 0.f, 0.f};

    #pragma unroll 2
    for (int cc = 0; cc < CIN / 32; ++cc) {
        bf16x8 aw[4], bp[2];
        #pragma unroll
        for (int mt = 0; mt < 4; ++mt)
            aw[mt] = *(const bf16x8*)&wbf[(size_t)(co0 + mt * 16 + l15) * CIN + cc * 32 + quad * 8];
        #pragma unroll
        for (int nt = 0; nt < 2; ++nt)
            bp[nt] = *(const bf16x8*)&xin[(size_t)(pix0 + nt * 16 + l15) * CIN + cc * 32 + quad * 8];
        #pragma unroll
        for (int mt = 0; mt < 4; ++mt)
            #pragma unroll
            for (int nt = 0; nt < 2; ++nt)
                acc[mt][nt] = __builtin_amdgcn_mfma_f32_16x16x32_bf16(
                    aw[mt], bp[nt], acc[mt][nt], 0, 0, 0);
    }

    const int bI = pix0 >> 12;
    const float a = BNACT ? al[0] : 0.f;

    if (OMODE == 0) {
        float* out = (float*)outv;
        #pragma unroll
        for (int mt = 0; mt < 4; ++mt)
            #pragma unroll
            for (int r = 0; r < 4; ++r) {
                const int co = co0 + mt * 16 + quad * 4 + r;
                float bb = bias[co];
                if (ebias) bb += ebias[bI * COUT + co];
                float scale = 1.f, shift = bb;
                if (BNACT) {
                    scale = bng[co] * rsqrtf(bnv[co] + EPSV);
                    shift = bb * scale + (bnb[co] - bnm[co] * scale);
                }
                #pragma unroll
                for (int nt = 0; nt < 2; ++nt) {
                    float t = acc[mt][nt][r] * scale + shift;
                    if (BNACT) t = t >= 0.f ? t : a * t;
                    out[((size_t)(bI * COUT + co)) * HW + (pix0 & 4095) + nt * 16 + l15] = t;
                }
            }
    } else {
        __shared__ ushort sT[4][32][68];
        #pragma unroll
        for (int mt = 0; mt < 4; ++mt)
            #pragma unroll
            for (int r = 0; r < 4; ++r) {
                const int co = co0 + mt * 16 + quad * 4 + r;
                float bb = bias[co];
                float scale = 1.f, shift = bb;
                if (BNACT) {
                    scale = bng[co] * rsqrtf(bnv[co] + EPSV);
                    shift = bb * scale + (bnb[co] - bnm[co] * scale);
                }
                #pragma unroll
                for (int nt = 0; nt < 2; ++nt) {
                    float t = acc[mt][nt][r] * scale + shift;
                    if (BNACT) t = t >= 0.f ? t : a * t;
                    sT[wave][nt * 16 + l15][mt * 16 + quad * 4 + r] = f2bf(t);
                }
            }
        __syncthreads();
        const int p = lane >> 1, half = lane & 1;
        ushort* out = (ushort*)outv;
        #pragma unroll
        for (int seg = 0; seg < 4; ++seg) {
            uint2 a0 = *(uint2*)&sT[wave][p][half * 32 + seg * 8];
            uint2 a1 = *(uint2*)&sT[wave][p][half * 32 + seg * 8 + 4];
            uint4 vv = {a0.x, a0.y, a1.x, a1.y};
            *(uint4*)&out[(size_t)(pix0 + p) * ostride + ocol + co0 + half * 32 + seg * 8] = vv;
        }
    }
}

// ---------------------------------------------------------------------------
// r13: qk + v as MFMA gemms on bf16 ch-last c2bh.  Grid (32, 3, 4).
// y==0: qk (COUT=32, stacked q|k) -> qpk/kpk packed [n][32] (+zero pad);
// y in {1,2}: v (COUT=64 tile) -> vbh bf16 ch-first [b][128][4096].
// ---------------------------------------------------------------------------
__global__ __launch_bounds__(256) void qkv_mfma(
    const ushort* __restrict__ c2bh,   // [b][4096][128] bf16 ch-last
    const ushort* __restrict__ wqkb,   // [32][128] bf16 (q rows 0-15, k 16-31)
    const float* __restrict__ qb2, const float* __restrict__ kb2,
    ushort* __restrict__ qpack, ushort* __restrict__ kpack,
    const ushort* __restrict__ wvb,    // [128][128] bf16
    const float* __restrict__ vb, ushort* __restrict__ vbh)
{
    const int tid = threadIdx.x;
    const int wave = tid >> 6, lane = tid & 63;
    const int l15 = lane & 15, quad = lane >> 4;
    const int b = blockIdx.z;
    const int pix0 = blockIdx.x * 128 + wave * 32;
    const size_t xrow = (size_t)(b * 4096);

    if (blockIdx.y == 0) {
        // ---- qk: COUT=32 MFMA gemm
        f32x4 acc[2][2];
        #pragma unroll
        for (int mt = 0; mt < 2; ++mt)
            #pragma unroll
            for (int nt = 0; nt < 2; ++nt) acc[mt][nt] = (f32x4){0.f, 0.f, 0.f, 0.f};
        #pragma unroll
        for (int cc = 0; cc < 4; ++cc) {
            bf16x8 aw[2], bp[2];
            #pragma unroll
            for (int mt = 0; mt < 2; ++mt)
                aw[mt] = *(const bf16x8*)&wqkb[(mt * 16 + l15) * 128 + cc * 32 + quad * 8];
            #pragma unroll
            for (int nt = 0; nt < 2; ++nt)
                bp[nt] = *(const bf16x8*)&c2bh[(xrow + pix0 + nt * 16 + l15) * 128 + cc * 32 + quad * 8];
            #pragma unroll
            for (int mt = 0; mt < 2; ++mt)
                #pragma unroll
                for (int nt = 0; nt < 2; ++nt)
                    acc[mt][nt] = __builtin_amdgcn_mfma_f32_16x16x32_bf16(
                        aw[mt], bp[nt], acc[mt][nt], 0, 0, 0);
        }
        __shared__ __align__(16) ushort sT[4][32][40];
        #pragma unroll
        for (int mt = 0; mt < 2; ++mt)
            #pragma unroll
            for (int r = 0; r < 4; ++r) {
                const int co = mt * 16 + quad * 4 + r;
                const float bb = (co < 16) ? qb2[co] : kb2[co - 16];
                #pragma unroll
                for (int nt = 0; nt < 2; ++nt)
                    sT[wave][nt * 16 + l15][co] = f2bf(acc[mt][nt][r] + bb);
            }
        __syncthreads();
        const int p = lane >> 1, half = lane & 1;
        ushort* dst = half ? kpack : qpack;
        const int cbase = half ? 16 : 0;
        const size_t off = (size_t)(b * 4096 + pix0 + p) * 32;
        *(uint4*)&dst[off]     = *(uint4*)&sT[wave][p][cbase];
        *(uint4*)&dst[off + 8] = *(uint4*)&sT[wave][p][cbase + 8];
        const uint4 zz = {0u, 0u, 0u, 0u};
        *(uint4*)&dst[off + 16] = zz;
        *(uint4*)&dst[off + 24] = zz;
    } else {
        // ---- v: COUT=64 tile MFMA gemm -> bf16 ch-first
        const int co0 = (blockIdx.y - 1) * 64;
        f32x4 acc[4][2];
        #pragma unroll
        for (int mt = 0; mt < 4; ++mt)
            #pragma unroll
            for (int nt = 0; nt < 2; ++nt) acc[mt][nt] = (f32x4){0.f, 0.f, 0.f, 0.f};
        #pragma unroll
        for (int cc = 0; cc < 4; ++cc) {
            bf16x8 aw[4], bp[2];
            #pragma unroll
            for (int mt = 0; mt < 4; ++mt)
                aw[mt] = *(const bf16x8*)&wvb[(size_t)(co0 + mt * 16 + l15) * 128 + cc * 32 + quad * 8];
            #pragma unroll
            for (int nt = 0; nt < 2; ++nt)
                bp[nt] = *(const bf16x8*)&c2bh[(xrow + pix0 + nt * 16 + l15) * 128 + cc * 32 + quad * 8];
            #pragma unroll
            for (int mt = 0; mt < 4; ++mt)
                #pragma unroll
                for (int nt = 0; nt < 2; ++nt)
                    acc[mt][nt] = __builtin_amdgcn_mfma_f32_16x16x32_bf16(
                        aw[mt], bp[nt], acc[mt][nt], 0, 0, 0);
        }
        #pragma unroll
        for (int mt = 0; mt < 4; ++mt)
            #pragma unroll
            for (int r = 0; r < 4; ++r) {
                const int co = co0 + mt * 16 + quad * 4 + r;
                const float shift = vb[co];
                #pragma unroll
                for (int nt = 0; nt < 2; ++nt) {
                    const int px = pix0 + nt * 16 + l15;
                    vbh[(size_t)(b * 128 + co) * HW + px] = f2bf(acc[mt][nt][r] + shift);
                }
            }
    }
}

// ---------------------------------------------------------------------------
// SINGLE-PASS flash attention (r8/r9-verified): online softmax + defer-max.
// Grid: (32 nblk, 8 msplit, 4 batch).
// ---------------------------------------------------------------------------
__global__ __launch_bounds__(256) void attn_flash(
    const ushort* __restrict__ qpack,
    const ushort* __restrict__ kpack,
    const ushort* __restrict__ vpackT,
    ushort* __restrict__ opart,       // [b][8j][4096n][128c] bf16
    float* __restrict__ Mpart,        // [b][8j][4096n]
    float* __restrict__ Spart)
{
    const int tid = threadIdx.x;
    const int wave = tid >> 6, lane = tid & 63;
    const int l15 = lane & 15, quad = lane >> 4;
    const int b = blockIdx.z, j = blockIdx.y;
    const int n0w = blockIdx.x * 128 + wave * 32;
    const int m_begin = j * 512;

    __shared__ __align__(16) ushort sV[2][128][40];
    __shared__ __align__(16) ushort sP[4][2][16][40];

    const bf16x8 bq0 = *(const bf16x8*)(qpack + ((size_t)(b * 4096 + n0w + l15) * 32 + quad * 8));
    const bf16x8 bq1 = *(const bf16x8*)(qpack + ((size_t)(b * 4096 + n0w + 16 + l15) * 32 + quad * 8));
    const f32x4 z = {0.f, 0.f, 0.f, 0.f};

    float runM0 = -3e30f, runM1 = -3e30f;
    float runS0 = 0.f, runS1 = 0.f;
    f32x4 oacc0[8], oacc1[8];
    #pragma unroll
    for (int cs = 0; cs < 8; ++cs) {
        oacc0[cs] = (f32x4){0.f, 0.f, 0.f, 0.f};
        oacc1[cs] = (f32x4){0.f, 0.f, 0.f, 0.f};
    }

    const int stc = tid >> 1, stseg = tid & 1;

    {
        uint4 v0 = *(const uint4*)&vpackT[(size_t)(b * 128 + stc) * HW + m_begin + stseg * 16];
        uint4 v1 = *(const uint4*)&vpackT[(size_t)(b * 128 + stc) * HW + m_begin + stseg * 16 + 8];
        *(uint4*)&sV[0][stc][stseg * 16] = v0;
        *(uint4*)&sV[0][stc][stseg * 16 + 8] = v1;
    }
    __syncthreads();

    #pragma unroll 1
    for (int t = 0; t < 16; ++t) {
        const int m0 = m_begin + t * 32;
        const int buf = t & 1;
        uint4 nv0, nv1;
        const bool more = (t + 1 < 16);
        if (more) {
            const size_t nb = (size_t)(b * 128 + stc) * HW + m0 + 32 + stseg * 16;
            nv0 = *(const uint4*)&vpackT[nb];
            nv1 = *(const uint4*)&vpackT[nb + 8];
        }
        f32x4 s0[2], s1[2];
        #pragma unroll
        for (int ms = 0; ms < 2; ++ms) {
            const bf16x8 ak = *(const bf16x8*)(
                kpack + ((size_t)(b * 4096 + m0 + ms * 16 + l15) * 32 + quad * 8));
            s0[ms] = __builtin_amdgcn_mfma_f32_16x16x32_bf16(ak, bq0, z, 0, 0, 0);
            s1[ms] = __builtin_amdgcn_mfma_f32_16x16x32_bf16(ak, bq1, z, 0, 0, 0);
        }

        float tM0 = fmaxf(fmaxf(fmaxf(s0[0][0], s0[0][1]), fmaxf(s0[0][2], s0[0][3])),
                          fmaxf(fmaxf(s0[1][0], s0[1][1]), fmaxf(s0[1][2], s0[1][3])));
        float tM1 = fmaxf(fmaxf(fmaxf(s1[0][0], s1[0][1]), fmaxf(s1[0][2], s1[0][3])),
                          fmaxf(fmaxf(s1[1][0], s1[1][1]), fmaxf(s1[1][2], s1[1][3])));
        tM0 = fmaxf(tM0, __shfl_xor(tM0, 16));
        tM0 = fmaxf(tM0, __shfl_xor(tM0, 32));
        tM1 = fmaxf(tM1, __shfl_xor(tM1, 16));
        tM1 = fmaxf(tM1, __shfl_xor(tM1, 32));
        if (__any(tM0 > runM0 + 8.f)) {
            const float nM = fmaxf(runM0, tM0);
            const float sc = __builtin_amdgcn_exp2f((runM0 - nM) * 1.44269504f);
            runS0 *= sc;
            float scr[4];
            #pragma unroll
            for (int r = 0; r < 4; ++r) scr[r] = __shfl(sc, quad * 4 + r);
            #pragma unroll
            for (int cs = 0; cs < 8; ++cs) {
                oacc0[cs][0] *= scr[0]; oacc0[cs][1] *= scr[1];
                oacc0[cs][2] *= scr[2]; oacc0[cs][3] *= scr[3];
            }
            runM0 = nM;
        }
        if (__any(tM1 > runM1 + 8.f)) {
            const float nM = fmaxf(runM1, tM1);
            const float sc = __builtin_amdgcn_exp2f((runM1 - nM) * 1.44269504f);
            runS1 *= sc;
            float scr[4];
            #pragma unroll
            for (int r = 0; r < 4; ++r) scr[r] = __shfl(sc, quad * 4 + r);
            #pragma unroll
            for (int cs = 0; cs < 8; ++cs) {
                oacc1[cs][0] *= scr[0]; oacc1[cs][1] *= scr[1];
                oacc1[cs][2] *= scr[2]; oacc1[cs][3] *= scr[3];
            }
            runM1 = nM;
        }
        const float Ms0 = runM0 * 1.44269504f;
        const float Ms1 = runM1 * 1.44269504f;

        #pragma unroll
        for (int ms = 0; ms < 2; ++ms) {
            float p0[4], p1[4];
            #pragma unroll
            for (int r = 0; r < 4; ++r) {
                p0[r] = __builtin_amdgcn_exp2f(fmaf(s0[ms][r], 1.44269504f, -Ms0));
                p1[r] = __builtin_amdgcn_exp2f(fmaf(s1[ms][r], 1.44269504f, -Ms1));
                runS0 += p0[r];
                runS1 += p1[r];
            }
            ushort4 u0, u1;
            u0.x = f2bf(p0[0]); u0.y = f2bf(p0[1]); u0.z = f2bf(p0[2]); u0.w = f2bf(p0[3]);
            u1.x = f2bf(p1[0]); u1.y = f2bf(p1[1]); u1.z = f2bf(p1[2]); u1.w = f2bf(p1[3]);
            *(uint2*)&sP[wave][0][l15][ms * 16 + quad * 4] = *(uint2*)&u0;
            *(uint2*)&sP[wave][1][l15][ms * 16 + quad * 4] = *(uint2*)&u1;
        }
        asm volatile("s_waitcnt lgkmcnt(0)" ::: "memory");
        const bf16x8 ap0 = *(const bf16x8*)&sP[wave][0][l15][quad * 8];
        const bf16x8 ap1 = *(const bf16x8*)&sP[wave][1][l15][quad * 8];
        #pragma unroll
        for (int cs = 0; cs < 8; ++cs) {
            const bf16x8 bv = *(const bf16x8*)&sV[buf][cs * 16 + l15][quad * 8];
            oacc0[cs] = __builtin_amdgcn_mfma_f32_16x16x32_bf16(ap0, bv, oacc0[cs], 0, 0, 0);
            oacc1[cs] = __builtin_amdgcn_mfma_f32_16x16x32_bf16(ap1, bv, oacc1[cs], 0, 0, 0);
        }
        if (more) {
            *(uint4*)&sV[buf ^ 1][stc][stseg * 16] = nv0;
            *(uint4*)&sV[buf ^ 1][stc][stseg * 16 + 8] = nv1;
            __syncthreads();
        }
    }

    runS0 += __shfl_xor(runS0, 16);
    runS0 += __shfl_xor(runS0, 32);
    runS1 += __shfl_xor(runS1, 16);
    runS1 += __shfl_xor(runS1, 32);
    if (lane < 32) {
        const float Mv = (lane < 16) ? runM0 : runM1;
        const float Sv = (lane < 16) ? runS0 : runS1;
        const int n = n0w + ((lane < 16) ? 0 : 16) + l15;
        Mpart[((size_t)b * 8 + j) * 4096 + n] = Mv;
        Spart[((size_t)b * 8 + j) * 4096 + n] = Sv;
    }
    #pragma unroll
    for (int cs = 0; cs < 8; ++cs)
        #pragma unroll
        for (int r = 0; r < 4; ++r) {
            const int n = n0w + quad * 4 + r;
            opart[(((size_t)b * 8 + j) * 4096 + n) * 128 + cs * 16 + l15] = f2bf(oacc0[cs][r]);
            opart[(((size_t)b * 8 + j) * 4096 + n + 16) * 128 + cs * 16 + l15] = f2bf(oacc1[cs][r]);
        }
}

// ---------------------------------------------------------------------------
// Combine 8 m-split partials, normalize, fuse gamma2*O + c2 -> catb[:,128:256]
// r13: residual read from bf16 ch-last c2bh (coalesced).
// ---------------------------------------------------------------------------
__global__ __launch_bounds__(256) void attn_combine(
    const ushort* __restrict__ opart, const float* __restrict__ Mpart,
    const float* __restrict__ Spart, const ushort* __restrict__ c2bh,
    const float* __restrict__ gamma2, ushort* __restrict__ catb)
{
    const int b = blockIdx.y, n0 = blockIdx.x * 32, tid = threadIdx.x;
    __shared__ float sC2[128][33];
    __shared__ float sWj[8][32];
    if (tid < 32) {
        const int n = n0 + tid;
        float Mj[8], Sj[8];
        #pragma unroll
        for (int j = 0; j < 8; ++j) {
            Mj[j] = Mpart[((size_t)b * 8 + j) * 4096 + n];
            Sj[j] = Spart[((size_t)b * 8 + j) * 4096 + n];
        }
        float M = -3e30f;
        #pragma unroll
        for (int j = 0; j < 8; ++j) M = fmaxf(M, Mj[j]);
        float St = 0.f, e[8];
        #pragma unroll
        for (int j = 0; j < 8; ++j) { e[j] = __expf(Mj[j] - M); St += Sj[j] * e[j]; }
        const float inv = 1.0f / St;
        #pragma unroll
        for (int j = 0; j < 8; ++j) sWj[j][tid] = e[j] * inv;
    }
    #pragma unroll
    for (int e = 0; e < 16; ++e) {
        const int idx = tid + e * 256;
        const int n = idx >> 7, c = idx & 127;
        sC2[c][n] = bf2f(c2bh[(size_t)(b * 4096 + n0 + n) * 128 + c]);
    }
    __syncthreads();
    const float g2 = gamma2[0];
    #pragma unroll
    for (int e = 0; e < 16; ++e) {
        const int idx = tid + e * 256;
        const int n = idx >> 7, c = idx & 127;
        float s = 0.f;
        #pragma unroll
        for (int j = 0; j < 8; ++j)
            s += bf2f(opart[(((size_t)b * 8 + j) * 4096 + n0 + n) * 128 + c]) * sWj[j][n];
        catb[(size_t)(b * 4096 + n0 + n) * 256 + 128 + c] = f2bf(fmaf(g2, s, sC2[c][n]));
    }
}

// ---------------------------------------------------------------------------
extern "C" void kernel_launch(void* const* d_in, const int* in_sizes, int n_in,
                              void* d_out, int out_size, void* d_ws, size_t ws_size,
                              hipStream_t stream)
{
    const float* x     = (const float*)d_in[0];
    const float* dc_w  = (const float*)d_in[1];
    const float* dc_b  = (const float*)d_in[2];
    const float* dc_g  = (const float*)d_in[3];
    const float* dc_bt = (const float*)d_in[4];
    const float* dc_m  = (const float*)d_in[5];
    const float* dc_v  = (const float*)d_in[6];
    const float* dc_a  = (const float*)d_in[7];
    const float* c1_w  = (const float*)d_in[8];
    const float* c1_b  = (const float*)d_in[9];
    const float* c1_g  = (const float*)d_in[10];
    const float* c1_bt = (const float*)d_in[11];
    const float* c1_m  = (const float*)d_in[12];
    const float* c1_v  = (const float*)d_in[13];
    const float* c1_a  = (const float*)d_in[14];
    const float* c2_w  = (const float*)d_in[15];
    const float* c2_b  = (const float*)d_in[16];
    const float* c2_g  = (const float*)d_in[17];
    const float* c2_bt = (const float*)d_in[18];
    const float* c2_m  = (const float*)d_in[19];
    const float* c2_v  = (const float*)d_in[20];
    const float* c2_a  = (const float*)d_in[21];
    const float* q_w   = (const float*)d_in[22];
    const float* q_b   = (const float*)d_in[23];
    const float* k_w   = (const float*)d_in[24];
    const float* k_b   = (const float*)d_in[25];
    const float* v_w   = (const float*)d_in[26];
    const float* v_b   = (const float*)d_in[27];
    const float* gamma2= (const float*)d_in[28];
    const float* c3_w  = (const float*)d_in[29];
    const float* c3_b  = (const float*)d_in[30];
    const float* c3_g  = (const float*)d_in[31];
    const float* c3_bt = (const float*)d_in[32];
    const float* c3_m  = (const float*)d_in[33];
    const float* c3_v  = (const float*)d_in[34];
    const float* c3_a  = (const float*)d_in[35];
    const float* f_w   = (const float*)d_in[36];
    const float* f_b   = (const float*)d_in[37];
    const float* f_g   = (const float*)d_in[38];
    const float* f_bt  = (const float*)d_in[39];
    const float* f_m   = (const float*)d_in[40];
    const float* f_v   = (const float*)d_in[41];
    const float* f_a   = (const float*)d_in[42];

    // ---- workspace layout by live range ----
    // opart  [0, 33554432)       attn_flash..attn_combine (xbf dead by then)
    // qpk    [33554432, ...)  kpk  vbh
    // c2bh   [39845888, 44040192)  c2 conv..attn_combine (bf16, r13)
    // wqkb   [48234496, 48242688); wvb [48242688, 48275456)  (gap region)
    // xpbf   [50331648, 58720256); catb [58720256, ...)
    char* base = (char*)d_ws;
    ushort* xbf   = (ushort*)base;                       // [4,4096,512] bf16
    ushort* opart = (ushort*)base;                       // [4,8,4096,128] bf16
    ushort* qpk   = (ushort*)(base + 33554432);          // [4,4096,32]
    ushort* kpk   = (ushort*)(base + 34603008);
    ushort* vbh   = (ushort*)(base + 35651584);          // [4,128,4096] bf16
    ushort* c2bh  = (ushort*)(base + 39845888);          // [4,4096,128] bf16
    ushort* wqkb  = (ushort*)(base + 48234496);          // [32,128] bf16
    ushort* wvb   = (ushort*)(base + 48242688);          // [128,128] bf16
    ushort* xpbf  = (ushort*)(base + 50331648);          // [4,4096,256] bf16
    ushort* catb  = (ushort*)(base + 58720256);          // [4,4096,256] bf16
    ushort* wdcp  = (ushort*)(base + 75497472);          // [9,16,256,32]
    ushort* wc2p  = (ushort*)(base + 77856768);          // [9,8,128,32]
    ushort* wc1b  = (ushort*)(base + 78446592);          // [128,256]
    ushort* wfb   = (ushort*)(base + 78512128);          // [256,256]
    float*  poolb = (float*)(base + 78643200);           // 1024 (atomic sums)
    float*  fbb   = (float*)(base + 78647296);           // 1024
    float*  Mpart = (float*)(base + 78651392);           // [4,8,4096]
    float*  Spart = (float*)(base + 79175680);           // [4,8,4096]

    // 0. packs (+qk/v bf16) + pool zero + x->chlast (ONE launch)
    pack_and_chlast<<<dim3(6228 + 2048), 256, 0, stream>>>(
        dc_w, wdcp, c2_w, wc2p, c1_w, wc1b, f_w, wfb,
        q_w, k_w, wqkb, v_w, wvb, poolb, x, xbf);
    // 1. down_conv 3x3 512->256, full-K, fused BN+PReLU -> xpbf + pool atomics
    conv3x3_fused<512, 256, 32, 1, 2, 0><<<dim3(32, 8, 4), 256, 0, stream>>>(
        xbf, wdcp, dc_b, dc_g, dc_bt, dc_m, dc_v, dc_a, xpbf, poolb);
    // 2. c2 dilated conv (bf16 ch-last) + c1 gemm + c3 fbias (ONE launch)
    c2_c1_c3<<<dim3(49, 4, 4), 256, 0, stream>>>(
        xpbf, wc2p, c2_b, c2_g, c2_bt, c2_m, c2_v, c2_a, c2bh,
        wc1b, c1_b, c1_g, c1_bt, c1_m, c1_v, c1_a, catb,
        poolb, c3_w, c3_b, c3_g, c3_bt, c3_m, c3_v, c3_a, f_w, fbb);
    // 3. q, k, v — all MFMA on bf16 ch-last (r13)
    qkv_mfma<<<dim3(32, 3, 4), 256, 0, stream>>>(
        c2bh, wqkb, q_b, k_b, qpk, kpk, wvb, v_b, vbh);
    // 4. single-pass online flash attention + combine
    attn_flash<<<dim3(32, 8, 4), 256, 0, stream>>>(qpk, kpk, vbh, opart, Mpart, Spart);
    attn_combine<<<dim3(128, 4), 256, 0, stream>>>(opart, Mpart, Spart, c2bh, gamma2, catb);
    // 5. fuse conv (MFMA, K=256) -> d_out
    gemm1x1_cl<256, 256, true, 0><<<dim3(128, 4), 256, 0, stream>>>(
        catb, wfb, f_b, f_g, f_bt, f_m, f_v, f_a, fbb, (float*)d_out, 0, 0);
}

// Round 14
// 365.874 us; speedup vs baseline: 1.2622x; 1.0085x over previous
//
#include <hip/hip_runtime.h>
#include <hip/hip_bf16.h>
#include <math.h>

#define HW 4096
#define EPSV 1e-5f

typedef unsigned short ushort;
typedef __attribute__((ext_vector_type(8))) short bf16x8;
typedef __attribute__((ext_vector_type(4))) float f32x4;

__device__ inline ushort f2bf(float f) {
    __hip_bfloat16 h = __float2bfloat16(f);
    return *reinterpret_cast<ushort*>(&h);
}
__device__ inline float bf2f(ushort u) {
    unsigned int v = ((unsigned int)u) << 16;
    return __uint_as_float(v);
}

// ---------------------------------------------------------------------------
// MERGED: all weight packs (+ qk/v bf16) + pool zero + x->chlast.
// ---------------------------------------------------------------------------
__global__ __launch_bounds__(256) void pack_and_chlast(
    const float* __restrict__ dc_w, ushort* __restrict__ wdcp,
    const float* __restrict__ c2_w, ushort* __restrict__ wc2p,
    const float* __restrict__ c1_w, ushort* __restrict__ wc1b,
    const float* __restrict__ f_w,  ushort* __restrict__ wfb,
    const float* __restrict__ q_w,  const float* __restrict__ k_w,
    ushort* __restrict__ wqkb,
    const float* __restrict__ v_w,  ushort* __restrict__ wvb,
    float* __restrict__ pool,
    const float* __restrict__ x, ushort* __restrict__ xbf)
{
    constexpr int PACK_BLKS = 6228;
    constexpr int T_DC = 9 * 16 * 256 * 32;
    constexpr int T_C2 = 9 * 8 * 128 * 32;
    constexpr int T_C1 = 32768;
    constexpr int T_F  = 65536;
    constexpr int T_QK = 4096;
    constexpr int T_V  = 16384;
    const int tid = threadIdx.x;
    __shared__ float sT[64][65];

    if (blockIdx.x < PACK_BLKS) {
        int idx = blockIdx.x * 256 + tid;
        if (idx < T_DC) {
            const int ci_in = idx & 31;
            int rest = idx >> 5;
            const int co = rest % 256; rest /= 256;
            const int cc = rest % 16;
            const int tap = rest / 16;
            wdcp[idx] = f2bf(dc_w[((size_t)co * 512 + cc * 32 + ci_in) * 9 + tap]);
            return;
        }
        idx -= T_DC;
        if (idx < T_C2) {
            const int ci_in = idx & 31;
            int rest = idx >> 5;
            const int co = rest % 128; rest /= 128;
            const int cc = rest % 8;
            const int tap = rest / 8;
            wc2p[idx] = f2bf(c2_w[((size_t)co * 256 + cc * 32 + ci_in) * 9 + tap]);
            return;
        }
        idx -= T_C2;
        if (idx < T_C1) { wc1b[idx] = f2bf(c1_w[idx]); return; }
        idx -= T_C1;
        if (idx < T_F) {
            const int co = idx >> 8, k = idx & 255;
            wfb[idx] = f2bf(f_w[co * 384 + k]);
            return;
        }
        idx -= T_F;
        if (idx < T_QK) {
            wqkb[idx] = f2bf(idx < 2048 ? q_w[idx] : k_w[idx - 2048]);
            return;
        }
        idx -= T_QK;
        if (idx < T_V) { wvb[idx] = f2bf(v_w[idx]); return; }
        idx -= T_V;
        if (idx < 1024) pool[idx] = 0.f;
        return;
    }

    const int f = blockIdx.x - PACK_BLKS;
    const int p0 = (f & 63) * 64;
    const int c0 = ((f >> 6) & 7) * 64;
    const int b  = f >> 9;
    for (int i = tid; i < 4096; i += 256) {
        const int ch = i >> 6, px = i & 63;
        sT[ch][px] = x[(size_t)(b * 512 + c0 + ch) * HW + p0 + px];
    }
    __syncthreads();
    const int px = tid >> 2, seg = tid & 3;
    ushort tmp[16];
    #pragma unroll
    for (int j = 0; j < 16; ++j) tmp[j] = f2bf(sT[seg * 16 + j][px]);
    ushort* d = xbf + (size_t)(b * HW + p0 + px) * 512 + c0 + seg * 16;
    *(uint4*)d = *(uint4*)&tmp[0];
    *(uint4*)(d + 8) = *(uint4*)&tmp[8];
}

// ---------------------------------------------------------------------------
// MFMA implicit-GEMM 3x3 conv, FULL-K, fused BN+PReLU epilogue (dc only).
// r9-verified.  COMPILER FACT (r5, r8): staging arrays with all elements
// live at once get spilled; only load->immediate-consume staging stays.
// ---------------------------------------------------------------------------
template<int CIN, int COUT, int COTILE, int DIL, int ROWS, int OMODE>
__global__ __launch_bounds__(256, OMODE == 0 ? 4 : 2) void conv3x3_fused(
    const ushort* __restrict__ xin,
    const ushort* __restrict__ wpk,
    const float* __restrict__ bias, const float* __restrict__ bng,
    const float* __restrict__ bnb, const float* __restrict__ bnm,
    const float* __restrict__ bnv, const float* __restrict__ al,
    void* __restrict__ outv,
    float* __restrict__ pool)
{
    constexpr int HR = ROWS + 2 * DIL;
    constexpr int NC = 64 + 2 * DIL;
    constexpr int MT = COTILE / 16;
    constexpr int WPR = 4 / ROWS;
    constexpr int NT = ROWS;
    constexpr int SAS = 40;
    constexpr int CH = CIN / 32;
    constexpr int NA = HR * NC * 4;
    constexpr int NREG = (NA + 255) / 256;
    constexpr int WCH = 9 * MT * 64;
    constexpr int WPT = (WCH + 255) / 256;

    const int tid = threadIdx.x;
    const int wave = tid >> 6, lane = tid & 63;
    const int l15 = lane & 15, quad = lane >> 4;
    const int b = blockIdx.z;
    const int cob = blockIdx.y;
    const int co0 = cob * COTILE;
    const int h0 = blockIdx.x * ROWS;
    const int row = wave / WPR;
    const int ntbase = (wave % WPR) * NT;

    __shared__ __align__(16) ushort sA[HR * NC * SAS];
    __shared__ __align__(16) ushort sW[WCH * 8];

    f32x4 acc[MT][NT];
    #pragma unroll
    for (int mt = 0; mt < MT; ++mt)
        #pragma unroll
        for (int nt = 0; nt < NT; ++nt) acc[mt][nt] = (f32x4){0.f, 0.f, 0.f, 0.f};

    #pragma unroll 1
    for (int cc = 0; cc < CH; ++cc) {
        if (cc != 0) __syncthreads();
        #pragma unroll
        for (int k = 0; k < NREG; ++k) {
            const int i = tid + k * 256;
            if (i < NA) {
                const int p = i >> 2, seg = i & 3;
                const int r = p / NC, c = p - r * NC;
                const int grow = h0 - DIL + r, gcol = c - DIL;
                uint4 val = {0u, 0u, 0u, 0u};
                if (grow >= 0 && grow < 64 && gcol >= 0 && gcol < 64)
                    val = *(const uint4*)&xin[((size_t)(b * 64 + grow) * 64 + gcol) * CIN
                                              + cc * 32 + seg * 8];
                *(uint4*)&sA[p * SAS + seg * 8] = val;
            }
        }
        #pragma unroll
        for (int k = 0; k < WPT; ++k) {
            const int i = tid + k * 256;
            if (i < WCH) {
                const int tap = i / (MT * 64);
                const int r = i - tap * (MT * 64);
                const int mt = r >> 6, n = r & 63;
                const uint4 wv = *(const uint4*)&wpk[
                    ((size_t)(tap * (CIN / 32) + cc) * COUT + co0 + mt * 16 + (n & 15)) * 32
                    + (n >> 4) * 8];
                *(uint4*)&sW[i * 8] = wv;
            }
        }
        __syncthreads();

        #pragma unroll
        for (int tap = 0; tap < 9; ++tap) {
            const int ty = tap / 3, tx = tap - ty * 3;
            const int rl = row + ty * DIL;
            bf16x8 wf[MT];
            #pragma unroll
            for (int mt = 0; mt < MT; ++mt)
                wf[mt] = *(const bf16x8*)&sW[((tap * MT + mt) * 64 + lane) * 8];
            #pragma unroll
            for (int nt = 0; nt < NT; ++nt) {
                const int cl = (ntbase + nt) * 16 + l15 + tx * DIL;
                const bf16x8 bp = *(const bf16x8*)&sA[(rl * NC + cl) * SAS + quad * 8];
                #pragma unroll
                for (int mt = 0; mt < MT; ++mt)
                    acc[mt][nt] = __builtin_amdgcn_mfma_f32_16x16x32_bf16(
                        wf[mt], bp, acc[mt][nt], 0, 0, 0);
            }
        }
    }

    const float a = al[0];

    if constexpr (OMODE == 0) {
        __syncthreads();
        ushort* sT = sA;
        #pragma unroll
        for (int mt = 0; mt < MT; ++mt) {
            float sc[4], sh[4], psum[4];
            #pragma unroll
            for (int rr = 0; rr < 4; ++rr) {
                const int co = co0 + mt * 16 + quad * 4 + rr;
                sc[rr] = bng[co] * rsqrtf(bnv[co] + EPSV);
                sh[rr] = (bias[co] - bnm[co]) * sc[rr] + bnb[co];
                psum[rr] = 0.f;
            }
            #pragma unroll
            for (int nt = 0; nt < NT; ++nt) {
                float tv[4];
                #pragma unroll
                for (int rr = 0; rr < 4; ++rr) {
                    float t = acc[mt][nt][rr] * sc[rr] + sh[rr];
                    t = t >= 0.f ? t : a * t;
                    tv[rr] = t;
                    psum[rr] += t;
                }
                ushort4 u;
                u.x = f2bf(tv[0]); u.y = f2bf(tv[1]);
                u.z = f2bf(tv[2]); u.w = f2bf(tv[3]);
                const int px = (ntbase + nt) * 16 + l15;
                *(ushort4*)&sT[(row * 64 + px) * 40 + mt * 16 + quad * 4] = u;
            }
            #pragma unroll
            for (int rr = 0; rr < 4; ++rr) {
                float v = psum[rr];
                v += __shfl_xor(v, 1);
                v += __shfl_xor(v, 2);
                v += __shfl_xor(v, 4);
                v += __shfl_xor(v, 8);
                if (l15 == 0)
                    atomicAdd(&pool[b * 256 + co0 + mt * 16 + quad * 4 + rr], v);
            }
        }
        __syncthreads();
        ushort* dst = (ushort*)outv;
        const int p = tid >> 1, half = tid & 1;
        const uint4 v0 = *(const uint4*)&sT[p * 40 + half * 16];
        const uint4 v1 = *(const uint4*)&sT[p * 40 + half * 16 + 8];
        const size_t off = ((size_t)(b * 4096 + (h0 + (p >> 6)) * 64 + (p & 63))) * 256
                           + co0 + half * 16;
        *(uint4*)&dst[off] = v0;
        *(uint4*)&dst[off + 8] = v1;
    } else {
        float* out = (float*)outv;
        #pragma unroll
        for (int mt = 0; mt < MT; ++mt)
            #pragma unroll
            for (int rr = 0; rr < 4; ++rr) {
                const int co = co0 + mt * 16 + quad * 4 + rr;
                const float sc = bng[co] * rsqrtf(bnv[co] + EPSV);
                const float sh = (bias[co] - bnm[co]) * sc + bnb[co];
                #pragma unroll
                for (int nt = 0; nt < NT; ++nt) {
                    float t = acc[mt][nt][rr] * sc + sh;
                    t = t >= 0.f ? t : a * t;
                    out[((size_t)(b * COUT + co) * 64 + h0 + row) * 64
                        + (ntbase + nt) * 16 + l15] = t;
                }
            }
    }
}

// ---------------------------------------------------------------------------
// MERGED: c2 dilated conv (bf16 ch-last out) + c1 gemm + c3 fbias.
// Grid (49, 4, 4): x<32 -> c2 conv; x>=32 -> flat c1/c3 blocks.
// ---------------------------------------------------------------------------
__global__ __launch_bounds__(256, 2) void c2_c1_c3(
    const ushort* __restrict__ xin,
    const ushort* __restrict__ wpk,
    const float* __restrict__ c2bias, const float* __restrict__ c2gn,
    const float* __restrict__ c2bt, const float* __restrict__ c2mn,
    const float* __restrict__ c2vr, const float* __restrict__ c2al,
    ushort* __restrict__ c2out,
    const ushort* __restrict__ wbf,
    const float* __restrict__ bias, const float* __restrict__ bng,
    const float* __restrict__ bnb, const float* __restrict__ bnm,
    const float* __restrict__ bnv, const float* __restrict__ al,
    ushort* __restrict__ catb,
    const float* __restrict__ pool, const float* __restrict__ c3w,
    const float* __restrict__ c3b, const float* __restrict__ c3g,
    const float* __restrict__ c3bt, const float* __restrict__ c3m,
    const float* __restrict__ c3v, const float* __restrict__ c3a,
    const float* __restrict__ fw, float* __restrict__ fbias)
{
    const int tid = threadIdx.x;
    const int wave = tid >> 6, lane = tid & 63;
    const int l15 = lane & 15, quad = lane >> 4;
    __shared__ __align__(16) char smem[51072];

    if (blockIdx.x < 32) {
        constexpr int CIN = 256, COUT = 128, COTILE = 32, DIL = 2, ROWS = 2;
        constexpr int HR = ROWS + 2 * DIL;
        constexpr int NC = 64 + 2 * DIL;
        constexpr int MT = COTILE / 16;
        constexpr int WPR = 4 / ROWS;
        constexpr int NT = ROWS;
        constexpr int SAS = 40;
        constexpr int CH = CIN / 32;
        constexpr int NA = HR * NC * 4;
        constexpr int NREG = (NA + 255) / 256;
        constexpr int WCH = 9 * MT * 64;
        constexpr int WPT = (WCH + 255) / 256;

        ushort* sA = (ushort*)smem;
        ushort* sW = (ushort*)(smem + 32640);

        const int b = blockIdx.z;
        const int co0 = blockIdx.y * COTILE;
        const int h0 = blockIdx.x * ROWS;
        const int row = wave / WPR;
        const int ntbase = (wave % WPR) * NT;

        f32x4 acc[MT][NT];
        #pragma unroll
        for (int mt = 0; mt < MT; ++mt)
            #pragma unroll
            for (int nt = 0; nt < NT; ++nt) acc[mt][nt] = (f32x4){0.f, 0.f, 0.f, 0.f};

        #pragma unroll 1
        for (int cc = 0; cc < CH; ++cc) {
            if (cc != 0) __syncthreads();
            #pragma unroll
            for (int k = 0; k < NREG; ++k) {
                const int i = tid + k * 256;
                if (i < NA) {
                    const int p = i >> 2, seg = i & 3;
                    const int r = p / NC, c = p - r * NC;
                    const int grow = h0 - DIL + r, gcol = c - DIL;
                    uint4 val = {0u, 0u, 0u, 0u};
                    if (grow >= 0 && grow < 64 && gcol >= 0 && gcol < 64)
                        val = *(const uint4*)&xin[((size_t)(b * 64 + grow) * 64 + gcol) * CIN
                                                  + cc * 32 + seg * 8];
                    *(uint4*)&sA[p * SAS + seg * 8] = val;
                }
            }
            #pragma unroll
            for (int k = 0; k < WPT; ++k) {
                const int i = tid + k * 256;
                if (i < WCH) {
                    const int tap = i / (MT * 64);
                    const int r = i - tap * (MT * 64);
                    const int mt = r >> 6, n = r & 63;
                    const uint4 wv = *(const uint4*)&wpk[
                        ((size_t)(tap * (CIN / 32) + cc) * COUT + co0 + mt * 16 + (n & 15)) * 32
                        + (n >> 4) * 8];
                    *(uint4*)&sW[i * 8] = wv;
                }
            }
            __syncthreads();

            #pragma unroll
            for (int tap = 0; tap < 9; ++tap) {
                const int ty = tap / 3, tx = tap - ty * 3;
                const int rl = row + ty * DIL;
                bf16x8 wf[MT];
                #pragma unroll
                for (int mt = 0; mt < MT; ++mt)
                    wf[mt] = *(const bf16x8*)&sW[((tap * MT + mt) * 64 + lane) * 8];
                #pragma unroll
                for (int nt = 0; nt < NT; ++nt) {
                    const int cl = (ntbase + nt) * 16 + l15 + tx * DIL;
                    const bf16x8 bp = *(const bf16x8*)&sA[(rl * NC + cl) * SAS + quad * 8];
                    #pragma unroll
                    for (int mt = 0; mt < MT; ++mt)
                        acc[mt][nt] = __builtin_amdgcn_mfma_f32_16x16x32_bf16(
                            wf[mt], bp, acc[mt][nt], 0, 0, 0);
                }
            }
        }

        const float a = c2al[0];
        __syncthreads();
        ushort* sTc = (ushort*)smem;
        #pragma unroll
        for (int mt = 0; mt < MT; ++mt) {
            float sc[4], sh[4];
            #pragma unroll
            for (int rr = 0; rr < 4; ++rr) {
                const int co = co0 + mt * 16 + quad * 4 + rr;
                sc[rr] = c2gn[co] * rsqrtf(c2vr[co] + EPSV);
                sh[rr] = (c2bias[co] - c2mn[co]) * sc[rr] + c2bt[co];
            }
            #pragma unroll
            for (int nt = 0; nt < NT; ++nt) {
                float tv[4];
                #pragma unroll
                for (int rr = 0; rr < 4; ++rr) {
                    float t = acc[mt][nt][rr] * sc[rr] + sh[rr];
                    tv[rr] = t >= 0.f ? t : a * t;
                }
                ushort4 u;
                u.x = f2bf(tv[0]); u.y = f2bf(tv[1]);
                u.z = f2bf(tv[2]); u.w = f2bf(tv[3]);
                const int px = (ntbase + nt) * 16 + l15;
                *(ushort4*)&sTc[(row * 64 + px) * 40 + mt * 16 + quad * 4] = u;
            }
        }
        __syncthreads();
        const int p = tid >> 1, half = tid & 1;
        const uint4 v0 = *(const uint4*)&sTc[p * 40 + half * 16];
        const uint4 v1 = *(const uint4*)&sTc[p * 40 + half * 16 + 8];
        const size_t off = ((size_t)(b * 4096 + (h0 + (p >> 6)) * 64 + (p & 63))) * 128
                           + co0 + half * 16;
        *(uint4*)&c2out[off] = v0;
        *(uint4*)&c2out[off + 8] = v1;
        return;
    }

    const int flat = (blockIdx.z * 4 + blockIdx.y) * 17 + (blockIdx.x - 32);
    if (flat >= 260) return;
    const int bx = flat % 130, by = flat / 130;

    if (bx >= 128) {
        const int b = (bx - 128) * 2 + by;
        float* sp  = (float*)smem;
        float* sc3 = (float*)(smem + 2048);
        sp[tid] = pool[b * 256 + tid] * (1.0f / 4096.0f);
        __syncthreads();
        if (tid < 128) {
            float acc2 = c3b[tid];
            for (int ci = 0; ci < 256; ++ci) acc2 = fmaf(c3w[tid * 256 + ci], sp[ci], acc2);
            const float scale = c3g[tid] * rsqrtf(c3v[tid] + EPSV);
            float t = (acc2 - c3m[tid]) * scale + c3bt[tid];
            const float a2 = c3a[0];
            sc3[tid] = t >= 0.f ? t : a2 * t;
        }
        __syncthreads();
        float f = 0.f;
        for (int j2 = 0; j2 < 128; ++j2) f = fmaf(fw[tid * 384 + 256 + j2], sc3[j2], f);
        fbias[b * 256 + tid] = f;
        return;
    }

    {
        constexpr int CIN = 256;
        const int pix0 = bx * 128 + wave * 32;
        const int co0 = by * 64;

        f32x4 acc[4][2];
        #pragma unroll
        for (int mt = 0; mt < 4; ++mt)
            #pragma unroll
            for (int nt = 0; nt < 2; ++nt) acc[mt][nt] = (f32x4){0.f, 0.f, 0.f, 0.f};

        #pragma unroll 2
        for (int cc = 0; cc < CIN / 32; ++cc) {
            bf16x8 aw[4], bp[2];
            #pragma unroll
            for (int mt = 0; mt < 4; ++mt)
                aw[mt] = *(const bf16x8*)&wbf[(size_t)(co0 + mt * 16 + l15) * CIN + cc * 32 + quad * 8];
            #pragma unroll
            for (int nt = 0; nt < 2; ++nt)
                bp[nt] = *(const bf16x8*)&xin[(size_t)(pix0 + nt * 16 + l15) * CIN + cc * 32 + quad * 8];
            #pragma unroll
            for (int mt = 0; mt < 4; ++mt)
                #pragma unroll
                for (int nt = 0; nt < 2; ++nt)
                    acc[mt][nt] = __builtin_amdgcn_mfma_f32_16x16x32_bf16(
                        aw[mt], bp[nt], acc[mt][nt], 0, 0, 0);
        }

        const float a = al[0];
        ushort* sT = (ushort*)smem;
        #pragma unroll
        for (int mt = 0; mt < 4; ++mt)
            #pragma unroll
            for (int r = 0; r < 4; ++r) {
                const int co = co0 + mt * 16 + quad * 4 + r;
                const float scale = bng[co] * rsqrtf(bnv[co] + EPSV);
                const float shift = bias[co] * scale + (bnb[co] - bnm[co] * scale);
                #pragma unroll
                for (int nt = 0; nt < 2; ++nt) {
                    float t = acc[mt][nt][r] * scale + shift;
                    t = t >= 0.f ? t : a * t;
                    sT[((wave * 32 + nt * 16 + l15) * 68) + mt * 16 + quad * 4 + r] = f2bf(t);
                }
            }
        __syncthreads();
        const int p = lane >> 1, half = lane & 1;
        #pragma unroll
        for (int seg = 0; seg < 4; ++seg) {
            uint2 a0 = *(uint2*)&sT[((wave * 32 + p) * 68) + half * 32 + seg * 8];
            uint2 a1 = *(uint2*)&sT[((wave * 32 + p) * 68) + half * 32 + seg * 8 + 4];
            uint4 vv = {a0.x, a0.y, a1.x, a1.y};
            *(uint4*)&catb[(size_t)(pix0 + p) * 256 + co0 + half * 32 + seg * 8] = vv;
        }
    }
}

// ---------------------------------------------------------------------------
// MFMA 1x1 conv on channel-last bf16 input (used for the FUSE conv, OMODE 0).
// ---------------------------------------------------------------------------
template<int CIN, int COUT, bool BNACT, int OMODE>
__global__ __launch_bounds__(256) void gemm1x1_cl(
    const ushort* __restrict__ xin,
    const ushort* __restrict__ wbf,
    const float* __restrict__ bias, const float* __restrict__ bng,
    const float* __restrict__ bnb, const float* __restrict__ bnm,
    const float* __restrict__ bnv, const float* __restrict__ al,
    const float* __restrict__ ebias, void* __restrict__ outv,
    int ostride, int ocol)
{
    const int tid = threadIdx.x;
    const int wave = tid >> 6, lane = tid & 63;
    const int l15 = lane & 15, quad = lane >> 4;
    const int pix0 = blockIdx.x * 128 + wave * 32;
    const int co0 = blockIdx.y * 64;

    f32x4 acc[4][2];
    #pragma unroll
    for (int mt = 0; mt < 4; ++mt)
        #pragma unroll
        for (int nt = 0; nt < 2; ++nt) acc[mt][nt] = (f32x4){0.f, 0.f, 0.f, 0.f};

    #pragma unroll 2
    for (int cc = 0; cc < CIN / 32; ++cc) {
        bf16x8 aw[4], bp[2];
        #pragma unroll
        for (int mt = 0; mt < 4; ++mt)
            aw[mt] = *(const bf16x8*)&wbf[(size_t)(co0 + mt * 16 + l15) * CIN + cc * 32 + quad * 8];
        #pragma unroll
        for (int nt = 0; nt < 2; ++nt)
            bp[nt] = *(const bf16x8*)&xin[(size_t)(pix0 + nt * 16 + l15) * CIN + cc * 32 + quad * 8];
        #pragma unroll
        for (int mt = 0; mt < 4; ++mt)
            #pragma unroll
            for (int nt = 0; nt < 2; ++nt)
                acc[mt][nt] = __builtin_amdgcn_mfma_f32_16x16x32_bf16(
                    aw[mt], bp[nt], acc[mt][nt], 0, 0, 0);
    }

    const int bI = pix0 >> 12;
    const float a = BNACT ? al[0] : 0.f;

    if (OMODE == 0) {
        float* out = (float*)outv;
        #pragma unroll
        for (int mt = 0; mt < 4; ++mt)
            #pragma unroll
            for (int r = 0; r < 4; ++r) {
                const int co = co0 + mt * 16 + quad * 4 + r;
                float bb = bias[co];
                if (ebias) bb += ebias[bI * COUT + co];
                float scale = 1.f, shift = bb;
                if (BNACT) {
                    scale = bng[co] * rsqrtf(bnv[co] + EPSV);
                    shift = bb * scale + (bnb[co] - bnm[co] * scale);
                }
                #pragma unroll
                for (int nt = 0; nt < 2; ++nt) {
                    float t = acc[mt][nt][r] * scale + shift;
                    if (BNACT) t = t >= 0.f ? t : a * t;
                    out[((size_t)(bI * COUT + co)) * HW + (pix0 & 4095) + nt * 16 + l15] = t;
                }
            }
    } else {
        __shared__ ushort sT[4][32][68];
        #pragma unroll
        for (int mt = 0; mt < 4; ++mt)
            #pragma unroll
            for (int r = 0; r < 4; ++r) {
                const int co = co0 + mt * 16 + quad * 4 + r;
                float bb = bias[co];
                float scale = 1.f, shift = bb;
                if (BNACT) {
                    scale = bng[co] * rsqrtf(bnv[co] + EPSV);
                    shift = bb * scale + (bnb[co] - bnm[co] * scale);
                }
                #pragma unroll
                for (int nt = 0; nt < 2; ++nt) {
                    float t = acc[mt][nt][r] * scale + shift;
                    if (BNACT) t = t >= 0.f ? t : a * t;
                    sT[wave][nt * 16 + l15][mt * 16 + quad * 4 + r] = f2bf(t);
                }
            }
        __syncthreads();
        const int p = lane >> 1, half = lane & 1;
        ushort* out = (ushort*)outv;
        #pragma unroll
        for (int seg = 0; seg < 4; ++seg) {
            uint2 a0 = *(uint2*)&sT[wave][p][half * 32 + seg * 8];
            uint2 a1 = *(uint2*)&sT[wave][p][half * 32 + seg * 8 + 4];
            uint4 vv = {a0.x, a0.y, a1.x, a1.y};
            *(uint4*)&out[(size_t)(pix0 + p) * ostride + ocol + co0 + half * 32 + seg * 8] = vv;
        }
    }
}

// ---------------------------------------------------------------------------
// qk + v as MFMA gemms on bf16 ch-last c2bh (r13-verified).  Grid (32, 3, 4).
// ---------------------------------------------------------------------------
__global__ __launch_bounds__(256) void qkv_mfma(
    const ushort* __restrict__ c2bh,
    const ushort* __restrict__ wqkb,
    const float* __restrict__ qb2, const float* __restrict__ kb2,
    ushort* __restrict__ qpack, ushort* __restrict__ kpack,
    const ushort* __restrict__ wvb,
    const float* __restrict__ vb, ushort* __restrict__ vbh)
{
    const int tid = threadIdx.x;
    const int wave = tid >> 6, lane = tid & 63;
    const int l15 = lane & 15, quad = lane >> 4;
    const int b = blockIdx.z;
    const int pix0 = blockIdx.x * 128 + wave * 32;
    const size_t xrow = (size_t)(b * 4096);

    if (blockIdx.y == 0) {
        f32x4 acc[2][2];
        #pragma unroll
        for (int mt = 0; mt < 2; ++mt)
            #pragma unroll
            for (int nt = 0; nt < 2; ++nt) acc[mt][nt] = (f32x4){0.f, 0.f, 0.f, 0.f};
        #pragma unroll
        for (int cc = 0; cc < 4; ++cc) {
            bf16x8 aw[2], bp[2];
            #pragma unroll
            for (int mt = 0; mt < 2; ++mt)
                aw[mt] = *(const bf16x8*)&wqkb[(mt * 16 + l15) * 128 + cc * 32 + quad * 8];
            #pragma unroll
            for (int nt = 0; nt < 2; ++nt)
                bp[nt] = *(const bf16x8*)&c2bh[(xrow + pix0 + nt * 16 + l15) * 128 + cc * 32 + quad * 8];
            #pragma unroll
            for (int mt = 0; mt < 2; ++mt)
                #pragma unroll
                for (int nt = 0; nt < 2; ++nt)
                    acc[mt][nt] = __builtin_amdgcn_mfma_f32_16x16x32_bf16(
                        aw[mt], bp[nt], acc[mt][nt], 0, 0, 0);
        }
        __shared__ __align__(16) ushort sT[4][32][40];
        #pragma unroll
        for (int mt = 0; mt < 2; ++mt)
            #pragma unroll
            for (int r = 0; r < 4; ++r) {
                const int co = mt * 16 + quad * 4 + r;
                const float bb = (co < 16) ? qb2[co] : kb2[co - 16];
                #pragma unroll
                for (int nt = 0; nt < 2; ++nt)
                    sT[wave][nt * 16 + l15][co] = f2bf(acc[mt][nt][r] + bb);
            }
        __syncthreads();
        const int p = lane >> 1, half = lane & 1;
        ushort* dst = half ? kpack : qpack;
        const int cbase = half ? 16 : 0;
        const size_t off = (size_t)(b * 4096 + pix0 + p) * 32;
        *(uint4*)&dst[off]     = *(uint4*)&sT[wave][p][cbase];
        *(uint4*)&dst[off + 8] = *(uint4*)&sT[wave][p][cbase + 8];
        const uint4 zz = {0u, 0u, 0u, 0u};
        *(uint4*)&dst[off + 16] = zz;
        *(uint4*)&dst[off + 24] = zz;
    } else {
        const int co0 = (blockIdx.y - 1) * 64;
        f32x4 acc[4][2];
        #pragma unroll
        for (int mt = 0; mt < 4; ++mt)
            #pragma unroll
            for (int nt = 0; nt < 2; ++nt) acc[mt][nt] = (f32x4){0.f, 0.f, 0.f, 0.f};
        #pragma unroll
        for (int cc = 0; cc < 4; ++cc) {
            bf16x8 aw[4], bp[2];
            #pragma unroll
            for (int mt = 0; mt < 4; ++mt)
                aw[mt] = *(const bf16x8*)&wvb[(size_t)(co0 + mt * 16 + l15) * 128 + cc * 32 + quad * 8];
            #pragma unroll
            for (int nt = 0; nt < 2; ++nt)
                bp[nt] = *(const bf16x8*)&c2bh[(xrow + pix0 + nt * 16 + l15) * 128 + cc * 32 + quad * 8];
            #pragma unroll
            for (int mt = 0; mt < 4; ++mt)
                #pragma unroll
                for (int nt = 0; nt < 2; ++nt)
                    acc[mt][nt] = __builtin_amdgcn_mfma_f32_16x16x32_bf16(
                        aw[mt], bp[nt], acc[mt][nt], 0, 0, 0);
        }
        #pragma unroll
        for (int mt = 0; mt < 4; ++mt)
            #pragma unroll
            for (int r = 0; r < 4; ++r) {
                const int co = co0 + mt * 16 + quad * 4 + r;
                const float shift = vb[co];
                #pragma unroll
                for (int nt = 0; nt < 2; ++nt) {
                    const int px = pix0 + nt * 16 + l15;
                    vbh[(size_t)(b * 128 + co) * HW + px] = f2bf(acc[mt][nt][r] + shift);
                }
            }
    }
}

// ---------------------------------------------------------------------------
// SINGLE-PASS flash attention, msplit=4 (r14): m range 1024 per block,
// halves opart traffic and combine work.  Grid: (32 nblk, 4 msplit, 4 batch).
// ---------------------------------------------------------------------------
__global__ __launch_bounds__(256) void attn_flash(
    const ushort* __restrict__ qpack,
    const ushort* __restrict__ kpack,
    const ushort* __restrict__ vpackT,
    ushort* __restrict__ opart,       // [b][4j][4096n][128c] bf16
    float* __restrict__ Mpart,        // [b][4j][4096n]
    float* __restrict__ Spart)
{
    const int tid = threadIdx.x;
    const int wave = tid >> 6, lane = tid & 63;
    const int l15 = lane & 15, quad = lane >> 4;
    const int b = blockIdx.z, j = blockIdx.y;
    const int n0w = blockIdx.x * 128 + wave * 32;
    const int m_begin = j * 1024;

    __shared__ __align__(16) ushort sV[2][128][40];
    __shared__ __align__(16) ushort sP[4][2][16][40];

    const bf16x8 bq0 = *(const bf16x8*)(qpack + ((size_t)(b * 4096 + n0w + l15) * 32 + quad * 8));
    const bf16x8 bq1 = *(const bf16x8*)(qpack + ((size_t)(b * 4096 + n0w + 16 + l15) * 32 + quad * 8));
    const f32x4 z = {0.f, 0.f, 0.f, 0.f};

    float runM0 = -3e30f, runM1 = -3e30f;
    float runS0 = 0.f, runS1 = 0.f;
    f32x4 oacc0[8], oacc1[8];
    #pragma unroll
    for (int cs = 0; cs < 8; ++cs) {
        oacc0[cs] = (f32x4){0.f, 0.f, 0.f, 0.f};
        oacc1[cs] = (f32x4){0.f, 0.f, 0.f, 0.f};
    }

    const int stc = tid >> 1, stseg = tid & 1;

    {
        uint4 v0 = *(const uint4*)&vpackT[(size_t)(b * 128 + stc) * HW + m_begin + stseg * 16];
        uint4 v1 = *(const uint4*)&vpackT[(size_t)(b * 128 + stc) * HW + m_begin + stseg * 16 + 8];
        *(uint4*)&sV[0][stc][stseg * 16] = v0;
        *(uint4*)&sV[0][stc][stseg * 16 + 8] = v1;
    }
    __syncthreads();

    #pragma unroll 1
    for (int t = 0; t < 32; ++t) {
        const int m0 = m_begin + t * 32;
        const int buf = t & 1;
        uint4 nv0, nv1;
        const bool more = (t + 1 < 32);
        if (more) {
            const size_t nb = (size_t)(b * 128 + stc) * HW + m0 + 32 + stseg * 16;
            nv0 = *(const uint4*)&vpackT[nb];
            nv1 = *(const uint4*)&vpackT[nb + 8];
        }
        f32x4 s0[2], s1[2];
        #pragma unroll
        for (int ms = 0; ms < 2; ++ms) {
            const bf16x8 ak = *(const bf16x8*)(
                kpack + ((size_t)(b * 4096 + m0 + ms * 16 + l15) * 32 + quad * 8));
            s0[ms] = __builtin_amdgcn_mfma_f32_16x16x32_bf16(ak, bq0, z, 0, 0, 0);
            s1[ms] = __builtin_amdgcn_mfma_f32_16x16x32_bf16(ak, bq1, z, 0, 0, 0);
        }

        float tM0 = fmaxf(fmaxf(fmaxf(s0[0][0], s0[0][1]), fmaxf(s0[0][2], s0[0][3])),
                          fmaxf(fmaxf(s0[1][0], s0[1][1]), fmaxf(s0[1][2], s0[1][3])));
        float tM1 = fmaxf(fmaxf(fmaxf(s1[0][0], s1[0][1]), fmaxf(s1[0][2], s1[0][3])),
                          fmaxf(fmaxf(s1[1][0], s1[1][1]), fmaxf(s1[1][2], s1[1][3])));
        tM0 = fmaxf(tM0, __shfl_xor(tM0, 16));
        tM0 = fmaxf(tM0, __shfl_xor(tM0, 32));
        tM1 = fmaxf(tM1, __shfl_xor(tM1, 16));
        tM1 = fmaxf(tM1, __shfl_xor(tM1, 32));
        if (__any(tM0 > runM0 + 8.f)) {
            const float nM = fmaxf(runM0, tM0);
            const float sc = __builtin_amdgcn_exp2f((runM0 - nM) * 1.44269504f);
            runS0 *= sc;
            float scr[4];
            #pragma unroll
            for (int r = 0; r < 4; ++r) scr[r] = __shfl(sc, quad * 4 + r);
            #pragma unroll
            for (int cs = 0; cs < 8; ++cs) {
                oacc0[cs][0] *= scr[0]; oacc0[cs][1] *= scr[1];
                oacc0[cs][2] *= scr[2]; oacc0[cs][3] *= scr[3];
            }
            runM0 = nM;
        }
        if (__any(tM1 > runM1 + 8.f)) {
            const float nM = fmaxf(runM1, tM1);
            const float sc = __builtin_amdgcn_exp2f((runM1 - nM) * 1.44269504f);
            runS1 *= sc;
            float scr[4];
            #pragma unroll
            for (int r = 0; r < 4; ++r) scr[r] = __shfl(sc, quad * 4 + r);
            #pragma unroll
            for (int cs = 0; cs < 8; ++cs) {
                oacc1[cs][0] *= scr[0]; oacc1[cs][1] *= scr[1];
                oacc1[cs][2] *= scr[2]; oacc1[cs][3] *= scr[3];
            }
            runM1 = nM;
        }
        const float Ms0 = runM0 * 1.44269504f;
        const float Ms1 = runM1 * 1.44269504f;

        #pragma unroll
        for (int ms = 0; ms < 2; ++ms) {
            float p0[4], p1[4];
            #pragma unroll
            for (int r = 0; r < 4; ++r) {
                p0[r] = __builtin_amdgcn_exp2f(fmaf(s0[ms][r], 1.44269504f, -Ms0));
                p1[r] = __builtin_amdgcn_exp2f(fmaf(s1[ms][r], 1.44269504f, -Ms1));
                runS0 += p0[r];
                runS1 += p1[r];
            }
            ushort4 u0, u1;
            u0.x = f2bf(p0[0]); u0.y = f2bf(p0[1]); u0.z = f2bf(p0[2]); u0.w = f2bf(p0[3]);
            u1.x = f2bf(p1[0]); u1.y = f2bf(p1[1]); u1.z = f2bf(p1[2]); u1.w = f2bf(p1[3]);
            *(uint2*)&sP[wave][0][l15][ms * 16 + quad * 4] = *(uint2*)&u0;
            *(uint2*)&sP[wave][1][l15][ms * 16 + quad * 4] = *(uint2*)&u1;
        }
        asm volatile("s_waitcnt lgkmcnt(0)" ::: "memory");
        const bf16x8 ap0 = *(const bf16x8*)&sP[wave][0][l15][quad * 8];
        const bf16x8 ap1 = *(const bf16x8*)&sP[wave][1][l15][quad * 8];
        #pragma unroll
        for (int cs = 0; cs < 8; ++cs) {
            const bf16x8 bv = *(const bf16x8*)&sV[buf][cs * 16 + l15][quad * 8];
            oacc0[cs] = __builtin_amdgcn_mfma_f32_16x16x32_bf16(ap0, bv, oacc0[cs], 0, 0, 0);
            oacc1[cs] = __builtin_amdgcn_mfma_f32_16x16x32_bf16(ap1, bv, oacc1[cs], 0, 0, 0);
        }
        if (more) {
            *(uint4*)&sV[buf ^ 1][stc][stseg * 16] = nv0;
            *(uint4*)&sV[buf ^ 1][stc][stseg * 16 + 8] = nv1;
            __syncthreads();
        }
    }

    runS0 += __shfl_xor(runS0, 16);
    runS0 += __shfl_xor(runS0, 32);
    runS1 += __shfl_xor(runS1, 16);
    runS1 += __shfl_xor(runS1, 32);
    if (lane < 32) {
        const float Mv = (lane < 16) ? runM0 : runM1;
        const float Sv = (lane < 16) ? runS0 : runS1;
        const int n = n0w + ((lane < 16) ? 0 : 16) + l15;
        Mpart[((size_t)b * 4 + j) * 4096 + n] = Mv;
        Spart[((size_t)b * 4 + j) * 4096 + n] = Sv;
    }
    #pragma unroll
    for (int cs = 0; cs < 8; ++cs)
        #pragma unroll
        for (int r = 0; r < 4; ++r) {
            const int n = n0w + quad * 4 + r;
            opart[(((size_t)b * 4 + j) * 4096 + n) * 128 + cs * 16 + l15] = f2bf(oacc0[cs][r]);
            opart[(((size_t)b * 4 + j) * 4096 + n + 16) * 128 + cs * 16 + l15] = f2bf(oacc1[cs][r]);
        }
}

// ---------------------------------------------------------------------------
// Combine 4 m-split partials (r14), normalize, fuse gamma2*O + c2 residual.
// ---------------------------------------------------------------------------
__global__ __launch_bounds__(256) void attn_combine(
    const ushort* __restrict__ opart, const float* __restrict__ Mpart,
    const float* __restrict__ Spart, const ushort* __restrict__ c2bh,
    const float* __restrict__ gamma2, ushort* __restrict__ catb)
{
    const int b = blockIdx.y, n0 = blockIdx.x * 32, tid = threadIdx.x;
    __shared__ float sC2[128][33];
    __shared__ float sWj[4][32];
    if (tid < 32) {
        const int n = n0 + tid;
        float Mj[4], Sj[4];
        #pragma unroll
        for (int j = 0; j < 4; ++j) {
            Mj[j] = Mpart[((size_t)b * 4 + j) * 4096 + n];
            Sj[j] = Spart[((size_t)b * 4 + j) * 4096 + n];
        }
        float M = -3e30f;
        #pragma unroll
        for (int j = 0; j < 4; ++j) M = fmaxf(M, Mj[j]);
        float St = 0.f, e[4];
        #pragma unroll
        for (int j = 0; j < 4; ++j) { e[j] = __expf(Mj[j] - M); St += Sj[j] * e[j]; }
        const float inv = 1.0f / St;
        #pragma unroll
        for (int j = 0; j < 4; ++j) sWj[j][tid] = e[j] * inv;
    }
    #pragma unroll
    for (int e = 0; e < 16; ++e) {
        const int idx = tid + e * 256;
        const int n = idx >> 7, c = idx & 127;
        sC2[c][n] = bf2f(c2bh[(size_t)(b * 4096 + n0 + n) * 128 + c]);
    }
    __syncthreads();
    const float g2 = gamma2[0];
    #pragma unroll
    for (int e = 0; e < 16; ++e) {
        const int idx = tid + e * 256;
        const int n = idx >> 7, c = idx & 127;
        float s = 0.f;
        #pragma unroll
        for (int j = 0; j < 4; ++j)
            s += bf2f(opart[(((size_t)b * 4 + j) * 4096 + n0 + n) * 128 + c]) * sWj[j][n];
        catb[(size_t)(b * 4096 + n0 + n) * 256 + 128 + c] = f2bf(fmaf(g2, s, sC2[c][n]));
    }
}

// ---------------------------------------------------------------------------
extern "C" void kernel_launch(void* const* d_in, const int* in_sizes, int n_in,
                              void* d_out, int out_size, void* d_ws, size_t ws_size,
                              hipStream_t stream)
{
    const float* x     = (const float*)d_in[0];
    const float* dc_w  = (const float*)d_in[1];
    const float* dc_b  = (const float*)d_in[2];
    const float* dc_g  = (const float*)d_in[3];
    const float* dc_bt = (const float*)d_in[4];
    const float* dc_m  = (const float*)d_in[5];
    const float* dc_v  = (const float*)d_in[6];
    const float* dc_a  = (const float*)d_in[7];
    const float* c1_w  = (const float*)d_in[8];
    const float* c1_b  = (const float*)d_in[9];
    const float* c1_g  = (const float*)d_in[10];
    const float* c1_bt = (const float*)d_in[11];
    const float* c1_m  = (const float*)d_in[12];
    const float* c1_v  = (const float*)d_in[13];
    const float* c1_a  = (const float*)d_in[14];
    const float* c2_w  = (const float*)d_in[15];
    const float* c2_b  = (const float*)d_in[16];
    const float* c2_g  = (const float*)d_in[17];
    const float* c2_bt = (const float*)d_in[18];
    const float* c2_m  = (const float*)d_in[19];
    const float* c2_v  = (const float*)d_in[20];
    const float* c2_a  = (const float*)d_in[21];
    const float* q_w   = (const float*)d_in[22];
    const float* q_b   = (const float*)d_in[23];
    const float* k_w   = (const float*)d_in[24];
    const float* k_b   = (const float*)d_in[25];
    const float* v_w   = (const float*)d_in[26];
    const float* v_b   = (const float*)d_in[27];
    const float* gamma2= (const float*)d_in[28];
    const float* c3_w  = (const float*)d_in[29];
    const float* c3_b  = (const float*)d_in[30];
    const float* c3_g  = (const float*)d_in[31];
    const float* c3_bt = (const float*)d_in[32];
    const float* c3_m  = (const float*)d_in[33];
    const float* c3_v  = (const float*)d_in[34];
    const float* c3_a  = (const float*)d_in[35];
    const float* f_w   = (const float*)d_in[36];
    const float* f_b   = (const float*)d_in[37];
    const float* f_g   = (const float*)d_in[38];
    const float* f_bt  = (const float*)d_in[39];
    const float* f_m   = (const float*)d_in[40];
    const float* f_v   = (const float*)d_in[41];
    const float* f_a   = (const float*)d_in[42];

    // ---- workspace layout by live range ----
    char* base = (char*)d_ws;
    ushort* xbf   = (ushort*)base;                       // [4,4096,512] bf16
    ushort* opart = (ushort*)base;                       // [4,4,4096,128] bf16 (r14)
    ushort* qpk   = (ushort*)(base + 33554432);          // [4,4096,32]
    ushort* kpk   = (ushort*)(base + 34603008);
    ushort* vbh   = (ushort*)(base + 35651584);          // [4,128,4096] bf16
    ushort* c2bh  = (ushort*)(base + 39845888);          // [4,4096,128] bf16
    ushort* wqkb  = (ushort*)(base + 48234496);          // [32,128] bf16
    ushort* wvb   = (ushort*)(base + 48242688);          // [128,128] bf16
    ushort* xpbf  = (ushort*)(base + 50331648);          // [4,4096,256] bf16
    ushort* catb  = (ushort*)(base + 58720256);          // [4,4096,256] bf16
    ushort* wdcp  = (ushort*)(base + 75497472);          // [9,16,256,32]
    ushort* wc2p  = (ushort*)(base + 77856768);          // [9,8,128,32]
    ushort* wc1b  = (ushort*)(base + 78446592);          // [128,256]
    ushort* wfb   = (ushort*)(base + 78512128);          // [256,256]
    float*  poolb = (float*)(base + 78643200);           // 1024 (atomic sums)
    float*  fbb   = (float*)(base + 78647296);           // 1024
    float*  Mpart = (float*)(base + 78651392);           // [4,4,4096]
    float*  Spart = (float*)(base + 79175680);           // [4,4,4096]

    // 0. packs (+qk/v bf16) + pool zero + x->chlast (ONE launch)
    pack_and_chlast<<<dim3(6228 + 2048), 256, 0, stream>>>(
        dc_w, wdcp, c2_w, wc2p, c1_w, wc1b, f_w, wfb,
        q_w, k_w, wqkb, v_w, wvb, poolb, x, xbf);
    // 1. down_conv 3x3 512->256, full-K, fused BN+PReLU -> xpbf + pool atomics
    conv3x3_fused<512, 256, 32, 1, 2, 0><<<dim3(32, 8, 4), 256, 0, stream>>>(
        xbf, wdcp, dc_b, dc_g, dc_bt, dc_m, dc_v, dc_a, xpbf, poolb);
    // 2. c2 dilated conv (bf16 ch-last) + c1 gemm + c3 fbias (ONE launch)
    c2_c1_c3<<<dim3(49, 4, 4), 256, 0, stream>>>(
        xpbf, wc2p, c2_b, c2_g, c2_bt, c2_m, c2_v, c2_a, c2bh,
        wc1b, c1_b, c1_g, c1_bt, c1_m, c1_v, c1_a, catb,
        poolb, c3_w, c3_b, c3_g, c3_bt, c3_m, c3_v, c3_a, f_w, fbb);
    // 3. q, k, v — all MFMA on bf16 ch-last
    qkv_mfma<<<dim3(32, 3, 4), 256, 0, stream>>>(
        c2bh, wqkb, q_b, k_b, qpk, kpk, wvb, v_b, vbh);
    // 4. single-pass online flash attention (msplit=4, r14) + combine
    attn_flash<<<dim3(32, 4, 4), 256, 0, stream>>>(qpk, kpk, vbh, opart, Mpart, Spart);
    attn_combine<<<dim3(128, 4), 256, 0, stream>>>(opart, Mpart, Spart, c2bh, gamma2, catb);
    // 5. fuse conv (MFMA, K=256) -> d_out
    gemm1x1_cl<256, 256, true, 0><<<dim3(128, 4), 256, 0, stream>>>(
        catb, wfb, f_b, f_g, f_bt, f_m, f_v, f_a, fbb, (float*)d_out, 0, 0);
}

// Round 15
// 351.506 us; speedup vs baseline: 1.3138x; 1.0409x over previous
//
#include <hip/hip_runtime.h>
#include <hip/hip_bf16.h>
#include <math.h>

#define HW 4096
#define EPSV 1e-5f

#if defined(__has_builtin)
#if __has_builtin(__builtin_amdgcn_global_load_lds)
#define USE_GLL 1
#endif
#endif
#ifndef USE_GLL
#define USE_GLL 0
#endif

typedef unsigned short ushort;
typedef __attribute__((ext_vector_type(8))) short bf16x8;
typedef __attribute__((ext_vector_type(4))) float f32x4;

__device__ inline ushort f2bf(float f) {
    __hip_bfloat16 h = __float2bfloat16(f);
    return *reinterpret_cast<ushort*>(&h);
}
__device__ inline float bf2f(ushort u) {
    unsigned int v = ((unsigned int)u) << 16;
    return __uint_as_float(v);
}

// ---------------------------------------------------------------------------
// MERGED: all weight packs (+ qk/v bf16) + pool zero + x->chlast.
// ---------------------------------------------------------------------------
__global__ __launch_bounds__(256) void pack_and_chlast(
    const float* __restrict__ dc_w, ushort* __restrict__ wdcp,
    const float* __restrict__ c2_w, ushort* __restrict__ wc2p,
    const float* __restrict__ c1_w, ushort* __restrict__ wc1b,
    const float* __restrict__ f_w,  ushort* __restrict__ wfb,
    const float* __restrict__ q_w,  const float* __restrict__ k_w,
    ushort* __restrict__ wqkb,
    const float* __restrict__ v_w,  ushort* __restrict__ wvb,
    float* __restrict__ pool,
    const float* __restrict__ x, ushort* __restrict__ xbf)
{
    constexpr int PACK_BLKS = 6228;
    constexpr int T_DC = 9 * 16 * 256 * 32;
    constexpr int T_C2 = 9 * 8 * 128 * 32;
    constexpr int T_C1 = 32768;
    constexpr int T_F  = 65536;
    constexpr int T_QK = 4096;
    constexpr int T_V  = 16384;
    const int tid = threadIdx.x;
    __shared__ float sT[64][65];

    if (blockIdx.x < PACK_BLKS) {
        int idx = blockIdx.x * 256 + tid;
        if (idx < T_DC) {
            const int ci_in = idx & 31;
            int rest = idx >> 5;
            const int co = rest % 256; rest /= 256;
            const int cc = rest % 16;
            const int tap = rest / 16;
            wdcp[idx] = f2bf(dc_w[((size_t)co * 512 + cc * 32 + ci_in) * 9 + tap]);
            return;
        }
        idx -= T_DC;
        if (idx < T_C2) {
            const int ci_in = idx & 31;
            int rest = idx >> 5;
            const int co = rest % 128; rest /= 128;
            const int cc = rest % 8;
            const int tap = rest / 8;
            wc2p[idx] = f2bf(c2_w[((size_t)co * 256 + cc * 32 + ci_in) * 9 + tap]);
            return;
        }
        idx -= T_C2;
        if (idx < T_C1) { wc1b[idx] = f2bf(c1_w[idx]); return; }
        idx -= T_C1;
        if (idx < T_F) {
            const int co = idx >> 8, k = idx & 255;
            wfb[idx] = f2bf(f_w[co * 384 + k]);
            return;
        }
        idx -= T_F;
        if (idx < T_QK) {
            wqkb[idx] = f2bf(idx < 2048 ? q_w[idx] : k_w[idx - 2048]);
            return;
        }
        idx -= T_QK;
        if (idx < T_V) { wvb[idx] = f2bf(v_w[idx]); return; }
        idx -= T_V;
        if (idx < 1024) pool[idx] = 0.f;
        return;
    }

    const int f = blockIdx.x - PACK_BLKS;
    const int p0 = (f & 63) * 64;
    const int c0 = ((f >> 6) & 7) * 64;
    const int b  = f >> 9;
    for (int i = tid; i < 4096; i += 256) {
        const int ch = i >> 6, px = i & 63;
        sT[ch][px] = x[(size_t)(b * 512 + c0 + ch) * HW + p0 + px];
    }
    __syncthreads();
    const int px = tid >> 2, seg = tid & 3;
    ushort tmp[16];
    #pragma unroll
    for (int j = 0; j < 16; ++j) tmp[j] = f2bf(sT[seg * 16 + j][px]);
    ushort* d = xbf + (size_t)(b * HW + p0 + px) * 512 + c0 + seg * 16;
    *(uint4*)d = *(uint4*)&tmp[0];
    *(uint4*)(d + 8) = *(uint4*)&tmp[8];
}

// ---------------------------------------------------------------------------
// MFMA implicit-GEMM 3x3 conv, FULL-K, fused BN+PReLU epilogue (dc only).
// r15: weight staging via global_load_lds (dest is lane-linear: chunk i ->
// sW[i*8], WCH wave-divisible; per-lane global src allowed per m173).
// Removes the VGPR round-trip (m151: reg-staged 646 vs glds 874 TF).
// Input staging unchanged (SAS=40 pad breaks lane-linearity).
// COMPILER FACT (r5, r8): staging arrays with all elements live at once get
// spilled; only load->immediate-consume staging stays in registers.
// ---------------------------------------------------------------------------
template<int CIN, int COUT, int COTILE, int DIL, int ROWS, int OMODE>
__global__ __launch_bounds__(256, OMODE == 0 ? 4 : 2) void conv3x3_fused(
    const ushort* __restrict__ xin,
    const ushort* __restrict__ wpk,
    const float* __restrict__ bias, const float* __restrict__ bng,
    const float* __restrict__ bnb, const float* __restrict__ bnm,
    const float* __restrict__ bnv, const float* __restrict__ al,
    void* __restrict__ outv,
    float* __restrict__ pool)
{
    constexpr int HR = ROWS + 2 * DIL;
    constexpr int NC = 64 + 2 * DIL;
    constexpr int MT = COTILE / 16;
    constexpr int WPR = 4 / ROWS;
    constexpr int NT = ROWS;
    constexpr int SAS = 40;
    constexpr int CH = CIN / 32;
    constexpr int NA = HR * NC * 4;
    constexpr int NREG = (NA + 255) / 256;
    constexpr int WCH = 9 * MT * 64;
    constexpr int WPT = (WCH + 255) / 256;

    const int tid = threadIdx.x;
    const int wave = tid >> 6, lane = tid & 63;
    const int l15 = lane & 15, quad = lane >> 4;
    const int b = blockIdx.z;
    const int cob = blockIdx.y;
    const int co0 = cob * COTILE;
    const int h0 = blockIdx.x * ROWS;
    const int row = wave / WPR;
    const int ntbase = (wave % WPR) * NT;

    __shared__ __align__(16) ushort sA[HR * NC * SAS];
    __shared__ __align__(16) ushort sW[WCH * 8];

    f32x4 acc[MT][NT];
    #pragma unroll
    for (int mt = 0; mt < MT; ++mt)
        #pragma unroll
        for (int nt = 0; nt < NT; ++nt) acc[mt][nt] = (f32x4){0.f, 0.f, 0.f, 0.f};

    #pragma unroll 1
    for (int cc = 0; cc < CH; ++cc) {
        if (cc != 0) __syncthreads();
        // ---- stage input tile: load -> immediate ds_write (padded layout)
        #pragma unroll
        for (int k = 0; k < NREG; ++k) {
            const int i = tid + k * 256;
            if (i < NA) {
                const int p = i >> 2, seg = i & 3;
                const int r = p / NC, c = p - r * NC;
                const int grow = h0 - DIL + r, gcol = c - DIL;
                uint4 val = {0u, 0u, 0u, 0u};
                if (grow >= 0 && grow < 64 && gcol >= 0 && gcol < 64)
                    val = *(const uint4*)&xin[((size_t)(b * 64 + grow) * 64 + gcol) * CIN
                                              + cc * 32 + seg * 8];
                *(uint4*)&sA[p * SAS + seg * 8] = val;
            }
        }
        // ---- stage weight slice: lane-linear dest -> global_load_lds (r15)
        #pragma unroll
        for (int k = 0; k < WPT; ++k) {
            const int i = tid + k * 256;
            if (i < WCH) {
                const int tap = i / (MT * 64);
                const int r = i - tap * (MT * 64);
                const int mt = r >> 6, n = r & 63;
                const ushort* gsrc = &wpk[
                    ((size_t)(tap * (CIN / 32) + cc) * COUT + co0 + mt * 16 + (n & 15)) * 32
                    + (n >> 4) * 8];
#if USE_GLL
                __builtin_amdgcn_global_load_lds(
                    (const unsigned int*)gsrc, (unsigned int*)&sW[i * 8], 16, 0, 0);
#else
                *(uint4*)&sW[i * 8] = *(const uint4*)gsrc;
#endif
            }
        }
        __syncthreads();

        #pragma unroll
        for (int tap = 0; tap < 9; ++tap) {
            const int ty = tap / 3, tx = tap - ty * 3;
            const int rl = row + ty * DIL;
            bf16x8 wf[MT];
            #pragma unroll
            for (int mt = 0; mt < MT; ++mt)
                wf[mt] = *(const bf16x8*)&sW[((tap * MT + mt) * 64 + lane) * 8];
            #pragma unroll
            for (int nt = 0; nt < NT; ++nt) {
                const int cl = (ntbase + nt) * 16 + l15 + tx * DIL;
                const bf16x8 bp = *(const bf16x8*)&sA[(rl * NC + cl) * SAS + quad * 8];
                #pragma unroll
                for (int mt = 0; mt < MT; ++mt)
                    acc[mt][nt] = __builtin_amdgcn_mfma_f32_16x16x32_bf16(
                        wf[mt], bp, acc[mt][nt], 0, 0, 0);
            }
        }
    }

    const float a = al[0];

    if constexpr (OMODE == 0) {
        __syncthreads();
        ushort* sT = sA;
        #pragma unroll
        for (int mt = 0; mt < MT; ++mt) {
            float sc[4], sh[4], psum[4];
            #pragma unroll
            for (int rr = 0; rr < 4; ++rr) {
                const int co = co0 + mt * 16 + quad * 4 + rr;
                sc[rr] = bng[co] * rsqrtf(bnv[co] + EPSV);
                sh[rr] = (bias[co] - bnm[co]) * sc[rr] + bnb[co];
                psum[rr] = 0.f;
            }
            #pragma unroll
            for (int nt = 0; nt < NT; ++nt) {
                float tv[4];
                #pragma unroll
                for (int rr = 0; rr < 4; ++rr) {
                    float t = acc[mt][nt][rr] * sc[rr] + sh[rr];
                    t = t >= 0.f ? t : a * t;
                    tv[rr] = t;
                    psum[rr] += t;
                }
                ushort4 u;
                u.x = f2bf(tv[0]); u.y = f2bf(tv[1]);
                u.z = f2bf(tv[2]); u.w = f2bf(tv[3]);
                const int px = (ntbase + nt) * 16 + l15;
                *(ushort4*)&sT[(row * 64 + px) * 40 + mt * 16 + quad * 4] = u;
            }
            #pragma unroll
            for (int rr = 0; rr < 4; ++rr) {
                float v = psum[rr];
                v += __shfl_xor(v, 1);
                v += __shfl_xor(v, 2);
                v += __shfl_xor(v, 4);
                v += __shfl_xor(v, 8);
                if (l15 == 0)
                    atomicAdd(&pool[b * 256 + co0 + mt * 16 + quad * 4 + rr], v);
            }
        }
        __syncthreads();
        ushort* dst = (ushort*)outv;
        const int p = tid >> 1, half = tid & 1;
        const uint4 v0 = *(const uint4*)&sT[p * 40 + half * 16];
        const uint4 v1 = *(const uint4*)&sT[p * 40 + half * 16 + 8];
        const size_t off = ((size_t)(b * 4096 + (h0 + (p >> 6)) * 64 + (p & 63))) * 256
                           + co0 + half * 16;
        *(uint4*)&dst[off] = v0;
        *(uint4*)&dst[off + 8] = v1;
    } else {
        float* out = (float*)outv;
        #pragma unroll
        for (int mt = 0; mt < MT; ++mt)
            #pragma unroll
            for (int rr = 0; rr < 4; ++rr) {
                const int co = co0 + mt * 16 + quad * 4 + rr;
                const float sc = bng[co] * rsqrtf(bnv[co] + EPSV);
                const float sh = (bias[co] - bnm[co]) * sc + bnb[co];
                #pragma unroll
                for (int nt = 0; nt < NT; ++nt) {
                    float t = acc[mt][nt][rr] * sc + sh;
                    t = t >= 0.f ? t : a * t;
                    out[((size_t)(b * COUT + co) * 64 + h0 + row) * 64
                        + (ntbase + nt) * 16 + l15] = t;
                }
            }
    }
}

// ---------------------------------------------------------------------------
// MERGED: c2 dilated conv (bf16 ch-last out) + c1 gemm + c3 fbias.
// Grid (49, 4, 4): x<32 -> c2 conv; x>=32 -> flat c1/c3 blocks.
// r15: c2 weight staging via global_load_lds (same lane-linear argument).
// ---------------------------------------------------------------------------
__global__ __launch_bounds__(256, 2) void c2_c1_c3(
    const ushort* __restrict__ xin,
    const ushort* __restrict__ wpk,
    const float* __restrict__ c2bias, const float* __restrict__ c2gn,
    const float* __restrict__ c2bt, const float* __restrict__ c2mn,
    const float* __restrict__ c2vr, const float* __restrict__ c2al,
    ushort* __restrict__ c2out,
    const ushort* __restrict__ wbf,
    const float* __restrict__ bias, const float* __restrict__ bng,
    const float* __restrict__ bnb, const float* __restrict__ bnm,
    const float* __restrict__ bnv, const float* __restrict__ al,
    ushort* __restrict__ catb,
    const float* __restrict__ pool, const float* __restrict__ c3w,
    const float* __restrict__ c3b, const float* __restrict__ c3g,
    const float* __restrict__ c3bt, const float* __restrict__ c3m,
    const float* __restrict__ c3v, const float* __restrict__ c3a,
    const float* __restrict__ fw, float* __restrict__ fbias)
{
    const int tid = threadIdx.x;
    const int wave = tid >> 6, lane = tid & 63;
    const int l15 = lane & 15, quad = lane >> 4;
    __shared__ __align__(16) char smem[51072];

    if (blockIdx.x < 32) {
        constexpr int CIN = 256, COUT = 128, COTILE = 32, DIL = 2, ROWS = 2;
        constexpr int HR = ROWS + 2 * DIL;
        constexpr int NC = 64 + 2 * DIL;
        constexpr int MT = COTILE / 16;
        constexpr int WPR = 4 / ROWS;
        constexpr int NT = ROWS;
        constexpr int SAS = 40;
        constexpr int CH = CIN / 32;
        constexpr int NA = HR * NC * 4;
        constexpr int NREG = (NA + 255) / 256;
        constexpr int WCH = 9 * MT * 64;
        constexpr int WPT = (WCH + 255) / 256;

        ushort* sA = (ushort*)smem;
        ushort* sW = (ushort*)(smem + 32640);

        const int b = blockIdx.z;
        const int co0 = blockIdx.y * COTILE;
        const int h0 = blockIdx.x * ROWS;
        const int row = wave / WPR;
        const int ntbase = (wave % WPR) * NT;

        f32x4 acc[MT][NT];
        #pragma unroll
        for (int mt = 0; mt < MT; ++mt)
            #pragma unroll
            for (int nt = 0; nt < NT; ++nt) acc[mt][nt] = (f32x4){0.f, 0.f, 0.f, 0.f};

        #pragma unroll 1
        for (int cc = 0; cc < CH; ++cc) {
            if (cc != 0) __syncthreads();
            #pragma unroll
            for (int k = 0; k < NREG; ++k) {
                const int i = tid + k * 256;
                if (i < NA) {
                    const int p = i >> 2, seg = i & 3;
                    const int r = p / NC, c = p - r * NC;
                    const int grow = h0 - DIL + r, gcol = c - DIL;
                    uint4 val = {0u, 0u, 0u, 0u};
                    if (grow >= 0 && grow < 64 && gcol >= 0 && gcol < 64)
                        val = *(const uint4*)&xin[((size_t)(b * 64 + grow) * 64 + gcol) * CIN
                                                  + cc * 32 + seg * 8];
                    *(uint4*)&sA[p * SAS + seg * 8] = val;
                }
            }
            #pragma unroll
            for (int k = 0; k < WPT; ++k) {
                const int i = tid + k * 256;
                if (i < WCH) {
                    const int tap = i / (MT * 64);
                    const int r = i - tap * (MT * 64);
                    const int mt = r >> 6, n = r & 63;
                    const ushort* gsrc = &wpk[
                        ((size_t)(tap * (CIN / 32) + cc) * COUT + co0 + mt * 16 + (n & 15)) * 32
                        + (n >> 4) * 8];
#if USE_GLL
                    __builtin_amdgcn_global_load_lds(
                        (const unsigned int*)gsrc, (unsigned int*)&sW[i * 8], 16, 0, 0);
#else
                    *(uint4*)&sW[i * 8] = *(const uint4*)gsrc;
#endif
                }
            }
            __syncthreads();

            #pragma unroll
            for (int tap = 0; tap < 9; ++tap) {
                const int ty = tap / 3, tx = tap - ty * 3;
                const int rl = row + ty * DIL;
                bf16x8 wf[MT];
                #pragma unroll
                for (int mt = 0; mt < MT; ++mt)
                    wf[mt] = *(const bf16x8*)&sW[((tap * MT + mt) * 64 + lane) * 8];
                #pragma unroll
                for (int nt = 0; nt < NT; ++nt) {
                    const int cl = (ntbase + nt) * 16 + l15 + tx * DIL;
                    const bf16x8 bp = *(const bf16x8*)&sA[(rl * NC + cl) * SAS + quad * 8];
                    #pragma unroll
                    for (int mt = 0; mt < MT; ++mt)
                        acc[mt][nt] = __builtin_amdgcn_mfma_f32_16x16x32_bf16(
                            wf[mt], bp, acc[mt][nt], 0, 0, 0);
                }
            }
        }

        const float a = c2al[0];
        __syncthreads();
        ushort* sTc = (ushort*)smem;
        #pragma unroll
        for (int mt = 0; mt < MT; ++mt) {
            float sc[4], sh[4];
            #pragma unroll
            for (int rr = 0; rr < 4; ++rr) {
                const int co = co0 + mt * 16 + quad * 4 + rr;
                sc[rr] = c2gn[co] * rsqrtf(c2vr[co] + EPSV);
                sh[rr] = (c2bias[co] - c2mn[co]) * sc[rr] + c2bt[co];
            }
            #pragma unroll
            for (int nt = 0; nt < NT; ++nt) {
                float tv[4];
                #pragma unroll
                for (int rr = 0; rr < 4; ++rr) {
                    float t = acc[mt][nt][rr] * sc[rr] + sh[rr];
                    tv[rr] = t >= 0.f ? t : a * t;
                }
                ushort4 u;
                u.x = f2bf(tv[0]); u.y = f2bf(tv[1]);
                u.z = f2bf(tv[2]); u.w = f2bf(tv[3]);
                const int px = (ntbase + nt) * 16 + l15;
                *(ushort4*)&sTc[(row * 64 + px) * 40 + mt * 16 + quad * 4] = u;
            }
        }
        __syncthreads();
        const int p = tid >> 1, half = tid & 1;
        const uint4 v0 = *(const uint4*)&sTc[p * 40 + half * 16];
        const uint4 v1 = *(const uint4*)&sTc[p * 40 + half * 16 + 8];
        const size_t off = ((size_t)(b * 4096 + (h0 + (p >> 6)) * 64 + (p & 63))) * 128
                           + co0 + half * 16;
        *(uint4*)&c2out[off] = v0;
        *(uint4*)&c2out[off + 8] = v1;
        return;
    }

    const int flat = (blockIdx.z * 4 + blockIdx.y) * 17 + (blockIdx.x - 32);
    if (flat >= 260) return;
    const int bx = flat % 130, by = flat / 130;

    if (bx >= 128) {
        const int b = (bx - 128) * 2 + by;
        float* sp  = (float*)smem;
        float* sc3 = (float*)(smem + 2048);
        sp[tid] = pool[b * 256 + tid] * (1.0f / 4096.0f);
        __syncthreads();
        if (tid < 128) {
            float acc2 = c3b[tid];
            for (int ci = 0; ci < 256; ++ci) acc2 = fmaf(c3w[tid * 256 + ci], sp[ci], acc2);
            const float scale = c3g[tid] * rsqrtf(c3v[tid] + EPSV);
            float t = (acc2 - c3m[tid]) * scale + c3bt[tid];
            const float a2 = c3a[0];
            sc3[tid] = t >= 0.f ? t : a2 * t;
        }
        __syncthreads();
        float f = 0.f;
        for (int j2 = 0; j2 < 128; ++j2) f = fmaf(fw[tid * 384 + 256 + j2], sc3[j2], f);
        fbias[b * 256 + tid] = f;
        return;
    }

    {
        constexpr int CIN = 256;
        const int pix0 = bx * 128 + wave * 32;
        const int co0 = by * 64;

        f32x4 acc[4][2];
        #pragma unroll
        for (int mt = 0; mt < 4; ++mt)
            #pragma unroll
            for (int nt = 0; nt < 2; ++nt) acc[mt][nt] = (f32x4){0.f, 0.f, 0.f, 0.f};

        #pragma unroll 2
        for (int cc = 0; cc < CIN / 32; ++cc) {
            bf16x8 aw[4], bp[2];
            #pragma unroll
            for (int mt = 0; mt < 4; ++mt)
                aw[mt] = *(const bf16x8*)&wbf[(size_t)(co0 + mt * 16 + l15) * CIN + cc * 32 + quad * 8];
            #pragma unroll
            for (int nt = 0; nt < 2; ++nt)
                bp[nt] = *(const bf16x8*)&xin[(size_t)(pix0 + nt * 16 + l15) * CIN + cc * 32 + quad * 8];
            #pragma unroll
            for (int mt = 0; mt < 4; ++mt)
                #pragma unroll
                for (int nt = 0; nt < 2; ++nt)
                    acc[mt][nt] = __builtin_amdgcn_mfma_f32_16x16x32_bf16(
                        aw[mt], bp[nt], acc[mt][nt], 0, 0, 0);
        }

        const float a = al[0];
        ushort* sT = (ushort*)smem;
        #pragma unroll
        for (int mt = 0; mt < 4; ++mt)
            #pragma unroll
            for (int r = 0; r < 4; ++r) {
                const int co = co0 + mt * 16 + quad * 4 + r;
                const float scale = bng[co] * rsqrtf(bnv[co] + EPSV);
                const float shift = bias[co] * scale + (bnb[co] - bnm[co] * scale);
                #pragma unroll
                for (int nt = 0; nt < 2; ++nt) {
                    float t = acc[mt][nt][r] * scale + shift;
                    t = t >= 0.f ? t : a * t;
                    sT[((wave * 32 + nt * 16 + l15) * 68) + mt * 16 + quad * 4 + r] = f2bf(t);
                }
            }
        __syncthreads();
        const int p = lane >> 1, half = lane & 1;
        #pragma unroll
        for (int seg = 0; seg < 4; ++seg) {
            uint2 a0 = *(uint2*)&sT[((wave * 32 + p) * 68) + half * 32 + seg * 8];
            uint2 a1 = *(uint2*)&sT[((wave * 32 + p) * 68) + half * 32 + seg * 8 + 4];
            uint4 vv = {a0.x, a0.y, a1.x, a1.y};
            *(uint4*)&catb[(size_t)(pix0 + p) * 256 + co0 + half * 32 + seg * 8] = vv;
        }
    }
}

// ---------------------------------------------------------------------------
// MFMA 1x1 conv on channel-last bf16 input (used for the FUSE conv, OMODE 0).
// ---------------------------------------------------------------------------
template<int CIN, int COUT, bool BNACT, int OMODE>
__global__ __launch_bounds__(256) void gemm1x1_cl(
    const ushort* __restrict__ xin,
    const ushort* __restrict__ wbf,
    const float* __restrict__ bias, const float* __restrict__ bng,
    const float* __restrict__ bnb, const float* __restrict__ bnm,
    const float* __restrict__ bnv, const float* __restrict__ al,
    const float* __restrict__ ebias, void* __restrict__ outv,
    int ostride, int ocol)
{
    const int tid = threadIdx.x;
    const int wave = tid >> 6, lane = tid & 63;
    const int l15 = lane & 15, quad = lane >> 4;
    const int pix0 = blockIdx.x * 128 + wave * 32;
    const int co0 = blockIdx.y * 64;

    f32x4 acc[4][2];
    #pragma unroll
    for (int mt = 0; mt < 4; ++mt)
        #pragma unroll
        for (int nt = 0; nt < 2; ++nt) acc[mt][nt] = (f32x4){0.f, 0.f, 0.f, 0.f};

    #pragma unroll 2
    for (int cc = 0; cc < CIN / 32; ++cc) {
        bf16x8 aw[4], bp[2];
        #pragma unroll
        for (int mt = 0; mt < 4; ++mt)
            aw[mt] = *(const bf16x8*)&wbf[(size_t)(co0 + mt * 16 + l15) * CIN + cc * 32 + quad * 8];
        #pragma unroll
        for (int nt = 0; nt < 2; ++nt)
            bp[nt] = *(const bf16x8*)&xin[(size_t)(pix0 + nt * 16 + l15) * CIN + cc * 32 + quad * 8];
        #pragma unroll
        for (int mt = 0; mt < 4; ++mt)
            #pragma unroll
            for (int nt = 0; nt < 2; ++nt)
                acc[mt][nt] = __builtin_amdgcn_mfma_f32_16x16x32_bf16(
                    aw[mt], bp[nt], acc[mt][nt], 0, 0, 0);
    }

    const int bI = pix0 >> 12;
    const float a = BNACT ? al[0] : 0.f;

    if (OMODE == 0) {
        float* out = (float*)outv;
        #pragma unroll
        for (int mt = 0; mt < 4; ++mt)
            #pragma unroll
            for (int r = 0; r < 4; ++r) {
                const int co = co0 + mt * 16 + quad * 4 + r;
                float bb = bias[co];
                if (ebias) bb += ebias[bI * COUT + co];
                float scale = 1.f, shift = bb;
                if (BNACT) {
                    scale = bng[co] * rsqrtf(bnv[co] + EPSV);
                    shift = bb * scale + (bnb[co] - bnm[co] * scale);
                }
                #pragma unroll
                for (int nt = 0; nt < 2; ++nt) {
                    float t = acc[mt][nt][r] * scale + shift;
                    if (BNACT) t = t >= 0.f ? t : a * t;
                    out[((size_t)(bI * COUT + co)) * HW + (pix0 & 4095) + nt * 16 + l15] = t;
                }
            }
    } else {
        __shared__ ushort sT[4][32][68];
        #pragma unroll
        for (int mt = 0; mt < 4; ++mt)
            #pragma unroll
            for (int r = 0; r < 4; ++r) {
                const int co = co0 + mt * 16 + quad * 4 + r;
                float bb = bias[co];
                float scale = 1.f, shift = bb;
                if (BNACT) {
                    scale = bng[co] * rsqrtf(bnv[co] + EPSV);
                    shift = bb * scale + (bnb[co] - bnm[co] * scale);
                }
                #pragma unroll
                for (int nt = 0; nt < 2; ++nt) {
                    float t = acc[mt][nt][r] * scale + shift;
                    if (BNACT) t = t >= 0.f ? t : a * t;
                    sT[wave][nt * 16 + l15][mt * 16 + quad * 4 + r] = f2bf(t);
                }
            }
        __syncthreads();
        const int p = lane >> 1, half = lane & 1;
        ushort* out = (ushort*)outv;
        #pragma unroll
        for (int seg = 0; seg < 4; ++seg) {
            uint2 a0 = *(uint2*)&sT[wave][p][half * 32 + seg * 8];
            uint2 a1 = *(uint2*)&sT[wave][p][half * 32 + seg * 8 + 4];
            uint4 vv = {a0.x, a0.y, a1.x, a1.y};
            *(uint4*)&out[(size_t)(pix0 + p) * ostride + ocol + co0 + half * 32 + seg * 8] = vv;
        }
    }
}

// ---------------------------------------------------------------------------
// qk + v as MFMA gemms on bf16 ch-last c2bh (r13-verified).  Grid (32, 3, 4).
// ---------------------------------------------------------------------------
__global__ __launch_bounds__(256) void qkv_mfma(
    const ushort* __restrict__ c2bh,
    const ushort* __restrict__ wqkb,
    const float* __restrict__ qb2, const float* __restrict__ kb2,
    ushort* __restrict__ qpack, ushort* __restrict__ kpack,
    const ushort* __restrict__ wvb,
    const float* __restrict__ vb, ushort* __restrict__ vbh)
{
    const int tid = threadIdx.x;
    const int wave = tid >> 6, lane = tid & 63;
    const int l15 = lane & 15, quad = lane >> 4;
    const int b = blockIdx.z;
    const int pix0 = blockIdx.x * 128 + wave * 32;
    const size_t xrow = (size_t)(b * 4096);

    if (blockIdx.y == 0) {
        f32x4 acc[2][2];
        #pragma unroll
        for (int mt = 0; mt < 2; ++mt)
            #pragma unroll
            for (int nt = 0; nt < 2; ++nt) acc[mt][nt] = (f32x4){0.f, 0.f, 0.f, 0.f};
        #pragma unroll
        for (int cc = 0; cc < 4; ++cc) {
            bf16x8 aw[2], bp[2];
            #pragma unroll
            for (int mt = 0; mt < 2; ++mt)
                aw[mt] = *(const bf16x8*)&wqkb[(mt * 16 + l15) * 128 + cc * 32 + quad * 8];
            #pragma unroll
            for (int nt = 0; nt < 2; ++nt)
                bp[nt] = *(const bf16x8*)&c2bh[(xrow + pix0 + nt * 16 + l15) * 128 + cc * 32 + quad * 8];
            #pragma unroll
            for (int mt = 0; mt < 2; ++mt)
                #pragma unroll
                for (int nt = 0; nt < 2; ++nt)
                    acc[mt][nt] = __builtin_amdgcn_mfma_f32_16x16x32_bf16(
                        aw[mt], bp[nt], acc[mt][nt], 0, 0, 0);
        }
        __shared__ __align__(16) ushort sT[4][32][40];
        #pragma unroll
        for (int mt = 0; mt < 2; ++mt)
            #pragma unroll
            for (int r = 0; r < 4; ++r) {
                const int co = mt * 16 + quad * 4 + r;
                const float bb = (co < 16) ? qb2[co] : kb2[co - 16];
                #pragma unroll
                for (int nt = 0; nt < 2; ++nt)
                    sT[wave][nt * 16 + l15][co] = f2bf(acc[mt][nt][r] + bb);
            }
        __syncthreads();
        const int p = lane >> 1, half = lane & 1;
        ushort* dst = half ? kpack : qpack;
        const int cbase = half ? 16 : 0;
        const size_t off = (size_t)(b * 4096 + pix0 + p) * 32;
        *(uint4*)&dst[off]     = *(uint4*)&sT[wave][p][cbase];
        *(uint4*)&dst[off + 8] = *(uint4*)&sT[wave][p][cbase + 8];
        const uint4 zz = {0u, 0u, 0u, 0u};
        *(uint4*)&dst[off + 16] = zz;
        *(uint4*)&dst[off + 24] = zz;
    } else {
        const int co0 = (blockIdx.y - 1) * 64;
        f32x4 acc[4][2];
        #pragma unroll
        for (int mt = 0; mt < 4; ++mt)
            #pragma unroll
            for (int nt = 0; nt < 2; ++nt) acc[mt][nt] = (f32x4){0.f, 0.f, 0.f, 0.f};
        #pragma unroll
        for (int cc = 0; cc < 4; ++cc) {
            bf16x8 aw[4], bp[2];
            #pragma unroll
            for (int mt = 0; mt < 4; ++mt)
                aw[mt] = *(const bf16x8*)&wvb[(size_t)(co0 + mt * 16 + l15) * 128 + cc * 32 + quad * 8];
            #pragma unroll
            for (int nt = 0; nt < 2; ++nt)
                bp[nt] = *(const bf16x8*)&c2bh[(xrow + pix0 + nt * 16 + l15) * 128 + cc * 32 + quad * 8];
            #pragma unroll
            for (int mt = 0; mt < 4; ++mt)
                #pragma unroll
                for (int nt = 0; nt < 2; ++nt)
                    acc[mt][nt] = __builtin_amdgcn_mfma_f32_16x16x32_bf16(
                        aw[mt], bp[nt], acc[mt][nt], 0, 0, 0);
        }
        #pragma unroll
        for (int mt = 0; mt < 4; ++mt)
            #pragma unroll
            for (int r = 0; r < 4; ++r) {
                const int co = co0 + mt * 16 + quad * 4 + r;
                const float shift = vb[co];
                #pragma unroll
                for (int nt = 0; nt < 2; ++nt) {
                    const int px = pix0 + nt * 16 + l15;
                    vbh[(size_t)(b * 128 + co) * HW + px] = f2bf(acc[mt][nt][r] + shift);
                }
            }
    }
}

// ---------------------------------------------------------------------------
// SINGLE-PASS flash attention, msplit=4 (r14-verified).
// Grid: (32 nblk, 4 msplit, 4 batch).
// ---------------------------------------------------------------------------
__global__ __launch_bounds__(256) void attn_flash(
    const ushort* __restrict__ qpack,
    const ushort* __restrict__ kpack,
    const ushort* __restrict__ vpackT,
    ushort* __restrict__ opart,       // [b][4j][4096n][128c] bf16
    float* __restrict__ Mpart,        // [b][4j][4096n]
    float* __restrict__ Spart)
{
    const int tid = threadIdx.x;
    const int wave = tid >> 6, lane = tid & 63;
    const int l15 = lane & 15, quad = lane >> 4;
    const int b = blockIdx.z, j = blockIdx.y;
    const int n0w = blockIdx.x * 128 + wave * 32;
    const int m_begin = j * 1024;

    __shared__ __align__(16) ushort sV[2][128][40];
    __shared__ __align__(16) ushort sP[4][2][16][40];

    const bf16x8 bq0 = *(const bf16x8*)(qpack + ((size_t)(b * 4096 + n0w + l15) * 32 + quad * 8));
    const bf16x8 bq1 = *(const bf16x8*)(qpack + ((size_t)(b * 4096 + n0w + 16 + l15) * 32 + quad * 8));
    const f32x4 z = {0.f, 0.f, 0.f, 0.f};

    float runM0 = -3e30f, runM1 = -3e30f;
    float runS0 = 0.f, runS1 = 0.f;
    f32x4 oacc0[8], oacc1[8];
    #pragma unroll
    for (int cs = 0; cs < 8; ++cs) {
        oacc0[cs] = (f32x4){0.f, 0.f, 0.f, 0.f};
        oacc1[cs] = (f32x4){0.f, 0.f, 0.f, 0.f};
    }

    const int stc = tid >> 1, stseg = tid & 1;

    {
        uint4 v0 = *(const uint4*)&vpackT[(size_t)(b * 128 + stc) * HW + m_begin + stseg * 16];
        uint4 v1 = *(const uint4*)&vpackT[(size_t)(b * 128 + stc) * HW + m_begin + stseg * 16 + 8];
        *(uint4*)&sV[0][stc][stseg * 16] = v0;
        *(uint4*)&sV[0][stc][stseg * 16 + 8] = v1;
    }
    __syncthreads();

    #pragma unroll 1
    for (int t = 0; t < 32; ++t) {
        const int m0 = m_begin + t * 32;
        const int buf = t & 1;
        uint4 nv0, nv1;
        const bool more = (t + 1 < 32);
        if (more) {
            const size_t nb = (size_t)(b * 128 + stc) * HW + m0 + 32 + stseg * 16;
            nv0 = *(const uint4*)&vpackT[nb];
            nv1 = *(const uint4*)&vpackT[nb + 8];
        }
        f32x4 s0[2], s1[2];
        #pragma unroll
        for (int ms = 0; ms < 2; ++ms) {
            const bf16x8 ak = *(const bf16x8*)(
                kpack + ((size_t)(b * 4096 + m0 + ms * 16 + l15) * 32 + quad * 8));
            s0[ms] = __builtin_amdgcn_mfma_f32_16x16x32_bf16(ak, bq0, z, 0, 0, 0);
            s1[ms] = __builtin_amdgcn_mfma_f32_16x16x32_bf16(ak, bq1, z, 0, 0, 0);
        }

        float tM0 = fmaxf(fmaxf(fmaxf(s0[0][0], s0[0][1]), fmaxf(s0[0][2], s0[0][3])),
                          fmaxf(fmaxf(s0[1][0], s0[1][1]), fmaxf(s0[1][2], s0[1][3])));
        float tM1 = fmaxf(fmaxf(fmaxf(s1[0][0], s1[0][1]), fmaxf(s1[0][2], s1[0][3])),
                          fmaxf(fmaxf(s1[1][0], s1[1][1]), fmaxf(s1[1][2], s1[1][3])));
        tM0 = fmaxf(tM0, __shfl_xor(tM0, 16));
        tM0 = fmaxf(tM0, __shfl_xor(tM0, 32));
        tM1 = fmaxf(tM1, __shfl_xor(tM1, 16));
        tM1 = fmaxf(tM1, __shfl_xor(tM1, 32));
        if (__any(tM0 > runM0 + 8.f)) {
            const float nM = fmaxf(runM0, tM0);
            const float sc = __builtin_amdgcn_exp2f((runM0 - nM) * 1.44269504f);
            runS0 *= sc;
            float scr[4];
            #pragma unroll
            for (int r = 0; r < 4; ++r) scr[r] = __shfl(sc, quad * 4 + r);
            #pragma unroll
            for (int cs = 0; cs < 8; ++cs) {
                oacc0[cs][0] *= scr[0]; oacc0[cs][1] *= scr[1];
                oacc0[cs][2] *= scr[2]; oacc0[cs][3] *= scr[3];
            }
            runM0 = nM;
        }
        if (__any(tM1 > runM1 + 8.f)) {
            const float nM = fmaxf(runM1, tM1);
            const float sc = __builtin_amdgcn_exp2f((runM1 - nM) * 1.44269504f);
            runS1 *= sc;
            float scr[4];
            #pragma unroll
            for (int r = 0; r < 4; ++r) scr[r] = __shfl(sc, quad * 4 + r);
            #pragma unroll
            for (int cs = 0; cs < 8; ++cs) {
                oacc1[cs][0] *= scr[0]; oacc1[cs][1] *= scr[1];
                oacc1[cs][2] *= scr[2]; oacc1[cs][3] *= scr[3];
            }
            runM1 = nM;
        }
        const float Ms0 = runM0 * 1.44269504f;
        const float Ms1 = runM1 * 1.44269504f;

        #pragma unroll
        for (int ms = 0; ms < 2; ++ms) {
            float p0[4], p1[4];
            #pragma unroll
            for (int r = 0; r < 4; ++r) {
                p0[r] = __builtin_amdgcn_exp2f(fmaf(s0[ms][r], 1.44269504f, -Ms0));
                p1[r] = __builtin_amdgcn_exp2f(fmaf(s1[ms][r], 1.44269504f, -Ms1));
                runS0 += p0[r];
                runS1 += p1[r];
            }
            ushort4 u0, u1;
            u0.x = f2bf(p0[0]); u0.y = f2bf(p0[1]); u0.z = f2bf(p0[2]); u0.w = f2bf(p0[3]);
            u1.x = f2bf(p1[0]); u1.y = f2bf(p1[1]); u1.z = f2bf(p1[2]); u1.w = f2bf(p1[3]);
            *(uint2*)&sP[wave][0][l15][ms * 16 + quad * 4] = *(uint2*)&u0;
            *(uint2*)&sP[wave][1][l15][ms * 16 + quad * 4] = *(uint2*)&u1;
        }
        asm volatile("s_waitcnt lgkmcnt(0)" ::: "memory");
        const bf16x8 ap0 = *(const bf16x8*)&sP[wave][0][l15][quad * 8];
        const bf16x8 ap1 = *(const bf16x8*)&sP[wave][1][l15][quad * 8];
        #pragma unroll
        for (int cs = 0; cs < 8; ++cs) {
            const bf16x8 bv = *(const bf16x8*)&sV[buf][cs * 16 + l15][quad * 8];
            oacc0[cs] = __builtin_amdgcn_mfma_f32_16x16x32_bf16(ap0, bv, oacc0[cs], 0, 0, 0);
            oacc1[cs] = __builtin_amdgcn_mfma_f32_16x16x32_bf16(ap1, bv, oacc1[cs], 0, 0, 0);
        }
        if (more) {
            *(uint4*)&sV[buf ^ 1][stc][stseg * 16] = nv0;
            *(uint4*)&sV[buf ^ 1][stc][stseg * 16 + 8] = nv1;
            __syncthreads();
        }
    }

    runS0 += __shfl_xor(runS0, 16);
    runS0 += __shfl_xor(runS0, 32);
    runS1 += __shfl_xor(runS1, 16);
    runS1 += __shfl_xor(runS1, 32);
    if (lane < 32) {
        const float Mv = (lane < 16) ? runM0 : runM1;
        const float Sv = (lane < 16) ? runS0 : runS1;
        const int n = n0w + ((lane < 16) ? 0 : 16) + l15;
        Mpart[((size_t)b * 4 + j) * 4096 + n] = Mv;
        Spart[((size_t)b * 4 + j) * 4096 + n] = Sv;
    }
    #pragma unroll
    for (int cs = 0; cs < 8; ++cs)
        #pragma unroll
        for (int r = 0; r < 4; ++r) {
            const int n = n0w + quad * 4 + r;
            opart[(((size_t)b * 4 + j) * 4096 + n) * 128 + cs * 16 + l15] = f2bf(oacc0[cs][r]);
            opart[(((size_t)b * 4 + j) * 4096 + n + 16) * 128 + cs * 16 + l15] = f2bf(oacc1[cs][r]);
        }
}

// ---------------------------------------------------------------------------
// Combine 4 m-split partials, normalize, fuse gamma2*O + c2 residual.
// ---------------------------------------------------------------------------
__global__ __launch_bounds__(256) void attn_combine(
    const ushort* __restrict__ opart, const float* __restrict__ Mpart,
    const float* __restrict__ Spart, const ushort* __restrict__ c2bh,
    const float* __restrict__ gamma2, ushort* __restrict__ catb)
{
    const int b = blockIdx.y, n0 = blockIdx.x * 32, tid = threadIdx.x;
    __shared__ float sC2[128][33];
    __shared__ float sWj[4][32];
    if (tid < 32) {
        const int n = n0 + tid;
        float Mj[4], Sj[4];
        #pragma unroll
        for (int j = 0; j < 4; ++j) {
            Mj[j] = Mpart[((size_t)b * 4 + j) * 4096 + n];
            Sj[j] = Spart[((size_t)b * 4 + j) * 4096 + n];
        }
        float M = -3e30f;
        #pragma unroll
        for (int j = 0; j < 4; ++j) M = fmaxf(M, Mj[j]);
        float St = 0.f, e[4];
        #pragma unroll
        for (int j = 0; j < 4; ++j) { e[j] = __expf(Mj[j] - M); St += Sj[j] * e[j]; }
        const float inv = 1.0f / St;
        #pragma unroll
        for (int j = 0; j < 4; ++j) sWj[j][tid] = e[j] * inv;
    }
    #pragma unroll
    for (int e = 0; e < 16; ++e) {
        const int idx = tid + e * 256;
        const int n = idx >> 7, c = idx & 127;
        sC2[c][n] = bf2f(c2bh[(size_t)(b * 4096 + n0 + n) * 128 + c]);
    }
    __syncthreads();
    const float g2 = gamma2[0];
    #pragma unroll
    for (int e = 0; e < 16; ++e) {
        const int idx = tid + e * 256;
        const int n = idx >> 7, c = idx & 127;
        float s = 0.f;
        #pragma unroll
        for (int j = 0; j < 4; ++j)
            s += bf2f(opart[(((size_t)b * 4 + j) * 4096 + n0 + n) * 128 + c]) * sWj[j][n];
        catb[(size_t)(b * 4096 + n0 + n) * 256 + 128 + c] = f2bf(fmaf(g2, s, sC2[c][n]));
    }
}

// ---------------------------------------------------------------------------
extern "C" void kernel_launch(void* const* d_in, const int* in_sizes, int n_in,
                              void* d_out, int out_size, void* d_ws, size_t ws_size,
                              hipStream_t stream)
{
    const float* x     = (const float*)d_in[0];
    const float* dc_w  = (const float*)d_in[1];
    const float* dc_b  = (const float*)d_in[2];
    const float* dc_g  = (const float*)d_in[3];
    const float* dc_bt = (const float*)d_in[4];
    const float* dc_m  = (const float*)d_in[5];
    const float* dc_v  = (const float*)d_in[6];
    const float* dc_a  = (const float*)d_in[7];
    const float* c1_w  = (const float*)d_in[8];
    const float* c1_b  = (const float*)d_in[9];
    const float* c1_g  = (const float*)d_in[10];
    const float* c1_bt = (const float*)d_in[11];
    const float* c1_m  = (const float*)d_in[12];
    const float* c1_v  = (const float*)d_in[13];
    const float* c1_a  = (const float*)d_in[14];
    const float* c2_w  = (const float*)d_in[15];
    const float* c2_b  = (const float*)d_in[16];
    const float* c2_g  = (const float*)d_in[17];
    const float* c2_bt = (const float*)d_in[18];
    const float* c2_m  = (const float*)d_in[19];
    const float* c2_v  = (const float*)d_in[20];
    const float* c2_a  = (const float*)d_in[21];
    const float* q_w   = (const float*)d_in[22];
    const float* q_b   = (const float*)d_in[23];
    const float* k_w   = (const float*)d_in[24];
    const float* k_b   = (const float*)d_in[25];
    const float* v_w   = (const float*)d_in[26];
    const float* v_b   = (const float*)d_in[27];
    const float* gamma2= (const float*)d_in[28];
    const float* c3_w  = (const float*)d_in[29];
    const float* c3_b  = (const float*)d_in[30];
    const float* c3_g  = (const float*)d_in[31];
    const float* c3_bt = (const float*)d_in[32];
    const float* c3_m  = (const float*)d_in[33];
    const float* c3_v  = (const float*)d_in[34];
    const float* c3_a  = (const float*)d_in[35];
    const float* f_w   = (const float*)d_in[36];
    const float* f_b   = (const float*)d_in[37];
    const float* f_g   = (const float*)d_in[38];
    const float* f_bt  = (const float*)d_in[39];
    const float* f_m   = (const float*)d_in[40];
    const float* f_v   = (const float*)d_in[41];
    const float* f_a   = (const float*)d_in[42];

    // ---- workspace layout by live range ----
    char* base = (char*)d_ws;
    ushort* xbf   = (ushort*)base;                       // [4,4096,512] bf16
    ushort* opart = (ushort*)base;                       // [4,4,4096,128] bf16
    ushort* qpk   = (ushort*)(base + 33554432);          // [4,4096,32]
    ushort* kpk   = (ushort*)(base + 34603008);
    ushort* vbh   = (ushort*)(base + 35651584);          // [4,128,4096] bf16
    ushort* c2bh  = (ushort*)(base + 39845888);          // [4,4096,128] bf16
    ushort* wqkb  = (ushort*)(base + 48234496);          // [32,128] bf16
    ushort* wvb   = (ushort*)(base + 48242688);          // [128,128] bf16
    ushort* xpbf  = (ushort*)(base + 50331648);          // [4,4096,256] bf16
    ushort* catb  = (ushort*)(base + 58720256);          // [4,4096,256] bf16
    ushort* wdcp  = (ushort*)(base + 75497472);          // [9,16,256,32]
    ushort* wc2p  = (ushort*)(base + 77856768);          // [9,8,128,32]
    ushort* wc1b  = (ushort*)(base + 78446592);          // [128,256]
    ushort* wfb   = (ushort*)(base + 78512128);          // [256,256]
    float*  poolb = (float*)(base + 78643200);           // 1024 (atomic sums)
    float*  fbb   = (float*)(base + 78647296);           // 1024
    float*  Mpart = (float*)(base + 78651392);           // [4,4,4096]
    float*  Spart = (float*)(base + 79175680);           // [4,4,4096]

    // 0. packs (+qk/v bf16) + pool zero + x->chlast (ONE launch)
    pack_and_chlast<<<dim3(6228 + 2048), 256, 0, stream>>>(
        dc_w, wdcp, c2_w, wc2p, c1_w, wc1b, f_w, wfb,
        q_w, k_w, wqkb, v_w, wvb, poolb, x, xbf);
    // 1. down_conv 3x3 512->256, full-K, fused BN+PReLU -> xpbf + pool atomics
    conv3x3_fused<512, 256, 32, 1, 2, 0><<<dim3(32, 8, 4), 256, 0, stream>>>(
        xbf, wdcp, dc_b, dc_g, dc_bt, dc_m, dc_v, dc_a, xpbf, poolb);
    // 2. c2 dilated conv (bf16 ch-last) + c1 gemm + c3 fbias (ONE launch)
    c2_c1_c3<<<dim3(49, 4, 4), 256, 0, stream>>>(
        xpbf, wc2p, c2_b, c2_g, c2_bt, c2_m, c2_v, c2_a, c2bh,
        wc1b, c1_b, c1_g, c1_bt, c1_m, c1_v, c1_a, catb,
        poolb, c3_w, c3_b, c3_g, c3_bt, c3_m, c3_v, c3_a, f_w, fbb);
    // 3. q, k, v — all MFMA on bf16 ch-last
    qkv_mfma<<<dim3(32, 3, 4), 256, 0, stream>>>(
        c2bh, wqkb, q_b, k_b, qpk, kpk, wvb, v_b, vbh);
    // 4. single-pass online flash attention (msplit=4) + combine
    attn_flash<<<dim3(32, 4, 4), 256, 0, stream>>>(qpk, kpk, vbh, opart, Mpart, Spart);
    attn_combine<<<dim3(128, 4), 256, 0, stream>>>(opart, Mpart, Spart, c2bh, gamma2, catb);
    // 5. fuse conv (MFMA, K=256) -> d_out
    gemm1x1_cl<256, 256, true, 0><<<dim3(128, 4), 256, 0, stream>>>(
        catb, wfb, f_b, f_g, f_bt, f_m, f_v, f_a, fbb, (float*)d_out, 0, 0);
}